// Round 29
// baseline (157.291 us; speedup 1.0000x reference)
//
#include <hip/hip_runtime.h>

#define BB 16
#define NO 512
#define NM 32
#define DOC 128
#define C8 1024
#define NH 64
#define KD 16

// ---------------- ws layout (float offsets), ~44 MiB used ----------------
#define OFF_X12   0          // [16][64][512][16] bf16 h-sliced x1/x2 (in-place)
#define OFF_UO    0          // [8192,128] f32 (alias: x12h dead by then)
#define OFF_LOG   1048576    // [16,16384] (alias, after Uo)
#define OFF_HOPES 8388608    // [8192,128] ext-attn output
#define OFF_HOPEG 9437184    // [8192,128] GAT h_ope
#define OFF_HMAC  10485760   // [512,128]  GAT h_mac (pre)
#define OFF_HMACS 10551296   // [512,128]  GAT output
#define OFF_AO    10616832   // [8192]
#define OFF_AM    10625024   // [512]
#define OFF_PO    10625536   // [16,128]
#define OFF_PM    10627584   // [16,128]
#define OFF_UMHM  10629632   // [512,128]  hmacs-part of Um (MFMA)
#define OFF_FLAG  10695168   // int flag (mask dtype probe)
#define OFF_CNT   10695680   // int cnt[16] actor completion tickets
#define OFF_UP    10720000   // [16,128]   Up[b] = A0[:,256:512]*(po,pm)+Ab0
#define OFF_PART2 10750000   // [4096,3] per-wave actor softmax partials
#define OFF_A1P   10900000   // [16384] bf16 A1 pre-converted (OUTSIDE x12h!)

using f32x4  = __attribute__((ext_vector_type(4))) float;
using s16x4  = __attribute__((ext_vector_type(4))) short;
using bf16x8 = __attribute__((ext_vector_type(8))) short;   // 8 bf16 (4 VGPRs)

// clamp-free: exp(2x)->{0,inf} at extremes gives exactly -1/+1 via rcp
__device__ __forceinline__ float fast_tanh(float x) {
  float e = __expf(2.0f * x);
  return 1.0f - 2.0f * __builtin_amdgcn_rcpf(e + 1.0f);
}

__device__ __forceinline__ short f2bf(float f) {          // RNE f32->bf16
  unsigned u = __builtin_bit_cast(unsigned, f);
  u += 0x7FFFu + ((u >> 16) & 1u);
  return (short)(u >> 16);
}

__device__ __forceinline__ float bf2f(short s) {
  return __builtin_bit_cast(float, ((unsigned)(unsigned short)s) << 16);
}

__device__ __forceinline__ unsigned cvtpk(float a, float b) {
  unsigned r;
  asm("v_cvt_pk_bf16_f32 %0, %1, %2" : "=v"(r) : "v"(a), "v"(b));
  return r;
}

__device__ __forceinline__ bf16x8 pack8(f32x4 u0, f32x4 u1) {
  union { unsigned u[4]; bf16x8 v; } cv;
  cv.u[0] = cvtpk(u0[0], u0[1]);
  cv.u[1] = cvtpk(u0[2], u0[3]);
  cv.u[2] = cvtpk(u1[0], u1[1]);
  cv.u[3] = cvtpk(u1[2], u1[3]);
  return cv.v;
}

__device__ __forceinline__ bf16x8 pack8f(const float* t) {
  union { unsigned u[4]; bf16x8 v; } cv;
  cv.u[0] = cvtpk(t[0], t[1]);
  cv.u[1] = cvtpk(t[2], t[3]);
  cv.u[2] = cvtpk(t[4], t[5]);
  cv.u[3] = cvtpk(t[6], t[7]);
  return cv.v;
}

// online-softmax partial merge: (Ma,Sa,Ta) += (Mb,Sb,Tb)
__device__ __forceinline__ void smmerge(float& lm, float& lS, float& lT,
                                        float om, float oS, float oT) {
  float nm = fmaxf(lm, om);
  float ea = __expf(lm - nm), eb = __expf(om - nm);
  lT = (lT + (lm - nm) * lS) * ea + (oT + (om - nm) * oS) * eb;
  lS = lS * ea + oS * eb;
  lm = nm;
}

// ---------------- mask dtype probe (body) + ticket zeroing ----------------
__device__ void probe_body(int tid, const unsigned int* __restrict__ mask,
                           int* __restrict__ flag, int* __restrict__ cnt) {
  __shared__ int s[4];
  if (tid < 16) cnt[tid] = 0;
  int bad = 0;
  for (int i = tid; i < 4096; i += 256) {
    unsigned int v = mask[i];
    if (!(v == 0u || v == 1u || v == 0x3f800000u)) bad = 1;
  }
  unsigned long long any = __ballot(bad);
  int lane = tid & 63, w = tid >> 6;
  if (lane == 0) s[w] = (any != 0ull) ? 1 : 0;
  __syncthreads();
  if (tid == 0) flag[0] = s[0] | s[1] | s[2] | s[3];
}

// ---------------- GEMM bodies (verbatim, verified) ----------------
template<int MT>
__device__ __forceinline__ void loadk(const float* xb, const float* wb,
                                      long sx, long sw, int k0,
                                      f32x4 (&xa)[MT][2], f32x4 (&wa)[4][2]) {
  #pragma unroll
  for (int mi = 0; mi < MT; ++mi) {
    xa[mi][0] = *(const f32x4*)(xb + mi * sx + k0);
    xa[mi][1] = *(const f32x4*)(xb + mi * sx + k0 + 4);
  }
  #pragma unroll
  for (int ni = 0; ni < 4; ++ni) {
    wa[ni][0] = *(const f32x4*)(wb + ni * sw + k0);
    wa[ni][1] = *(const f32x4*)(wb + ni * sw + k0 + 4);
  }
}

template<int MT>
__device__ __forceinline__ void consume(f32x4 (&xa)[MT][2], f32x4 (&wa)[4][2],
                                        f32x4 (&acc)[MT][4]) {
  bf16x8 bfr[4];
  #pragma unroll
  for (int ni = 0; ni < 4; ++ni) bfr[ni] = pack8(wa[ni][0], wa[ni][1]);
  #pragma unroll
  for (int mi = 0; mi < MT; ++mi) {
    bf16x8 af = pack8(xa[mi][0], xa[mi][1]);
    #pragma unroll
    for (int ni = 0; ni < 4; ++ni)
      acc[mi][ni] = __builtin_amdgcn_mfma_f32_16x16x32_bf16(af, bfr[ni], acc[mi][ni], 0, 0, 0);
  }
}

template<int MT>
__device__ void gemm_wave_body(int bx, int by, int tid,
    const float* __restrict__ X, const float* __restrict__ W,
    const float* __restrict__ bias, float* __restrict__ C,
    int N, int Kdim, int ldx, int ldw) {
  const int lane = tid & 63, w = tid >> 6;
  const int rowl = lane & 15, kg = lane >> 4;
  const int n0 = bx * 64;
  const int m0 = (by * 4 + w) * (MT * 16);
  const float* xb = X + (long)(m0 + rowl) * ldx + kg * 8;
  const float* wb = W + (long)(n0 + rowl) * ldw + kg * 8;
  const long sx = (long)16 * ldx, sw = (long)16 * ldw;
  f32x4 acc[MT][4] = {};
  f32x4 A0[MT][2], B0[4][2], A1[MT][2], B1[4][2];
  loadk<MT>(xb, wb, sx, sw, 0, A0, B0);
  for (int k = 0; k < Kdim; k += 64) {
    loadk<MT>(xb, wb, sx, sw, k + 32, A1, B1);
    consume<MT>(A0, B0, acc);
    if (k + 64 < Kdim) loadk<MT>(xb, wb, sx, sw, k + 64, A0, B0);
    consume<MT>(A1, B1, acc);
  }
  #pragma unroll
  for (int mi = 0; mi < MT; ++mi) {
    #pragma unroll
    for (int ni = 0; ni < 4; ++ni) {
      int col = n0 + ni * 16 + rowl;
      float bv = bias ? bias[col] : 0.0f;
      int rb = m0 + mi * 16 + kg * 4;
      #pragma unroll
      for (int r = 0; r < 4; ++r)
        C[(long)(rb + r) * N + col] = acc[mi][ni][r] + bv;
    }
  }
}

// trans GEMM body: f32 in, bf16 h-sliced out.
template<int MT>
__device__ void gemm_ht_body(int bx, int by, int tid,
    const float* __restrict__ X, const float* __restrict__ W,
    const float* __restrict__ bias, short* __restrict__ Ch,
    int Kdim, int ldx, int ldw) {
  const int lane = tid & 63, w = tid >> 6;
  const int rowl = lane & 15, kg = lane >> 4;
  const int n0 = bx * 64;
  const int m0 = (by * 4 + w) * (MT * 16);
  const float* xb = X + (long)(m0 + rowl) * ldx + kg * 8;
  const float* wb = W + (long)(n0 + rowl) * ldw + kg * 8;
  const long sx = (long)16 * ldx, sw = (long)16 * ldw;
  f32x4 acc[MT][4] = {};
  f32x4 A0[MT][2], B0[4][2], A1[MT][2], B1[4][2];
  loadk<MT>(xb, wb, sx, sw, 0, A0, B0);
  for (int k = 0; k < Kdim; k += 64) {
    loadk<MT>(xb, wb, sx, sw, k + 32, A1, B1);
    consume<MT>(A0, B0, acc);
    if (k + 64 < Kdim) loadk<MT>(xb, wb, sx, sw, k + 64, A0, B0);
    consume<MT>(A1, B1, acc);
  }
  #pragma unroll
  for (int mi = 0; mi < MT; ++mi) {
    #pragma unroll
    for (int ni = 0; ni < 4; ++ni) {
      int col = n0 + ni * 16 + rowl;
      float bv = bias ? bias[col] : 0.0f;
      int h = col >> 4, e = col & 15;
      int rb = m0 + mi * 16 + kg * 4;
      #pragma unroll
      for (int r = 0; r < 4; ++r) {
        int rowI = rb + r;
        int b = rowI >> 9, n = rowI & 511;
        Ch[((long)(b * 64 + h) * 512 + n) * 16 + e] = f2bf(acc[mi][ni][r] + bv);
      }
    }
  }
}

__device__ void convert_a1_body(int blk, int tid,
    const float* __restrict__ A1, short* __restrict__ A1p) {
  int i = blk * 256 + tid;
  int col = i >> 7, k = i & 127;
  A1p[((k >> 3) * 128 + col) * 8 + (k & 7)] = f2bf(A1[i]);
}

// ---------------- mega1: trans MT=4 (512) + hopeG(256) + hmac(16) + convertA1(64) + probe(1) ----------------
__global__ __launch_bounds__(256) void mega1_kernel(
    const float* __restrict__ nop, const float* __restrict__ Wtr,
    const float* __restrict__ btr, short* __restrict__ x12h,
    const float* __restrict__ Wo, float* __restrict__ hopeG,
    const float* __restrict__ nmac, const float* __restrict__ Wm,
    float* __restrict__ hmac,
    const float* __restrict__ A1, short* __restrict__ A1p,
    const unsigned int* __restrict__ mask, int* __restrict__ flag,
    int* __restrict__ cnt) {
  const int blk = blockIdx.x, tid = threadIdx.x;
  if (blk < 512) {
    gemm_ht_body<4>(blk & 15, blk >> 4, tid, nop, Wtr, btr, x12h, 128, 128, 128);
  } else if (blk < 768) {
    int t = blk - 512;
    gemm_wave_body<1>(t & 1, t >> 1, tid, nop, Wo, nullptr, hopeG, 128, 128, 128, 128);
  } else if (blk < 784) {
    int t = blk - 768;
    gemm_wave_body<1>(t & 1, t >> 1, tid, nmac, Wm, nullptr, hmac, 128, 64, 64, 64);
  } else if (blk < 848) {
    convert_a1_body(blk - 784, tid, A1, A1p);
  } else {
    probe_body(tid, mask, flag, cnt);
  }
}

// ---------------- attn v3: MFMA-based (verified r23/r24) ----------------
__device__ void attn3_body(int b, int h, int tid, short* __restrict__ x12h,
    const float* __restrict__ W0, const float* __restrict__ b0,
    const float* __restrict__ W1, const float* __restrict__ b1) {
  __shared__ short Pb[4][128 * 16];      // 16 KB
  __shared__ float cmw[4][16], csw[4][16];
  const int wq = tid >> 6, lane = tid & 63;
  const int rowl = lane & 15, kg = lane >> 4;
  short* slice = x12h + (long)(b * 64 + h) * 8192;
  const short* wrows = slice + (long)(wq * 128) * 16;
  const bf16x8 zero8 = {};
  bf16x8 xa[8];
  #pragma unroll
  for (int t = 0; t < 8; ++t) {
    if (kg < 2)
      xa[t] = *(const bf16x8*)(wrows + (t * 16 + rowl) * 16 + kg * 8);
    else
      xa[t] = zero8;
  }
  bf16x8 w0f = zero8;
  if (kg < 2) {
    f32x4 a = *(const f32x4*)(W0 + rowl * 16 + kg * 8);
    f32x4 c = *(const f32x4*)(W0 + rowl * 16 + kg * 8 + 4);
    w0f = pack8(a, c);
  }
  const float b0v = b0[rowl];
  f32x4 acc[8];
  #pragma unroll
  for (int t = 0; t < 8; ++t) {
    f32x4 z = {0.f, 0.f, 0.f, 0.f};
    acc[t] = __builtin_amdgcn_mfma_f32_16x16x32_bf16(xa[t], w0f, z, 0, 0, 0);
  }
  float m = -1e30f;
  #pragma unroll
  for (int t = 0; t < 8; ++t)
    #pragma unroll
    for (int r = 0; r < 4; ++r) {
      acc[t][r] += b0v;
      m = fmaxf(m, acc[t][r]);
    }
  m = fmaxf(m, __shfl_xor(m, 16));
  m = fmaxf(m, __shfl_xor(m, 32));
  if (lane < 16) cmw[wq][lane] = m;
  __syncthreads();
  const float cm = fmaxf(fmaxf(cmw[0][rowl], cmw[1][rowl]),
                         fmaxf(cmw[2][rowl], cmw[3][rowl]));
  float s = 0.f;
  #pragma unroll
  for (int t = 0; t < 8; ++t)
    #pragma unroll
    for (int r = 0; r < 4; ++r) {
      float e = __expf(acc[t][r] - cm);
      acc[t][r] = e;
      s += e;
    }
  s += __shfl_xor(s, 16);
  s += __shfl_xor(s, 32);
  if (lane < 16) csw[wq][lane] = s;
  __syncthreads();
  const float cs = csw[0][rowl] + csw[1][rowl] + csw[2][rowl] + csw[3][rowl];
  const float cinv = 1.0f / cs;
  short* pbw = Pb[wq];
  #pragma unroll
  for (int t = 0; t < 8; ++t)
    #pragma unroll
    for (int r = 0; r < 4; ++r) {
      float al = acc[t][r] * cinv;
      float rsv = al;
      rsv += __shfl_xor(rsv, 1);
      rsv += __shfl_xor(rsv, 2);
      rsv += __shfl_xor(rsv, 4);
      rsv += __shfl_xor(rsv, 8);
      float pf = al / (1e-10f + rsv);
      pbw[(t * 16 + kg * 4 + r) * 16 + rowl] = f2bf(pf);
    }
  __syncthreads();
  bf16x8 w1f = zero8;
  if (kg < 2) {
    f32x4 a = *(const f32x4*)(W1 + rowl * 16 + kg * 8);
    f32x4 c = *(const f32x4*)(W1 + rowl * 16 + kg * 8 + 4);
    w1f = pack8(a, c);
  }
  const float b1v = b1[rowl];
  #pragma unroll
  for (int t = 0; t < 8; ++t) {
    bf16x8 pa = zero8;
    if (kg < 2)
      pa = *(const bf16x8*)(pbw + (t * 16 + rowl) * 16 + kg * 8);
    f32x4 z = {0.f, 0.f, 0.f, 0.f};
    f32x4 oacc = __builtin_amdgcn_mfma_f32_16x16x32_bf16(pa, w1f, z, 0, 0, 0);
    #pragma unroll
    for (int r = 0; r < 4; ++r) {
      int n = wq * 128 + t * 16 + kg * 4 + r;
      slice[(long)n * 16 + rowl] = f2bf(oacc[r] + b1v);
    }
  }
}

// ---------------- mega2: attn3(1024) + rowdot2(2176) ----------------
__global__ __launch_bounds__(256) void mega2_kernel(
    short* __restrict__ x12h,
    const float* __restrict__ W0, const float* __restrict__ b0,
    const float* __restrict__ W1, const float* __restrict__ b1,
    const float* __restrict__ hopeG, const float* __restrict__ alo,
    float* __restrict__ ao,
    const float* __restrict__ hmac, const float* __restrict__ alm,
    float* __restrict__ am) {
  const int blk = blockIdx.x, tid = threadIdx.x;
  if (blk < 1024) {
    attn3_body(blk >> 6, blk & 63, tid, x12h, W0, b0, W1, b1);
  } else {
    int t = blk - 1024;
    int wid = t * 4 + (tid >> 6);
    int lane = tid & 63;
    const float* X; const float* al; float* out; int r;
    if (wid < 8192)       { X = hopeG; al = alo; out = ao; r = wid; }
    else if (wid < 8704)  { X = hmac;  al = alm; out = am; r = wid - 8192; }
    else return;
    const float* row = X + (long)r * 128;
    float v = fmaf(row[lane], al[lane], row[lane + 64] * al[lane + 64]);
    #pragma unroll
    for (int off = 32; off; off >>= 1) v += __shfl_down(v, off);
    if (lane == 0) out[r] = v;
  }
}

// ---------------- proj GEMM body v1 (verified r15-r24) ----------------
__device__ void gemm_hx_body(int bx, int by, int tid,
    const short* __restrict__ Xh, const float* __restrict__ W,
    const float* __restrict__ bias, float* __restrict__ C) {
  const int lane = tid & 63, w = tid >> 6;
  const int rowl = lane & 15, kg = lane >> 4;
  const int n0 = bx * 64;
  const int m0 = (by * 4 + w) * 16;
  const int row = m0 + rowl, b = row >> 9, n = row & 511;
  const short* xb = Xh + (long)b * 524288 + (long)n * 16 + (kg & 1) * 8;
  const long hofs = kg >> 1;
  const float* wb = W + (long)(n0 + rowl) * 1024 + kg * 8;
  const long sw = 16 * 1024L;
  f32x4 acc[4] = {};
  bf16x8 A0, A1;
  f32x4 Wb0[4][2], Wb1[4][2];
  A0 = *(const bf16x8*)(xb + hofs * 8192);
  #pragma unroll
  for (int ni = 0; ni < 4; ++ni) {
    Wb0[ni][0] = *(const f32x4*)(wb + ni * sw);
    Wb0[ni][1] = *(const f32x4*)(wb + ni * sw + 4);
  }
  for (int k = 0; k < 1024; k += 64) {
    A1 = *(const bf16x8*)(xb + (((k + 32) >> 4) + hofs) * 8192);
    #pragma unroll
    for (int ni = 0; ni < 4; ++ni) {
      Wb1[ni][0] = *(const f32x4*)(wb + ni * sw + k + 32);
      Wb1[ni][1] = *(const f32x4*)(wb + ni * sw + k + 36);
    }
    #pragma unroll
    for (int ni = 0; ni < 4; ++ni) {
      bf16x8 bfr = pack8(Wb0[ni][0], Wb0[ni][1]);
      acc[ni] = __builtin_amdgcn_mfma_f32_16x16x32_bf16(A0, bfr, acc[ni], 0, 0, 0);
    }
    if (k + 64 < 1024) {
      A0 = *(const bf16x8*)(xb + (((k + 64) >> 4) + hofs) * 8192);
      #pragma unroll
      for (int ni = 0; ni < 4; ++ni) {
        Wb0[ni][0] = *(const f32x4*)(wb + ni * sw + k + 64);
        Wb0[ni][1] = *(const f32x4*)(wb + ni * sw + k + 68);
      }
    }
    #pragma unroll
    for (int ni = 0; ni < 4; ++ni) {
      bf16x8 bfr = pack8(Wb1[ni][0], Wb1[ni][1]);
      acc[ni] = __builtin_amdgcn_mfma_f32_16x16x32_bf16(A1, bfr, acc[ni], 0, 0, 0);
    }
  }
  #pragma unroll
  for (int ni = 0; ni < 4; ++ni) {
    int col = n0 + ni * 16 + rowl;
    float bv = bias ? bias[col] : 0.0f;
    int rb = m0 + kg * 4;
    #pragma unroll
    for (int r = 0; r < 4; ++r)
      C[(long)(rb + r) * 128 + col] = acc[ni][r] + bv;
  }
}

// ---------------- GAT body: 256 threads, 2 o's/thread (verified) ----------------
__device__ void gat_body(int b, int m, int tid,
    const float* __restrict__ adj, const float* __restrict__ ao,
    const float* __restrict__ am, const float* __restrict__ hopeG,
    const float* __restrict__ hmac, float* __restrict__ hmacs) {
  __shared__ float al[NO];
  __shared__ float redA[4], redB[4];
  __shared__ float part[2][128];
  const int lane = tid & 63, w = tid >> 6;
  const float amv = am[b * NM + m];
  float av[2], ev[2];
  float mx = -1e30f;
  #pragma unroll
  for (int i = 0; i < 2; ++i) {
    int o = tid + i * 256;
    float a = adj[(b * NO + o) * NM + m];
    float e = ao[b * NO + o] + amv;
    e = (e >= 0.f) ? e : 0.2f * e;
    av[i] = a; ev[i] = e;
    if (a == 1.0f) mx = fmaxf(mx, e);
  }
  #pragma unroll
  for (int off = 32; off; off >>= 1) mx = fmaxf(mx, __shfl_down(mx, off));
  if (lane == 0) redA[w] = mx;
  __syncthreads();
  mx = fmaxf(fmaxf(redA[0], redA[1]), fmaxf(redA[2], redA[3]));
  float p[2], s = 0.f;
  #pragma unroll
  for (int i = 0; i < 2; ++i) {
    p[i] = (av[i] == 1.0f) ? __expf(ev[i] - mx) : 0.f;
    s += p[i];
  }
  #pragma unroll
  for (int off = 32; off; off >>= 1) s += __shfl_down(s, off);
  if (lane == 0) redB[w] = s;
  __syncthreads();
  s = redB[0] + redB[1] + redB[2] + redB[3];
  const float sinv = (s > 0.f) ? 1.0f / s : 0.f;
  al[tid] = p[0] * sinv;
  al[tid + 256] = p[1] * sinv;
  __syncthreads();
  const int d = tid & 127, og = tid >> 7;
  float acc0 = 0.f, acc1 = 0.f;
  const float* hb = hopeG + ((long)(b * NO) + og * 256) * DOC + d;
  #pragma unroll 8
  for (int i = 0; i < 256; i += 2) {
    acc0 = fmaf(al[og * 256 + i],     hb[(long)i * DOC],       acc0);
    acc1 = fmaf(al[og * 256 + i + 1], hb[(long)(i + 1) * DOC], acc1);
  }
  part[og][d] = acc0 + acc1;
  __syncthreads();
  if (og == 0)
    hmacs[(b * NM + m) * DOC + d] = part[0][d] + part[1][d]
                                   + hmac[(b * NM + m) * DOC + d];
}

// ---------------- mega3: proj v1(256) + gat(512, b-major XCD remap) ----------------
__global__ __launch_bounds__(256) void mega3_kernel(
    const short* __restrict__ x12h, const float* __restrict__ Wp,
    const float* __restrict__ bp, float* __restrict__ hopes,
    const float* __restrict__ adj, const float* __restrict__ ao,
    const float* __restrict__ am, const float* __restrict__ hopeG,
    const float* __restrict__ hmac, float* __restrict__ hmacs) {
  const int blk = blockIdx.x, tid = threadIdx.x;
  if (blk < 256) {
    gemm_hx_body(blk & 1, blk >> 1, tid, x12h, Wp, bp, hopes);
  } else {
    int t = blk - 256;            // t = m*16 + b  -> XCD (t%8) = b%8: all m of a
    gat_body(t & 15, t >> 4, tid, // given b share one XCD's L2 for hopeG/adj
             adj, ao, am, hopeG, hmac, hmacs);
  }
}

// ---------------- pool+up+critic: one block per b (critic math = ex-final2c) ----------------
__device__ void pool_up_body(int b, int tid,
    const float* __restrict__ hopes, const float* __restrict__ hmacs,
    const float* __restrict__ A0, const float* __restrict__ Ab0,
    const float* __restrict__ C0, const float* __restrict__ Cb0,
    const float* __restrict__ C1, const float* __restrict__ Cb1,
    const float* __restrict__ C2, const float* __restrict__ Cb2,
    float* __restrict__ po, float* __restrict__ pm, float* __restrict__ up,
    float* __restrict__ out) {
  __shared__ float part[2][128];
  __shared__ float pos[128], pms[128];
  __shared__ float zc[128];
  __shared__ float scc[2];
  const int j = tid & 127, og = tid >> 7;
  // hopes sum: each og-half covers 256 rows, coalesced 512B row reads
  const float* hb = hopes + ((long)(b * 512) + og * 256) * 128 + j;
  float a0 = 0.f, a1 = 0.f;
  #pragma unroll 8
  for (int i = 0; i < 256; i += 2) {
    a0 += hb[(long)i * 128];
    a1 += hb[(long)(i + 1) * 128];
  }
  part[og][j] = a0 + a1;
  __syncthreads();
  if (og == 0) {
    float s = (part[0][j] + part[1][j]) * (1.0f / 512.0f);
    po[b * 128 + j] = s;
    pos[j] = s;
  } else {
    const float* mb = hmacs + (long)(b * 32) * 128 + j;
    float t0 = 0.f;
    #pragma unroll 8
    for (int i = 0; i < 32; ++i) t0 += mb[(long)i * 128];
    t0 *= (1.0f / 32.0f);
    pm[b * 128 + j] = t0;
    pms[j] = t0;
  }
  __syncthreads();
  if (tid < 128) {
    const float* a1p = A0 + (long)j * 512 + 256;
    const float* a2p = A0 + (long)j * 512 + 384;
    float acc = Ab0[j];
    #pragma unroll 4
    for (int k4 = 0; k4 < 32; ++k4) {
      f32x4 av = *(const f32x4*)(a1p + k4 * 4);
      acc = fmaf(av[0], pos[k4 * 4], acc);
      acc = fmaf(av[1], pos[k4 * 4 + 1], acc);
      acc = fmaf(av[2], pos[k4 * 4 + 2], acc);
      acc = fmaf(av[3], pos[k4 * 4 + 3], acc);
    }
    #pragma unroll 4
    for (int k4 = 0; k4 < 32; ++k4) {
      f32x4 av = *(const f32x4*)(a2p + k4 * 4);
      acc = fmaf(av[0], pms[k4 * 4], acc);
      acc = fmaf(av[1], pms[k4 * 4 + 1], acc);
      acc = fmaf(av[2], pms[k4 * 4 + 2], acc);
      acc = fmaf(av[3], pms[k4 * 4 + 3], acc);
    }
    up[b * 128 + j] = acc;
    // critic layer 1: v = (pos, pms)
    float cacc = Cb0[j];
    for (int k = 0; k < 128; ++k) cacc = fmaf(C0[j * 256 + k], pos[k], cacc);
    for (int k = 0; k < 128; ++k) cacc = fmaf(C0[j * 256 + 128 + k], pms[k], cacc);
    zc[j] = fast_tanh(cacc);
  }
  __syncthreads();
  if (tid < 128) {
    float acc2 = Cb1[j];
    for (int k = 0; k < 128; ++k) acc2 = fmaf(C1[j * 128 + k], zc[k], acc2);
    float z2 = fast_tanh(acc2);
    float p = C2[j] * z2;
    #pragma unroll
    for (int off = 32; off; off >>= 1) p += __shfl_down(p, off);
    const int lane = tid & 63, w = tid >> 6;
    if (lane == 0) scc[w] = p;
  }
  __syncthreads();
  if (tid == 0) out[16 + b] = scc[0] + scc[1] + Cb2[0];   // state_values
}

// ---------------- mega4 v3: pool+up+critic(16) + UoGEMM(256) + UmhmGEMM(16) ----------------
__global__ __launch_bounds__(256) void mega4_kernel(
    const float* __restrict__ hopes, const float* __restrict__ hmacs,
    const float* __restrict__ A0, const float* __restrict__ Ab0,
    const float* __restrict__ C0, const float* __restrict__ Cb0,
    const float* __restrict__ C1, const float* __restrict__ Cb1,
    const float* __restrict__ C2, const float* __restrict__ Cb2,
    float* __restrict__ po, float* __restrict__ pm, float* __restrict__ up,
    float* __restrict__ Uo, float* __restrict__ umhm,
    float* __restrict__ out) {
  const int blk = blockIdx.x, tid = threadIdx.x;
  if (blk < 16) {
    pool_up_body(blk, tid, hopes, hmacs, A0, Ab0, C0, Cb0, C1, Cb1, C2, Cb2,
                 po, pm, up, out);
  } else if (blk < 272) {
    int t = blk - 16;
    gemm_wave_body<1>(t & 1, t >> 1, tid, hopes, A0, nullptr, Uo, 128, 128, 128, 512);
  } else {
    int t = blk - 272;            // M=512 rows of hmacs, W=A0 cols 128:256
    gemm_wave_body<1>(t & 1, t >> 1, tid, hmacs, A0 + 128, nullptr, umhm, 128, 128, 128, 512);
  }
}

// ---------------- actor v10: v9 + last-block-ticket final combine ----------------
// Each b's 256 triples come from 64 blocks; 64th block (ticket) merges them,
// gathers aidx logit, writes action_logprob + entropy. cnt[] zeroed in mega1.
__global__ __launch_bounds__(256) void actor_mfma10_kernel(
    const float* __restrict__ Uo, const float* __restrict__ umhm,
    const float* __restrict__ up, const short* __restrict__ A1p,
    const float* __restrict__ Ab1, const float* __restrict__ A2,
    const float* __restrict__ Ab2, const void* __restrict__ maskp,
    const int* __restrict__ flag, const int* __restrict__ aidx,
    float* __restrict__ logits, float* __restrict__ partw,
    int* __restrict__ cnt, float* __restrict__ out) {
  const int tid = threadIdx.x;
  const int blk = blockIdx.x;
  const int oc = blk & 7;
  const int mg = (blk >> 3) & 7;
  const int b  = blk >> 6;
  const int obase = oc * 64;
  const int m0 = mg * 4;
  const int lane = tid & 63, w = tid >> 6;
  const int rowl = lane & 15, kg = lane >> 4;
  const float* uo = Uo + (long)(b * NO + obase + w * 16 + rowl) * 128;
  const float* upb = up + b * 128;
  const float* umb = umhm + (b * NM + m0) * 128;
  bf16x8 af[4][4];                       // [mi][kk]
  #pragma unroll
  for (int kk = 0; kk < 4; ++kk) {
    int kb = kk * 32 + kg * 8;
    f32x4 u0 = *(const f32x4*)(uo + kb);
    f32x4 u1 = *(const f32x4*)(uo + kb + 4);
    f32x4 p0 = *(const f32x4*)(upb + kb);
    f32x4 p1 = *(const f32x4*)(upb + kb + 4);
    float base0[4], base1[4];
    #pragma unroll
    for (int e = 0; e < 4; ++e) {
      base0[e] = u0[e] + p0[e];
      base1[e] = u1[e] + p1[e];
    }
    #pragma unroll
    for (int mi = 0; mi < 4; ++mi) {
      f32x4 a0 = *(const f32x4*)(umb + mi * 128 + kb);
      f32x4 a1 = *(const f32x4*)(umb + mi * 128 + kb + 4);
      float t[8];
      #pragma unroll
      for (int e = 0; e < 4; ++e) {
        t[e]     = fast_tanh(base0[e] + a0[e]);
        t[4 + e] = fast_tanh(base1[e] + a1[e]);
      }
      af[mi][kk] = pack8f(t);
    }
  }
  float pr[4][4] = {};
  #pragma unroll
  for (int ct = 0; ct < 8; ++ct) {
    const int col = ct * 16 + rowl;
    bf16x8 bf[4];
    #pragma unroll
    for (int kk = 0; kk < 4; ++kk)
      bf[kk] = *(const bf16x8*)(A1p + ((kk * 4 + kg) * 128 + col) * 8);
    f32x4 ac[4] = {};
    #pragma unroll
    for (int kk = 0; kk < 4; ++kk)
      #pragma unroll
      for (int mi = 0; mi < 4; ++mi)
        ac[mi] = __builtin_amdgcn_mfma_f32_16x16x32_bf16(af[mi][kk], bf[kk], ac[mi], 0, 0, 0);
    const float ab = Ab1[col], a2c = A2[col];
    #pragma unroll
    for (int mi = 0; mi < 4; ++mi)
      #pragma unroll
      for (int r = 0; r < 4; ++r) {
        float z = fast_tanh(ac[mi][r] + ab);
        pr[mi][r] = fmaf(a2c, z, pr[mi][r]);
      }
  }
  const float ab2 = Ab2[0];
  // butterfly-reduce; keep all 16 final logits per lane (identical across rowl)
  float rv[4][4];                        // [r][mi]
  #pragma unroll
  for (int r = 0; r < 4; ++r) {
    float v0 = pr[0][r], v1 = pr[1][r], v2 = pr[2][r], v3 = pr[3][r];
    #pragma unroll
    for (int off = 1; off < 16; off <<= 1) {
      v0 += __shfl_xor(v0, off);
      v1 += __shfl_xor(v1, off);
      v2 += __shfl_xor(v2, off);
      v3 += __shfl_xor(v3, off);
    }
    rv[r][0] = v0 + ab2; rv[r][1] = v1 + ab2;
    rv[r][2] = v2 + ab2; rv[r][3] = v3 + ab2;
  }
  const long base0 = ((long)b << 14) + (long)m0 * 512 + obase + w * 16 + kg * 4;
  if (rowl == 0) {
    #pragma unroll
    for (int r = 0; r < 4; ++r) {
      logits[base0 + r]        = rv[r][0];
      logits[base0 + 512 + r]  = rv[r][1];
      logits[base0 + 1024 + r] = rv[r][2];
      logits[base0 + 1536 + r] = rv[r][3];
    }
  }
  // fused masked softmax partial: lane covers o = obase+w*16+kg*4+r, m = m0+mi
  const bool word_mode = (flag[0] == 0);
  const int ob = obase + w * 16 + kg * 4;
  bool mk[4][4];
  if (word_mode) {
    const unsigned int* mw = (const unsigned int*)maskp;
    #pragma unroll
    for (int r = 0; r < 4; ++r) {
      long mo = (long)(b * NO + ob + r) * NM + m0;
      #pragma unroll
      for (int mi = 0; mi < 4; ++mi) mk[r][mi] = (mw[mo + mi] != 0u);
    }
  } else {
    const unsigned char* mb = (const unsigned char*)maskp;
    #pragma unroll
    for (int r = 0; r < 4; ++r) {
      long mo = (long)(b * NO + ob + r) * NM + m0;
      #pragma unroll
      for (int mi = 0; mi < 4; ++mi) mk[r][mi] = (mb[mo + mi] != 0);
    }
  }
  float lm = -1e30f;
  #pragma unroll
  for (int r = 0; r < 4; ++r)
    #pragma unroll
    for (int mi = 0; mi < 4; ++mi)
      if (mk[r][mi]) lm = fmaxf(lm, rv[r][mi]);
  float lS = 0.f, lT = 0.f;
  #pragma unroll
  for (int r = 0; r < 4; ++r)
    #pragma unroll
    for (int mi = 0; mi < 4; ++mi)
      if (mk[r][mi]) {
        float d = rv[r][mi] - lm;
        float e = __expf(d);
        lS += e; lT += e * d;
      }
  // merge across kg groups only (rowl lanes are duplicates)
  #pragma unroll
  for (int off = 16; off < 64; off <<= 1) {
    float om = __shfl_xor(lm, off);
    float oS = __shfl_xor(lS, off);
    float oT = __shfl_xor(lT, off);
    smmerge(lm, lS, lT, om, oS, oT);
  }
  if (lane == 0) {
    float* pp = partw + ((long)blk * 4 + w) * 3;
    pp[0] = lm; pp[1] = lS; pp[2] = lT;
  }
  // ---- last-block ticket: 64th block of this b does the final combine ----
  __shared__ int sdone;
  __syncthreads();                 // all 4 waves' partw stores issued
  if (tid == 0) {
    __threadfence();               // release: partw + logits visible device-wide
    int old = atomicAdd((int*)&cnt[b], 1);
    sdone = (old == 63) ? 1 : 0;
  }
  __syncthreads();
  if (sdone && tid < 64) {
    __threadfence();               // acquire: invalidate caches before reads
    float fm = -3e30f, fS = 0.f, fT = 0.f;
    const float* pp = partw + ((long)b * 256 + tid * 4) * 3;
    #pragma unroll
    for (int t = 0; t < 4; ++t)
      smmerge(fm, fS, fT, pp[t * 3], pp[t * 3 + 1], pp[t * 3 + 2]);
    #pragma unroll
    for (int off = 1; off < 64; off <<= 1) {
      float om = __shfl_xor(fm, off);
      float oS = __shfl_xor(fS, off);
      float oT = __shfl_xor(fT, off);
      smmerge(fm, fS, fT, om, oS, oT);
    }
    if (tid == 0) {
      float lSm = logf(fS);
      out[b] = logits[(long)b * (NM * NO) + aidx[b]] - fm - lSm;  // action_logprobs
      out[32 + b] = lSm - fT / fS;                                // dist_entropys
    }
  }
}

extern "C" void kernel_launch(void* const* d_in, const int* in_sizes, int n_in,
                              void* d_out, int out_size, void* d_ws, size_t ws_size,
                              hipStream_t stream) {
  (void)in_sizes; (void)n_in; (void)out_size; (void)ws_size;
  const float* adj  = (const float*)d_in[0];
  const float* nop  = (const float*)d_in[1];
  const float* nmac = (const float*)d_in[2];
  const void*  maskp = d_in[3];
  const int*   aidx = (const int*)d_in[4];
  const float* Wtr  = (const float*)d_in[5];
  const float* btr  = (const float*)d_in[6];
  const float* W0   = (const float*)d_in[7];
  const float* b0   = (const float*)d_in[8];
  const float* W1   = (const float*)d_in[9];
  const float* b1   = (const float*)d_in[10];
  const float* Wp   = (const float*)d_in[11];
  const float* bp   = (const float*)d_in[12];
  const float* Wo   = (const float*)d_in[13];
  const float* Wm   = (const float*)d_in[14];
  const float* alo  = (const float*)d_in[15];
  const float* alm  = (const float*)d_in[16];
  const float* A0   = (const float*)d_in[17];
  const float* Ab0  = (const float*)d_in[18];
  const float* A1   = (const float*)d_in[19];
  const float* Ab1  = (const float*)d_in[20];
  const float* A2   = (const float*)d_in[21];
  const float* Ab2  = (const float*)d_in[22];
  const float* C0   = (const float*)d_in[23];
  const float* Cb0  = (const float*)d_in[24];
  const float* C1   = (const float*)d_in[25];
  const float* Cb1  = (const float*)d_in[26];
  const float* C2   = (const float*)d_in[27];
  const float* Cb2  = (const float*)d_in[28];

  float* ws     = (float*)d_ws;        // needs ~44 MiB
  short* x12h   = (short*)(ws + OFF_X12);
  float* hopes  = ws + OFF_HOPES;
  float* hopeG  = ws + OFF_HOPEG;
  float* hmac   = ws + OFF_HMAC;
  float* hmacs  = ws + OFF_HMACS;
  float* ao     = ws + OFF_AO;
  float* am     = ws + OFF_AM;
  float* po     = ws + OFF_PO;
  float* pm     = ws + OFF_PM;
  float* Uo     = ws + OFF_UO;
  float* umhm   = ws + OFF_UMHM;
  float* logits = ws + OFF_LOG;
  float* up     = ws + OFF_UP;
  short* A1p    = (short*)(ws + OFF_A1P);
  int*   flag   = (int*)(ws + OFF_FLAG);
  int*   cnt    = (int*)(ws + OFF_CNT);
  float* partw  = ws + OFF_PART2;
  float* outp   = (float*)d_out;

  // 1: trans(MT=4) + hopeG + hmac + A1-convert + mask-probe (+ticket zero)
  mega1_kernel<<<849, 256, 0, stream>>>(nop, Wtr, btr, x12h, Wo, hopeG,
                                        nmac, Wm, hmac, A1, A1p,
                                        (const unsigned int*)maskp, flag, cnt);
  // 2: attention middle (MFMA) + rowdots
  mega2_kernel<<<3200, 256, 0, stream>>>(x12h, W0, b0, W1, b1,
                                         hopeG, alo, ao, hmac, alm, am);
  // 3: proj v1 + gat (b-major XCD remap)
  mega3_kernel<<<768, 256, 0, stream>>>(x12h, Wp, bp, hopes,
                                        adj, ao, am, hopeG, hmac, hmacs);
  // 4: pool+up+critic + Uo GEMM + Um-hmacs GEMM
  mega4_kernel<<<288, 256, 0, stream>>>(hopes, hmacs, A0, Ab0,
                                        C0, Cb0, C1, Cb1, C2, Cb2,
                                        po, pm, up, Uo, umhm, outp);
  // 5: actor v10 (fused softmax partials + last-block final combine)
  actor_mfma10_kernel<<<1024, 256, 0, stream>>>(Uo, umhm, up, A1p, Ab1, A2, Ab2,
                                                maskp, flag, aidx,
                                                logits, partw, cnt, outp);
}

// Round 30
// 138.893 us; speedup vs baseline: 1.1325x; 1.1325x over previous
//
#include <hip/hip_runtime.h>

#define BB 16
#define NO 512
#define NM 32
#define DOC 128
#define C8 1024
#define NH 64
#define KD 16

// ---------------- ws layout (float offsets), ~44 MiB used ----------------
#define OFF_X12   0          // [16][64][512][16] bf16 h-sliced x1/x2 (in-place)
#define OFF_UO    0          // [8192,128] f32 (alias: x12h dead by then)
#define OFF_LOG   1048576    // [16,16384] (alias, after Uo)
#define OFF_HOPES 8388608    // [8192,128] ext-attn output
#define OFF_HOPEG 9437184    // [8192,128] GAT h_ope
#define OFF_HMAC  10485760   // [512,128]  GAT h_mac (pre)
#define OFF_HMACS 10551296   // [512,128]  GAT output
#define OFF_AO    10616832   // [8192]
#define OFF_AM    10625024   // [512]
#define OFF_PO    10625536   // [16,128]
#define OFF_PM    10627584   // [16,128]
#define OFF_UMHM  10629632   // [512,128]  hmacs-part of Um (MFMA)
#define OFF_FLAG  10695168   // int flag (mask dtype probe)
#define OFF_UP    10720000   // [16,128]   Up[b] = A0[:,256:512]*(po,pm)+Ab0
#define OFF_PART2 10750000   // [4096,3] per-wave actor softmax partials
#define OFF_A1P   10900000   // [16384] bf16 A1 pre-converted (OUTSIDE x12h!)

using f32x4  = __attribute__((ext_vector_type(4))) float;
using s16x4  = __attribute__((ext_vector_type(4))) short;
using bf16x8 = __attribute__((ext_vector_type(8))) short;   // 8 bf16 (4 VGPRs)

// clamp-free: exp(2x)->{0,inf} at extremes gives exactly -1/+1 via rcp
__device__ __forceinline__ float fast_tanh(float x) {
  float e = __expf(2.0f * x);
  return 1.0f - 2.0f * __builtin_amdgcn_rcpf(e + 1.0f);
}

__device__ __forceinline__ short f2bf(float f) {          // RNE f32->bf16
  unsigned u = __builtin_bit_cast(unsigned, f);
  u += 0x7FFFu + ((u >> 16) & 1u);
  return (short)(u >> 16);
}

__device__ __forceinline__ float bf2f(short s) {
  return __builtin_bit_cast(float, ((unsigned)(unsigned short)s) << 16);
}

__device__ __forceinline__ unsigned cvtpk(float a, float b) {
  unsigned r;
  asm("v_cvt_pk_bf16_f32 %0, %1, %2" : "=v"(r) : "v"(a), "v"(b));
  return r;
}

__device__ __forceinline__ bf16x8 pack8(f32x4 u0, f32x4 u1) {
  union { unsigned u[4]; bf16x8 v; } cv;
  cv.u[0] = cvtpk(u0[0], u0[1]);
  cv.u[1] = cvtpk(u0[2], u0[3]);
  cv.u[2] = cvtpk(u1[0], u1[1]);
  cv.u[3] = cvtpk(u1[2], u1[3]);
  return cv.v;
}

__device__ __forceinline__ bf16x8 pack8f(const float* t) {
  union { unsigned u[4]; bf16x8 v; } cv;
  cv.u[0] = cvtpk(t[0], t[1]);
  cv.u[1] = cvtpk(t[2], t[3]);
  cv.u[2] = cvtpk(t[4], t[5]);
  cv.u[3] = cvtpk(t[6], t[7]);
  return cv.v;
}

// online-softmax partial merge: (Ma,Sa,Ta) += (Mb,Sb,Tb)
__device__ __forceinline__ void smmerge(float& lm, float& lS, float& lT,
                                        float om, float oS, float oT) {
  float nm = fmaxf(lm, om);
  float ea = __expf(lm - nm), eb = __expf(om - nm);
  lT = (lT + (lm - nm) * lS) * ea + (oT + (om - nm) * oS) * eb;
  lS = lS * ea + oS * eb;
  lm = nm;
}

// ---------------- mask dtype probe (body) ----------------
__device__ void probe_body(int tid, const unsigned int* __restrict__ mask,
                           int* __restrict__ flag) {
  __shared__ int s[4];
  int bad = 0;
  for (int i = tid; i < 4096; i += 256) {
    unsigned int v = mask[i];
    if (!(v == 0u || v == 1u || v == 0x3f800000u)) bad = 1;
  }
  unsigned long long any = __ballot(bad);
  int lane = tid & 63, w = tid >> 6;
  if (lane == 0) s[w] = (any != 0ull) ? 1 : 0;
  __syncthreads();
  if (tid == 0) flag[0] = s[0] | s[1] | s[2] | s[3];
}

// ---------------- GEMM bodies (verbatim, verified) ----------------
template<int MT>
__device__ __forceinline__ void loadk(const float* xb, const float* wb,
                                      long sx, long sw, int k0,
                                      f32x4 (&xa)[MT][2], f32x4 (&wa)[4][2]) {
  #pragma unroll
  for (int mi = 0; mi < MT; ++mi) {
    xa[mi][0] = *(const f32x4*)(xb + mi * sx + k0);
    xa[mi][1] = *(const f32x4*)(xb + mi * sx + k0 + 4);
  }
  #pragma unroll
  for (int ni = 0; ni < 4; ++ni) {
    wa[ni][0] = *(const f32x4*)(wb + ni * sw + k0);
    wa[ni][1] = *(const f32x4*)(wb + ni * sw + k0 + 4);
  }
}

template<int MT>
__device__ __forceinline__ void consume(f32x4 (&xa)[MT][2], f32x4 (&wa)[4][2],
                                        f32x4 (&acc)[MT][4]) {
  bf16x8 bfr[4];
  #pragma unroll
  for (int ni = 0; ni < 4; ++ni) bfr[ni] = pack8(wa[ni][0], wa[ni][1]);
  #pragma unroll
  for (int mi = 0; mi < MT; ++mi) {
    bf16x8 af = pack8(xa[mi][0], xa[mi][1]);
    #pragma unroll
    for (int ni = 0; ni < 4; ++ni)
      acc[mi][ni] = __builtin_amdgcn_mfma_f32_16x16x32_bf16(af, bfr[ni], acc[mi][ni], 0, 0, 0);
  }
}

template<int MT>
__device__ void gemm_wave_body(int bx, int by, int tid,
    const float* __restrict__ X, const float* __restrict__ W,
    const float* __restrict__ bias, float* __restrict__ C,
    int N, int Kdim, int ldx, int ldw) {
  const int lane = tid & 63, w = tid >> 6;
  const int rowl = lane & 15, kg = lane >> 4;
  const int n0 = bx * 64;
  const int m0 = (by * 4 + w) * (MT * 16);
  const float* xb = X + (long)(m0 + rowl) * ldx + kg * 8;
  const float* wb = W + (long)(n0 + rowl) * ldw + kg * 8;
  const long sx = (long)16 * ldx, sw = (long)16 * ldw;
  f32x4 acc[MT][4] = {};
  f32x4 A0[MT][2], B0[4][2], A1[MT][2], B1[4][2];
  loadk<MT>(xb, wb, sx, sw, 0, A0, B0);
  for (int k = 0; k < Kdim; k += 64) {
    loadk<MT>(xb, wb, sx, sw, k + 32, A1, B1);
    consume<MT>(A0, B0, acc);
    if (k + 64 < Kdim) loadk<MT>(xb, wb, sx, sw, k + 64, A0, B0);
    consume<MT>(A1, B1, acc);
  }
  #pragma unroll
  for (int mi = 0; mi < MT; ++mi) {
    #pragma unroll
    for (int ni = 0; ni < 4; ++ni) {
      int col = n0 + ni * 16 + rowl;
      float bv = bias ? bias[col] : 0.0f;
      int rb = m0 + mi * 16 + kg * 4;
      #pragma unroll
      for (int r = 0; r < 4; ++r)
        C[(long)(rb + r) * N + col] = acc[mi][ni][r] + bv;
    }
  }
}

// trans GEMM body: f32 in, bf16 h-sliced out.
template<int MT>
__device__ void gemm_ht_body(int bx, int by, int tid,
    const float* __restrict__ X, const float* __restrict__ W,
    const float* __restrict__ bias, short* __restrict__ Ch,
    int Kdim, int ldx, int ldw) {
  const int lane = tid & 63, w = tid >> 6;
  const int rowl = lane & 15, kg = lane >> 4;
  const int n0 = bx * 64;
  const int m0 = (by * 4 + w) * (MT * 16);
  const float* xb = X + (long)(m0 + rowl) * ldx + kg * 8;
  const float* wb = W + (long)(n0 + rowl) * ldw + kg * 8;
  const long sx = (long)16 * ldx, sw = (long)16 * ldw;
  f32x4 acc[MT][4] = {};
  f32x4 A0[MT][2], B0[4][2], A1[MT][2], B1[4][2];
  loadk<MT>(xb, wb, sx, sw, 0, A0, B0);
  for (int k = 0; k < Kdim; k += 64) {
    loadk<MT>(xb, wb, sx, sw, k + 32, A1, B1);
    consume<MT>(A0, B0, acc);
    if (k + 64 < Kdim) loadk<MT>(xb, wb, sx, sw, k + 64, A0, B0);
    consume<MT>(A1, B1, acc);
  }
  #pragma unroll
  for (int mi = 0; mi < MT; ++mi) {
    #pragma unroll
    for (int ni = 0; ni < 4; ++ni) {
      int col = n0 + ni * 16 + rowl;
      float bv = bias ? bias[col] : 0.0f;
      int h = col >> 4, e = col & 15;
      int rb = m0 + mi * 16 + kg * 4;
      #pragma unroll
      for (int r = 0; r < 4; ++r) {
        int rowI = rb + r;
        int b = rowI >> 9, n = rowI & 511;
        Ch[((long)(b * 64 + h) * 512 + n) * 16 + e] = f2bf(acc[mi][ni][r] + bv);
      }
    }
  }
}

__device__ void convert_a1_body(int blk, int tid,
    const float* __restrict__ A1, short* __restrict__ A1p) {
  int i = blk * 256 + tid;
  int col = i >> 7, k = i & 127;
  A1p[((k >> 3) * 128 + col) * 8 + (k & 7)] = f2bf(A1[i]);
}

// ---------------- mega1: trans MT=4 (512) + hopeG(256) + hmac(16) + convertA1(64) + probe(1) ----------------
__global__ __launch_bounds__(256) void mega1_kernel(
    const float* __restrict__ nop, const float* __restrict__ Wtr,
    const float* __restrict__ btr, short* __restrict__ x12h,
    const float* __restrict__ Wo, float* __restrict__ hopeG,
    const float* __restrict__ nmac, const float* __restrict__ Wm,
    float* __restrict__ hmac,
    const float* __restrict__ A1, short* __restrict__ A1p,
    const unsigned int* __restrict__ mask, int* __restrict__ flag) {
  const int blk = blockIdx.x, tid = threadIdx.x;
  if (blk < 512) {
    gemm_ht_body<4>(blk & 15, blk >> 4, tid, nop, Wtr, btr, x12h, 128, 128, 128);
  } else if (blk < 768) {
    int t = blk - 512;
    gemm_wave_body<1>(t & 1, t >> 1, tid, nop, Wo, nullptr, hopeG, 128, 128, 128, 128);
  } else if (blk < 784) {
    int t = blk - 768;
    gemm_wave_body<1>(t & 1, t >> 1, tid, nmac, Wm, nullptr, hmac, 128, 64, 64, 64);
  } else if (blk < 848) {
    convert_a1_body(blk - 784, tid, A1, A1p);
  } else {
    probe_body(tid, mask, flag);
  }
}

// ---------------- attn v3: MFMA-based (verified r23/r24) ----------------
__device__ void attn3_body(int b, int h, int tid, short* __restrict__ x12h,
    const float* __restrict__ W0, const float* __restrict__ b0,
    const float* __restrict__ W1, const float* __restrict__ b1) {
  __shared__ short Pb[4][128 * 16];      // 16 KB
  __shared__ float cmw[4][16], csw[4][16];
  const int wq = tid >> 6, lane = tid & 63;
  const int rowl = lane & 15, kg = lane >> 4;
  short* slice = x12h + (long)(b * 64 + h) * 8192;
  const short* wrows = slice + (long)(wq * 128) * 16;
  const bf16x8 zero8 = {};
  bf16x8 xa[8];
  #pragma unroll
  for (int t = 0; t < 8; ++t) {
    if (kg < 2)
      xa[t] = *(const bf16x8*)(wrows + (t * 16 + rowl) * 16 + kg * 8);
    else
      xa[t] = zero8;
  }
  bf16x8 w0f = zero8;
  if (kg < 2) {
    f32x4 a = *(const f32x4*)(W0 + rowl * 16 + kg * 8);
    f32x4 c = *(const f32x4*)(W0 + rowl * 16 + kg * 8 + 4);
    w0f = pack8(a, c);
  }
  const float b0v = b0[rowl];
  f32x4 acc[8];
  #pragma unroll
  for (int t = 0; t < 8; ++t) {
    f32x4 z = {0.f, 0.f, 0.f, 0.f};
    acc[t] = __builtin_amdgcn_mfma_f32_16x16x32_bf16(xa[t], w0f, z, 0, 0, 0);
  }
  float m = -1e30f;
  #pragma unroll
  for (int t = 0; t < 8; ++t)
    #pragma unroll
    for (int r = 0; r < 4; ++r) {
      acc[t][r] += b0v;
      m = fmaxf(m, acc[t][r]);
    }
  m = fmaxf(m, __shfl_xor(m, 16));
  m = fmaxf(m, __shfl_xor(m, 32));
  if (lane < 16) cmw[wq][lane] = m;
  __syncthreads();
  const float cm = fmaxf(fmaxf(cmw[0][rowl], cmw[1][rowl]),
                         fmaxf(cmw[2][rowl], cmw[3][rowl]));
  float s = 0.f;
  #pragma unroll
  for (int t = 0; t < 8; ++t)
    #pragma unroll
    for (int r = 0; r < 4; ++r) {
      float e = __expf(acc[t][r] - cm);
      acc[t][r] = e;
      s += e;
    }
  s += __shfl_xor(s, 16);
  s += __shfl_xor(s, 32);
  if (lane < 16) csw[wq][lane] = s;
  __syncthreads();
  const float cs = csw[0][rowl] + csw[1][rowl] + csw[2][rowl] + csw[3][rowl];
  const float cinv = 1.0f / cs;
  short* pbw = Pb[wq];
  #pragma unroll
  for (int t = 0; t < 8; ++t)
    #pragma unroll
    for (int r = 0; r < 4; ++r) {
      float al = acc[t][r] * cinv;
      float rsv = al;
      rsv += __shfl_xor(rsv, 1);
      rsv += __shfl_xor(rsv, 2);
      rsv += __shfl_xor(rsv, 4);
      rsv += __shfl_xor(rsv, 8);
      float pf = al / (1e-10f + rsv);
      pbw[(t * 16 + kg * 4 + r) * 16 + rowl] = f2bf(pf);
    }
  __syncthreads();
  bf16x8 w1f = zero8;
  if (kg < 2) {
    f32x4 a = *(const f32x4*)(W1 + rowl * 16 + kg * 8);
    f32x4 c = *(const f32x4*)(W1 + rowl * 16 + kg * 8 + 4);
    w1f = pack8(a, c);
  }
  const float b1v = b1[rowl];
  #pragma unroll
  for (int t = 0; t < 8; ++t) {
    bf16x8 pa = zero8;
    if (kg < 2)
      pa = *(const bf16x8*)(pbw + (t * 16 + rowl) * 16 + kg * 8);
    f32x4 z = {0.f, 0.f, 0.f, 0.f};
    f32x4 oacc = __builtin_amdgcn_mfma_f32_16x16x32_bf16(pa, w1f, z, 0, 0, 0);
    #pragma unroll
    for (int r = 0; r < 4; ++r) {
      int n = wq * 128 + t * 16 + kg * 4 + r;
      slice[(long)n * 16 + rowl] = f2bf(oacc[r] + b1v);
    }
  }
}

// ---------------- mega2: attn3(1024) + rowdot2(2176) ----------------
__global__ __launch_bounds__(256) void mega2_kernel(
    short* __restrict__ x12h,
    const float* __restrict__ W0, const float* __restrict__ b0,
    const float* __restrict__ W1, const float* __restrict__ b1,
    const float* __restrict__ hopeG, const float* __restrict__ alo,
    float* __restrict__ ao,
    const float* __restrict__ hmac, const float* __restrict__ alm,
    float* __restrict__ am) {
  const int blk = blockIdx.x, tid = threadIdx.x;
  if (blk < 1024) {
    attn3_body(blk >> 6, blk & 63, tid, x12h, W0, b0, W1, b1);
  } else {
    int t = blk - 1024;
    int wid = t * 4 + (tid >> 6);
    int lane = tid & 63;
    const float* X; const float* al; float* out; int r;
    if (wid < 8192)       { X = hopeG; al = alo; out = ao; r = wid; }
    else if (wid < 8704)  { X = hmac;  al = alm; out = am; r = wid - 8192; }
    else return;
    const float* row = X + (long)r * 128;
    float v = fmaf(row[lane], al[lane], row[lane + 64] * al[lane + 64]);
    #pragma unroll
    for (int off = 32; off; off >>= 1) v += __shfl_down(v, off);
    if (lane == 0) out[r] = v;
  }
}

// ---------------- proj GEMM body v1 (verified r15-r24) ----------------
__device__ void gemm_hx_body(int bx, int by, int tid,
    const short* __restrict__ Xh, const float* __restrict__ W,
    const float* __restrict__ bias, float* __restrict__ C) {
  const int lane = tid & 63, w = tid >> 6;
  const int rowl = lane & 15, kg = lane >> 4;
  const int n0 = bx * 64;
  const int m0 = (by * 4 + w) * 16;
  const int row = m0 + rowl, b = row >> 9, n = row & 511;
  const short* xb = Xh + (long)b * 524288 + (long)n * 16 + (kg & 1) * 8;
  const long hofs = kg >> 1;
  const float* wb = W + (long)(n0 + rowl) * 1024 + kg * 8;
  const long sw = 16 * 1024L;
  f32x4 acc[4] = {};
  bf16x8 A0, A1;
  f32x4 Wb0[4][2], Wb1[4][2];
  A0 = *(const bf16x8*)(xb + hofs * 8192);
  #pragma unroll
  for (int ni = 0; ni < 4; ++ni) {
    Wb0[ni][0] = *(const f32x4*)(wb + ni * sw);
    Wb0[ni][1] = *(const f32x4*)(wb + ni * sw + 4);
  }
  for (int k = 0; k < 1024; k += 64) {
    A1 = *(const bf16x8*)(xb + (((k + 32) >> 4) + hofs) * 8192);
    #pragma unroll
    for (int ni = 0; ni < 4; ++ni) {
      Wb1[ni][0] = *(const f32x4*)(wb + ni * sw + k + 32);
      Wb1[ni][1] = *(const f32x4*)(wb + ni * sw + k + 36);
    }
    #pragma unroll
    for (int ni = 0; ni < 4; ++ni) {
      bf16x8 bfr = pack8(Wb0[ni][0], Wb0[ni][1]);
      acc[ni] = __builtin_amdgcn_mfma_f32_16x16x32_bf16(A0, bfr, acc[ni], 0, 0, 0);
    }
    if (k + 64 < 1024) {
      A0 = *(const bf16x8*)(xb + (((k + 64) >> 4) + hofs) * 8192);
      #pragma unroll
      for (int ni = 0; ni < 4; ++ni) {
        Wb0[ni][0] = *(const f32x4*)(wb + ni * sw + k + 64);
        Wb0[ni][1] = *(const f32x4*)(wb + ni * sw + k + 68);
      }
    }
    #pragma unroll
    for (int ni = 0; ni < 4; ++ni) {
      bf16x8 bfr = pack8(Wb1[ni][0], Wb1[ni][1]);
      acc[ni] = __builtin_amdgcn_mfma_f32_16x16x32_bf16(A1, bfr, acc[ni], 0, 0, 0);
    }
  }
  #pragma unroll
  for (int ni = 0; ni < 4; ++ni) {
    int col = n0 + ni * 16 + rowl;
    float bv = bias ? bias[col] : 0.0f;
    int rb = m0 + kg * 4;
    #pragma unroll
    for (int r = 0; r < 4; ++r)
      C[(long)(rb + r) * 128 + col] = acc[ni][r] + bv;
  }
}

// ---------------- GAT body: 256 threads, 2 o's/thread (verified) ----------------
__device__ void gat_body(int b, int m, int tid,
    const float* __restrict__ adj, const float* __restrict__ ao,
    const float* __restrict__ am, const float* __restrict__ hopeG,
    const float* __restrict__ hmac, float* __restrict__ hmacs) {
  __shared__ float al[NO];
  __shared__ float redA[4], redB[4];
  __shared__ float part[2][128];
  const int lane = tid & 63, w = tid >> 6;
  const float amv = am[b * NM + m];
  float av[2], ev[2];
  float mx = -1e30f;
  #pragma unroll
  for (int i = 0; i < 2; ++i) {
    int o = tid + i * 256;
    float a = adj[(b * NO + o) * NM + m];
    float e = ao[b * NO + o] + amv;
    e = (e >= 0.f) ? e : 0.2f * e;
    av[i] = a; ev[i] = e;
    if (a == 1.0f) mx = fmaxf(mx, e);
  }
  #pragma unroll
  for (int off = 32; off; off >>= 1) mx = fmaxf(mx, __shfl_down(mx, off));
  if (lane == 0) redA[w] = mx;
  __syncthreads();
  mx = fmaxf(fmaxf(redA[0], redA[1]), fmaxf(redA[2], redA[3]));
  float p[2], s = 0.f;
  #pragma unroll
  for (int i = 0; i < 2; ++i) {
    p[i] = (av[i] == 1.0f) ? __expf(ev[i] - mx) : 0.f;
    s += p[i];
  }
  #pragma unroll
  for (int off = 32; off; off >>= 1) s += __shfl_down(s, off);
  if (lane == 0) redB[w] = s;
  __syncthreads();
  s = redB[0] + redB[1] + redB[2] + redB[3];
  const float sinv = (s > 0.f) ? 1.0f / s : 0.f;
  al[tid] = p[0] * sinv;
  al[tid + 256] = p[1] * sinv;
  __syncthreads();
  const int d = tid & 127, og = tid >> 7;
  float acc0 = 0.f, acc1 = 0.f;
  const float* hb = hopeG + ((long)(b * NO) + og * 256) * DOC + d;
  #pragma unroll 8
  for (int i = 0; i < 256; i += 2) {
    acc0 = fmaf(al[og * 256 + i],     hb[(long)i * DOC],       acc0);
    acc1 = fmaf(al[og * 256 + i + 1], hb[(long)(i + 1) * DOC], acc1);
  }
  part[og][d] = acc0 + acc1;
  __syncthreads();
  if (og == 0)
    hmacs[(b * NM + m) * DOC + d] = part[0][d] + part[1][d]
                                   + hmac[(b * NM + m) * DOC + d];
}

// ---------------- mega3: proj v1(256) + gat(512, b-major XCD remap) ----------------
__global__ __launch_bounds__(256) void mega3_kernel(
    const short* __restrict__ x12h, const float* __restrict__ Wp,
    const float* __restrict__ bp, float* __restrict__ hopes,
    const float* __restrict__ adj, const float* __restrict__ ao,
    const float* __restrict__ am, const float* __restrict__ hopeG,
    const float* __restrict__ hmac, float* __restrict__ hmacs) {
  const int blk = blockIdx.x, tid = threadIdx.x;
  if (blk < 256) {
    gemm_hx_body(blk & 1, blk >> 1, tid, x12h, Wp, bp, hopes);
  } else {
    int t = blk - 256;            // t = m*16 + b  -> XCD (t%8) = b%8: all m of a
    gat_body(t & 15, t >> 4, tid, // given b share one XCD's L2 for hopeG/adj
             adj, ao, am, hopeG, hmac, hmacs);
  }
}

// ---------------- pool+up+critic: one block per b (verified r29 interior) ----------------
__device__ void pool_up_body(int b, int tid,
    const float* __restrict__ hopes, const float* __restrict__ hmacs,
    const float* __restrict__ A0, const float* __restrict__ Ab0,
    const float* __restrict__ C0, const float* __restrict__ Cb0,
    const float* __restrict__ C1, const float* __restrict__ Cb1,
    const float* __restrict__ C2, const float* __restrict__ Cb2,
    float* __restrict__ po, float* __restrict__ pm, float* __restrict__ up,
    float* __restrict__ out) {
  __shared__ float part[2][128];
  __shared__ float pos[128], pms[128];
  __shared__ float zc[128];
  __shared__ float scc[2];
  const int j = tid & 127, og = tid >> 7;
  // hopes sum: each og-half covers 256 rows, coalesced 512B row reads
  const float* hb = hopes + ((long)(b * 512) + og * 256) * 128 + j;
  float a0 = 0.f, a1 = 0.f;
  #pragma unroll 8
  for (int i = 0; i < 256; i += 2) {
    a0 += hb[(long)i * 128];
    a1 += hb[(long)(i + 1) * 128];
  }
  part[og][j] = a0 + a1;
  __syncthreads();
  if (og == 0) {
    float s = (part[0][j] + part[1][j]) * (1.0f / 512.0f);
    po[b * 128 + j] = s;
    pos[j] = s;
  } else {
    const float* mb = hmacs + (long)(b * 32) * 128 + j;
    float t0 = 0.f;
    #pragma unroll 8
    for (int i = 0; i < 32; ++i) t0 += mb[(long)i * 128];
    t0 *= (1.0f / 32.0f);
    pm[b * 128 + j] = t0;
    pms[j] = t0;
  }
  __syncthreads();
  if (tid < 128) {
    const float* a1p = A0 + (long)j * 512 + 256;
    const float* a2p = A0 + (long)j * 512 + 384;
    float acc = Ab0[j];
    #pragma unroll 4
    for (int k4 = 0; k4 < 32; ++k4) {
      f32x4 av = *(const f32x4*)(a1p + k4 * 4);
      acc = fmaf(av[0], pos[k4 * 4], acc);
      acc = fmaf(av[1], pos[k4 * 4 + 1], acc);
      acc = fmaf(av[2], pos[k4 * 4 + 2], acc);
      acc = fmaf(av[3], pos[k4 * 4 + 3], acc);
    }
    #pragma unroll 4
    for (int k4 = 0; k4 < 32; ++k4) {
      f32x4 av = *(const f32x4*)(a2p + k4 * 4);
      acc = fmaf(av[0], pms[k4 * 4], acc);
      acc = fmaf(av[1], pms[k4 * 4 + 1], acc);
      acc = fmaf(av[2], pms[k4 * 4 + 2], acc);
      acc = fmaf(av[3], pms[k4 * 4 + 3], acc);
    }
    up[b * 128 + j] = acc;
    // critic layer 1: v = (pos, pms)
    float cacc = Cb0[j];
    for (int k = 0; k < 128; ++k) cacc = fmaf(C0[j * 256 + k], pos[k], cacc);
    for (int k = 0; k < 128; ++k) cacc = fmaf(C0[j * 256 + 128 + k], pms[k], cacc);
    zc[j] = fast_tanh(cacc);
  }
  __syncthreads();
  if (tid < 128) {
    float acc2 = Cb1[j];
    for (int k = 0; k < 128; ++k) acc2 = fmaf(C1[j * 128 + k], zc[k], acc2);
    float z2 = fast_tanh(acc2);
    float p = C2[j] * z2;
    #pragma unroll
    for (int off = 32; off; off >>= 1) p += __shfl_down(p, off);
    const int lane = tid & 63, w = tid >> 6;
    if (lane == 0) scc[w] = p;
  }
  __syncthreads();
  if (tid == 0) out[16 + b] = scc[0] + scc[1] + Cb2[0];   // state_values
}

// ---------------- mega4 v3: pool+up+critic(16) + UoGEMM(256) + UmhmGEMM(16) ----------------
__global__ __launch_bounds__(256) void mega4_kernel(
    const float* __restrict__ hopes, const float* __restrict__ hmacs,
    const float* __restrict__ A0, const float* __restrict__ Ab0,
    const float* __restrict__ C0, const float* __restrict__ Cb0,
    const float* __restrict__ C1, const float* __restrict__ Cb1,
    const float* __restrict__ C2, const float* __restrict__ Cb2,
    float* __restrict__ po, float* __restrict__ pm, float* __restrict__ up,
    float* __restrict__ Uo, float* __restrict__ umhm,
    float* __restrict__ out) {
  const int blk = blockIdx.x, tid = threadIdx.x;
  if (blk < 16) {
    pool_up_body(blk, tid, hopes, hmacs, A0, Ab0, C0, Cb0, C1, Cb1, C2, Cb2,
                 po, pm, up, out);
  } else if (blk < 272) {
    int t = blk - 16;
    gemm_wave_body<1>(t & 1, t >> 1, tid, hopes, A0, nullptr, Uo, 128, 128, 128, 512);
  } else {
    int t = blk - 272;            // M=512 rows of hmacs, W=A0 cols 128:256
    gemm_wave_body<1>(t & 1, t >> 1, tid, hmacs, A0 + 128, nullptr, umhm, 128, 128, 128, 512);
  }
}

// ---------------- actor v9: fused per-wave masked softmax partials (verified r27/r28) ----------------
__global__ __launch_bounds__(256) void actor_mfma9_kernel(
    const float* __restrict__ Uo, const float* __restrict__ umhm,
    const float* __restrict__ up, const short* __restrict__ A1p,
    const float* __restrict__ Ab1, const float* __restrict__ A2,
    const float* __restrict__ Ab2, const void* __restrict__ maskp,
    const int* __restrict__ flag, float* __restrict__ logits,
    float* __restrict__ partw) {
  const int tid = threadIdx.x;
  const int blk = blockIdx.x;
  const int oc = blk & 7;
  const int mg = (blk >> 3) & 7;
  const int b  = blk >> 6;
  const int obase = oc * 64;
  const int m0 = mg * 4;
  const int lane = tid & 63, w = tid >> 6;
  const int rowl = lane & 15, kg = lane >> 4;
  const float* uo = Uo + (long)(b * NO + obase + w * 16 + rowl) * 128;
  const float* upb = up + b * 128;
  const float* umb = umhm + (b * NM + m0) * 128;
  bf16x8 af[4][4];                       // [mi][kk]
  #pragma unroll
  for (int kk = 0; kk < 4; ++kk) {
    int kb = kk * 32 + kg * 8;
    f32x4 u0 = *(const f32x4*)(uo + kb);
    f32x4 u1 = *(const f32x4*)(uo + kb + 4);
    f32x4 p0 = *(const f32x4*)(upb + kb);
    f32x4 p1 = *(const f32x4*)(upb + kb + 4);
    float base0[4], base1[4];
    #pragma unroll
    for (int e = 0; e < 4; ++e) {
      base0[e] = u0[e] + p0[e];
      base1[e] = u1[e] + p1[e];
    }
    #pragma unroll
    for (int mi = 0; mi < 4; ++mi) {
      f32x4 a0 = *(const f32x4*)(umb + mi * 128 + kb);
      f32x4 a1 = *(const f32x4*)(umb + mi * 128 + kb + 4);
      float t[8];
      #pragma unroll
      for (int e = 0; e < 4; ++e) {
        t[e]     = fast_tanh(base0[e] + a0[e]);
        t[4 + e] = fast_tanh(base1[e] + a1[e]);
      }
      af[mi][kk] = pack8f(t);
    }
  }
  float pr[4][4] = {};
  #pragma unroll
  for (int ct = 0; ct < 8; ++ct) {
    const int col = ct * 16 + rowl;
    bf16x8 bf[4];
    #pragma unroll
    for (int kk = 0; kk < 4; ++kk)
      bf[kk] = *(const bf16x8*)(A1p + ((kk * 4 + kg) * 128 + col) * 8);
    f32x4 ac[4] = {};
    #pragma unroll
    for (int kk = 0; kk < 4; ++kk)
      #pragma unroll
      for (int mi = 0; mi < 4; ++mi)
        ac[mi] = __builtin_amdgcn_mfma_f32_16x16x32_bf16(af[mi][kk], bf[kk], ac[mi], 0, 0, 0);
    const float ab = Ab1[col], a2c = A2[col];
    #pragma unroll
    for (int mi = 0; mi < 4; ++mi)
      #pragma unroll
      for (int r = 0; r < 4; ++r) {
        float z = fast_tanh(ac[mi][r] + ab);
        pr[mi][r] = fmaf(a2c, z, pr[mi][r]);
      }
  }
  const float ab2 = Ab2[0];
  // butterfly-reduce; keep all 16 final logits per lane (identical across rowl)
  float rv[4][4];                        // [r][mi]
  #pragma unroll
  for (int r = 0; r < 4; ++r) {
    float v0 = pr[0][r], v1 = pr[1][r], v2 = pr[2][r], v3 = pr[3][r];
    #pragma unroll
    for (int off = 1; off < 16; off <<= 1) {
      v0 += __shfl_xor(v0, off);
      v1 += __shfl_xor(v1, off);
      v2 += __shfl_xor(v2, off);
      v3 += __shfl_xor(v3, off);
    }
    rv[r][0] = v0 + ab2; rv[r][1] = v1 + ab2;
    rv[r][2] = v2 + ab2; rv[r][3] = v3 + ab2;
  }
  const long base0 = ((long)b << 14) + (long)m0 * 512 + obase + w * 16 + kg * 4;
  if (rowl == 0) {
    #pragma unroll
    for (int r = 0; r < 4; ++r) {
      logits[base0 + r]        = rv[r][0];
      logits[base0 + 512 + r]  = rv[r][1];
      logits[base0 + 1024 + r] = rv[r][2];
      logits[base0 + 1536 + r] = rv[r][3];
    }
  }
  // fused masked softmax partial: lane covers o = obase+w*16+kg*4+r, m = m0+mi
  const bool word_mode = (flag[0] == 0);
  const int ob = obase + w * 16 + kg * 4;
  bool mk[4][4];
  if (word_mode) {
    const unsigned int* mw = (const unsigned int*)maskp;
    #pragma unroll
    for (int r = 0; r < 4; ++r) {
      long mo = (long)(b * NO + ob + r) * NM + m0;
      #pragma unroll
      for (int mi = 0; mi < 4; ++mi) mk[r][mi] = (mw[mo + mi] != 0u);
    }
  } else {
    const unsigned char* mb = (const unsigned char*)maskp;
    #pragma unroll
    for (int r = 0; r < 4; ++r) {
      long mo = (long)(b * NO + ob + r) * NM + m0;
      #pragma unroll
      for (int mi = 0; mi < 4; ++mi) mk[r][mi] = (mb[mo + mi] != 0);
    }
  }
  float lm = -1e30f;
  #pragma unroll
  for (int r = 0; r < 4; ++r)
    #pragma unroll
    for (int mi = 0; mi < 4; ++mi)
      if (mk[r][mi]) lm = fmaxf(lm, rv[r][mi]);
  float lS = 0.f, lT = 0.f;
  #pragma unroll
  for (int r = 0; r < 4; ++r)
    #pragma unroll
    for (int mi = 0; mi < 4; ++mi)
      if (mk[r][mi]) {
        float d = rv[r][mi] - lm;
        float e = __expf(d);
        lS += e; lT += e * d;
      }
  // merge across kg groups only (rowl lanes are duplicates)
  #pragma unroll
  for (int off = 16; off < 64; off <<= 1) {
    float om = __shfl_xor(lm, off);
    float oS = __shfl_xor(lS, off);
    float oT = __shfl_xor(lT, off);
    smmerge(lm, lS, lT, om, oS, oT);
  }
  if (lane == 0) {
    float* pp = partw + ((long)blk * 4 + w) * 3;
    pp[0] = lm; pp[1] = lS; pp[2] = lT;
  }
}

// ---------------- final_ab: 256-triple combine + gather + entropy (16 blocks x 64) ----------------
__global__ __launch_bounds__(64) void final_ab_kernel(
    const float* __restrict__ part, const float* __restrict__ logits,
    const int* __restrict__ aidx, float* __restrict__ out) {
  const int b = blockIdx.x;
  const int lane = threadIdx.x;
  float lm = -3e30f, lS = 0.f, lT = 0.f;
  const float* pp = part + ((long)b * 256 + lane * 4) * 3;
  #pragma unroll
  for (int t = 0; t < 4; ++t)
    smmerge(lm, lS, lT, pp[t * 3], pp[t * 3 + 1], pp[t * 3 + 2]);
  #pragma unroll
  for (int off = 1; off < 64; off <<= 1) {
    float om = __shfl_xor(lm, off);
    float oS = __shfl_xor(lS, off);
    float oT = __shfl_xor(lT, off);
    smmerge(lm, lS, lT, om, oS, oT);
  }
  if (lane == 0) {
    float lSm = logf(lS);
    out[b] = logits[(long)b * (NM * NO) + aidx[b]] - lm - lSm;  // action_logprobs
    out[32 + b] = lSm - lT / lS;                                // dist_entropys
  }
}

extern "C" void kernel_launch(void* const* d_in, const int* in_sizes, int n_in,
                              void* d_out, int out_size, void* d_ws, size_t ws_size,
                              hipStream_t stream) {
  (void)in_sizes; (void)n_in; (void)out_size; (void)ws_size;
  const float* adj  = (const float*)d_in[0];
  const float* nop  = (const float*)d_in[1];
  const float* nmac = (const float*)d_in[2];
  const void*  maskp = d_in[3];
  const int*   aidx = (const int*)d_in[4];
  const float* Wtr  = (const float*)d_in[5];
  const float* btr  = (const float*)d_in[6];
  const float* W0   = (const float*)d_in[7];
  const float* b0   = (const float*)d_in[8];
  const float* W1   = (const float*)d_in[9];
  const float* b1   = (const float*)d_in[10];
  const float* Wp   = (const float*)d_in[11];
  const float* bp   = (const float*)d_in[12];
  const float* Wo   = (const float*)d_in[13];
  const float* Wm   = (const float*)d_in[14];
  const float* alo  = (const float*)d_in[15];
  const float* alm  = (const float*)d_in[16];
  const float* A0   = (const float*)d_in[17];
  const float* Ab0  = (const float*)d_in[18];
  const float* A1   = (const float*)d_in[19];
  const float* Ab1  = (const float*)d_in[20];
  const float* A2   = (const float*)d_in[21];
  const float* Ab2  = (const float*)d_in[22];
  const float* C0   = (const float*)d_in[23];
  const float* Cb0  = (const float*)d_in[24];
  const float* C1   = (const float*)d_in[25];
  const float* Cb1  = (const float*)d_in[26];
  const float* C2   = (const float*)d_in[27];
  const float* Cb2  = (const float*)d_in[28];

  float* ws     = (float*)d_ws;        // needs ~44 MiB
  short* x12h   = (short*)(ws + OFF_X12);
  float* hopes  = ws + OFF_HOPES;
  float* hopeG  = ws + OFF_HOPEG;
  float* hmac   = ws + OFF_HMAC;
  float* hmacs  = ws + OFF_HMACS;
  float* ao     = ws + OFF_AO;
  float* am     = ws + OFF_AM;
  float* po     = ws + OFF_PO;
  float* pm     = ws + OFF_PM;
  float* Uo     = ws + OFF_UO;
  float* umhm   = ws + OFF_UMHM;
  float* logits = ws + OFF_LOG;
  float* up     = ws + OFF_UP;
  short* A1p    = (short*)(ws + OFF_A1P);
  int*   flag   = (int*)(ws + OFF_FLAG);
  float* partw  = ws + OFF_PART2;
  float* outp   = (float*)d_out;

  // 1: trans(MT=4) + hopeG + hmac + A1-convert + mask-probe
  mega1_kernel<<<849, 256, 0, stream>>>(nop, Wtr, btr, x12h, Wo, hopeG,
                                        nmac, Wm, hmac, A1, A1p,
                                        (const unsigned int*)maskp, flag);
  // 2: attention middle (MFMA) + rowdots
  mega2_kernel<<<3200, 256, 0, stream>>>(x12h, W0, b0, W1, b1,
                                         hopeG, alo, ao, hmac, alm, am);
  // 3: proj v1 + gat (b-major XCD remap)
  mega3_kernel<<<768, 256, 0, stream>>>(x12h, Wp, bp, hopes,
                                        adj, ao, am, hopeG, hmac, hmacs);
  // 4: pool+up+critic + Uo GEMM + Um-hmacs GEMM
  mega4_kernel<<<288, 256, 0, stream>>>(hopes, hmacs, A0, Ab0,
                                        C0, Cb0, C1, Cb1, C2, Cb2,
                                        po, pm, up, Uo, umhm, outp);
  // 5: actor v9 (fused softmax partials, no fences)
  actor_mfma9_kernel<<<1024, 256, 0, stream>>>(Uo, umhm, up, A1p, Ab1, A2, Ab2,
                                               maskp, flag, logits, partw);
  // 6: combine(256 triples) + gather + entropy
  final_ab_kernel<<<16, 64, 0, stream>>>(partw, logits, aidx, outp);
}

// Round 31
// 126.312 us; speedup vs baseline: 1.2453x; 1.0996x over previous
//
#include <hip/hip_runtime.h>

#define BB 16
#define NO 512
#define NM 32
#define DOC 128
#define C8 1024
#define NH 64
#define KD 16

// ---------------- ws layout (float offsets), ~44 MiB used ----------------
#define OFF_X12   0          // [16][64][512][16] bf16 h-sliced x1/x2 (in-place)
#define OFF_UO    0          // [8192,128] f32 (alias: x12h dead by then)
#define OFF_LOG   1048576    // [16,16384] (alias, after Uo)
#define OFF_HOPES 8388608    // [8192,128] ext-attn output
#define OFF_HOPEG 9437184    // [8192,128] GAT h_ope
#define OFF_HMAC  10485760   // [512,128]  GAT h_mac (pre)
#define OFF_HMACS 10551296   // [512,128]  GAT output
#define OFF_AO    10616832   // [8192]
#define OFF_AM    10625024   // [512]
#define OFF_PO    10625536   // [16,128]
#define OFF_PM    10627584   // [16,128]
#define OFF_UMHM  10629632   // [512,128]  hmacs-part of Um (MFMA)
#define OFF_FLAG  10695168   // int flag (mask dtype probe)
#define OFF_UP    10720000   // [16,128]   Up[b] = A0[:,256:512]*(po,pm)+Ab0
#define OFF_PART2 10750000   // [4096,3] per-wave actor softmax partials
#define OFF_A1P   10900000   // [16384] bf16 A1 pre-converted (OUTSIDE x12h!)
#define OFF_WPH   11000000   // [131072] bf16 Wp pre-converted (65536 floats)

using f32x4  = __attribute__((ext_vector_type(4))) float;
using s16x4  = __attribute__((ext_vector_type(4))) short;
using bf16x8 = __attribute__((ext_vector_type(8))) short;   // 8 bf16 (4 VGPRs)

// clamp-free: exp(2x)->{0,inf} at extremes gives exactly -1/+1 via rcp
__device__ __forceinline__ float fast_tanh(float x) {
  float e = __expf(2.0f * x);
  return 1.0f - 2.0f * __builtin_amdgcn_rcpf(e + 1.0f);
}

__device__ __forceinline__ short f2bf(float f) {          // RNE f32->bf16
  unsigned u = __builtin_bit_cast(unsigned, f);
  u += 0x7FFFu + ((u >> 16) & 1u);
  return (short)(u >> 16);
}

__device__ __forceinline__ float bf2f(short s) {
  return __builtin_bit_cast(float, ((unsigned)(unsigned short)s) << 16);
}

__device__ __forceinline__ unsigned cvtpk(float a, float b) {
  unsigned r;
  asm("v_cvt_pk_bf16_f32 %0, %1, %2" : "=v"(r) : "v"(a), "v"(b));
  return r;
}

__device__ __forceinline__ bf16x8 pack8(f32x4 u0, f32x4 u1) {
  union { unsigned u[4]; bf16x8 v; } cv;
  cv.u[0] = cvtpk(u0[0], u0[1]);
  cv.u[1] = cvtpk(u0[2], u0[3]);
  cv.u[2] = cvtpk(u1[0], u1[1]);
  cv.u[3] = cvtpk(u1[2], u1[3]);
  return cv.v;
}

__device__ __forceinline__ bf16x8 pack8f(const float* t) {
  union { unsigned u[4]; bf16x8 v; } cv;
  cv.u[0] = cvtpk(t[0], t[1]);
  cv.u[1] = cvtpk(t[2], t[3]);
  cv.u[2] = cvtpk(t[4], t[5]);
  cv.u[3] = cvtpk(t[6], t[7]);
  return cv.v;
}

// online-softmax partial merge: (Ma,Sa,Ta) += (Mb,Sb,Tb)
__device__ __forceinline__ void smmerge(float& lm, float& lS, float& lT,
                                        float om, float oS, float oT) {
  float nm = fmaxf(lm, om);
  float ea = __expf(lm - nm), eb = __expf(om - nm);
  lT = (lT + (lm - nm) * lS) * ea + (oT + (om - nm) * oS) * eb;
  lS = lS * ea + oS * eb;
  lm = nm;
}

// ---------------- mask dtype probe (body) ----------------
__device__ void probe_body(int tid, const unsigned int* __restrict__ mask,
                           int* __restrict__ flag) {
  __shared__ int s[4];
  int bad = 0;
  for (int i = tid; i < 4096; i += 256) {
    unsigned int v = mask[i];
    if (!(v == 0u || v == 1u || v == 0x3f800000u)) bad = 1;
  }
  unsigned long long any = __ballot(bad);
  int lane = tid & 63, w = tid >> 6;
  if (lane == 0) s[w] = (any != 0ull) ? 1 : 0;
  __syncthreads();
  if (tid == 0) flag[0] = s[0] | s[1] | s[2] | s[3];
}

// ---------------- GEMM bodies (verbatim, verified) ----------------
template<int MT>
__device__ __forceinline__ void loadk(const float* xb, const float* wb,
                                      long sx, long sw, int k0,
                                      f32x4 (&xa)[MT][2], f32x4 (&wa)[4][2]) {
  #pragma unroll
  for (int mi = 0; mi < MT; ++mi) {
    xa[mi][0] = *(const f32x4*)(xb + mi * sx + k0);
    xa[mi][1] = *(const f32x4*)(xb + mi * sx + k0 + 4);
  }
  #pragma unroll
  for (int ni = 0; ni < 4; ++ni) {
    wa[ni][0] = *(const f32x4*)(wb + ni * sw + k0);
    wa[ni][1] = *(const f32x4*)(wb + ni * sw + k0 + 4);
  }
}

template<int MT>
__device__ __forceinline__ void consume(f32x4 (&xa)[MT][2], f32x4 (&wa)[4][2],
                                        f32x4 (&acc)[MT][4]) {
  bf16x8 bfr[4];
  #pragma unroll
  for (int ni = 0; ni < 4; ++ni) bfr[ni] = pack8(wa[ni][0], wa[ni][1]);
  #pragma unroll
  for (int mi = 0; mi < MT; ++mi) {
    bf16x8 af = pack8(xa[mi][0], xa[mi][1]);
    #pragma unroll
    for (int ni = 0; ni < 4; ++ni)
      acc[mi][ni] = __builtin_amdgcn_mfma_f32_16x16x32_bf16(af, bfr[ni], acc[mi][ni], 0, 0, 0);
  }
}

template<int MT>
__device__ void gemm_wave_body(int bx, int by, int tid,
    const float* __restrict__ X, const float* __restrict__ W,
    const float* __restrict__ bias, float* __restrict__ C,
    int N, int Kdim, int ldx, int ldw) {
  const int lane = tid & 63, w = tid >> 6;
  const int rowl = lane & 15, kg = lane >> 4;
  const int n0 = bx * 64;
  const int m0 = (by * 4 + w) * (MT * 16);
  const float* xb = X + (long)(m0 + rowl) * ldx + kg * 8;
  const float* wb = W + (long)(n0 + rowl) * ldw + kg * 8;
  const long sx = (long)16 * ldx, sw = (long)16 * ldw;
  f32x4 acc[MT][4] = {};
  f32x4 A0[MT][2], B0[4][2], A1[MT][2], B1[4][2];
  loadk<MT>(xb, wb, sx, sw, 0, A0, B0);
  for (int k = 0; k < Kdim; k += 64) {
    loadk<MT>(xb, wb, sx, sw, k + 32, A1, B1);
    consume<MT>(A0, B0, acc);
    if (k + 64 < Kdim) loadk<MT>(xb, wb, sx, sw, k + 64, A0, B0);
    consume<MT>(A1, B1, acc);
  }
  #pragma unroll
  for (int mi = 0; mi < MT; ++mi) {
    #pragma unroll
    for (int ni = 0; ni < 4; ++ni) {
      int col = n0 + ni * 16 + rowl;
      float bv = bias ? bias[col] : 0.0f;
      int rb = m0 + mi * 16 + kg * 4;
      #pragma unroll
      for (int r = 0; r < 4; ++r)
        C[(long)(rb + r) * N + col] = acc[mi][ni][r] + bv;
    }
  }
}

// trans GEMM body: f32 in, bf16 h-sliced out.
template<int MT>
__device__ void gemm_ht_body(int bx, int by, int tid,
    const float* __restrict__ X, const float* __restrict__ W,
    const float* __restrict__ bias, short* __restrict__ Ch,
    int Kdim, int ldx, int ldw) {
  const int lane = tid & 63, w = tid >> 6;
  const int rowl = lane & 15, kg = lane >> 4;
  const int n0 = bx * 64;
  const int m0 = (by * 4 + w) * (MT * 16);
  const float* xb = X + (long)(m0 + rowl) * ldx + kg * 8;
  const float* wb = W + (long)(n0 + rowl) * ldw + kg * 8;
  const long sx = (long)16 * ldx, sw = (long)16 * ldw;
  f32x4 acc[MT][4] = {};
  f32x4 A0[MT][2], B0[4][2], A1[MT][2], B1[4][2];
  loadk<MT>(xb, wb, sx, sw, 0, A0, B0);
  for (int k = 0; k < Kdim; k += 64) {
    loadk<MT>(xb, wb, sx, sw, k + 32, A1, B1);
    consume<MT>(A0, B0, acc);
    if (k + 64 < Kdim) loadk<MT>(xb, wb, sx, sw, k + 64, A0, B0);
    consume<MT>(A1, B1, acc);
  }
  #pragma unroll
  for (int mi = 0; mi < MT; ++mi) {
    #pragma unroll
    for (int ni = 0; ni < 4; ++ni) {
      int col = n0 + ni * 16 + rowl;
      float bv = bias ? bias[col] : 0.0f;
      int h = col >> 4, e = col & 15;
      int rb = m0 + mi * 16 + kg * 4;
      #pragma unroll
      for (int r = 0; r < 4; ++r) {
        int rowI = rb + r;
        int b = rowI >> 9, n = rowI & 511;
        Ch[((long)(b * 64 + h) * 512 + n) * 16 + e] = f2bf(acc[mi][ni][r] + bv);
      }
    }
  }
}

__device__ void convert_a1_body(int blk, int tid,
    const float* __restrict__ A1, short* __restrict__ A1p) {
  int i = blk * 256 + tid;
  int col = i >> 7, k = i & 127;
  A1p[((k >> 3) * 128 + col) * 8 + (k & 7)] = f2bf(A1[i]);
}

// Wp f32 -> bf16 (same layout; cvt_pk = identical rounding to runtime path)
__device__ void convert_wp_body(int blk, int tid,
    const float* __restrict__ Wp, short* __restrict__ Wph) {
  int i = (blk * 256 + tid) * 8;
  f32x4 a = *(const f32x4*)(Wp + i);
  f32x4 b = *(const f32x4*)(Wp + i + 4);
  *(bf16x8*)(Wph + i) = pack8(a, b);
}

// ---------------- mega1: trans MT=4 (512) + hopeG(256) + hmac(16) + convA1(64) + convWp(64) + probe(1) ----------------
__global__ __launch_bounds__(256) void mega1_kernel(
    const float* __restrict__ nop, const float* __restrict__ Wtr,
    const float* __restrict__ btr, short* __restrict__ x12h,
    const float* __restrict__ Wo, float* __restrict__ hopeG,
    const float* __restrict__ nmac, const float* __restrict__ Wm,
    float* __restrict__ hmac,
    const float* __restrict__ A1, short* __restrict__ A1p,
    const float* __restrict__ Wp, short* __restrict__ Wph,
    const unsigned int* __restrict__ mask, int* __restrict__ flag) {
  const int blk = blockIdx.x, tid = threadIdx.x;
  if (blk < 512) {
    gemm_ht_body<4>(blk & 15, blk >> 4, tid, nop, Wtr, btr, x12h, 128, 128, 128);
  } else if (blk < 768) {
    int t = blk - 512;
    gemm_wave_body<1>(t & 1, t >> 1, tid, nop, Wo, nullptr, hopeG, 128, 128, 128, 128);
  } else if (blk < 784) {
    int t = blk - 768;
    gemm_wave_body<1>(t & 1, t >> 1, tid, nmac, Wm, nullptr, hmac, 128, 64, 64, 64);
  } else if (blk < 848) {
    convert_a1_body(blk - 784, tid, A1, A1p);
  } else if (blk < 912) {
    convert_wp_body(blk - 848, tid, Wp, Wph);
  } else {
    probe_body(tid, mask, flag);
  }
}

// ---------------- attn v3: MFMA-based (verified r23/r24) ----------------
__device__ void attn3_body(int b, int h, int tid, short* __restrict__ x12h,
    const float* __restrict__ W0, const float* __restrict__ b0,
    const float* __restrict__ W1, const float* __restrict__ b1) {
  __shared__ short Pb[4][128 * 16];      // 16 KB
  __shared__ float cmw[4][16], csw[4][16];
  const int wq = tid >> 6, lane = tid & 63;
  const int rowl = lane & 15, kg = lane >> 4;
  short* slice = x12h + (long)(b * 64 + h) * 8192;
  const short* wrows = slice + (long)(wq * 128) * 16;
  const bf16x8 zero8 = {};
  bf16x8 xa[8];
  #pragma unroll
  for (int t = 0; t < 8; ++t) {
    if (kg < 2)
      xa[t] = *(const bf16x8*)(wrows + (t * 16 + rowl) * 16 + kg * 8);
    else
      xa[t] = zero8;
  }
  bf16x8 w0f = zero8;
  if (kg < 2) {
    f32x4 a = *(const f32x4*)(W0 + rowl * 16 + kg * 8);
    f32x4 c = *(const f32x4*)(W0 + rowl * 16 + kg * 8 + 4);
    w0f = pack8(a, c);
  }
  const float b0v = b0[rowl];
  f32x4 acc[8];
  #pragma unroll
  for (int t = 0; t < 8; ++t) {
    f32x4 z = {0.f, 0.f, 0.f, 0.f};
    acc[t] = __builtin_amdgcn_mfma_f32_16x16x32_bf16(xa[t], w0f, z, 0, 0, 0);
  }
  float m = -1e30f;
  #pragma unroll
  for (int t = 0; t < 8; ++t)
    #pragma unroll
    for (int r = 0; r < 4; ++r) {
      acc[t][r] += b0v;
      m = fmaxf(m, acc[t][r]);
    }
  m = fmaxf(m, __shfl_xor(m, 16));
  m = fmaxf(m, __shfl_xor(m, 32));
  if (lane < 16) cmw[wq][lane] = m;
  __syncthreads();
  const float cm = fmaxf(fmaxf(cmw[0][rowl], cmw[1][rowl]),
                         fmaxf(cmw[2][rowl], cmw[3][rowl]));
  float s = 0.f;
  #pragma unroll
  for (int t = 0; t < 8; ++t)
    #pragma unroll
    for (int r = 0; r < 4; ++r) {
      float e = __expf(acc[t][r] - cm);
      acc[t][r] = e;
      s += e;
    }
  s += __shfl_xor(s, 16);
  s += __shfl_xor(s, 32);
  if (lane < 16) csw[wq][lane] = s;
  __syncthreads();
  const float cs = csw[0][rowl] + csw[1][rowl] + csw[2][rowl] + csw[3][rowl];
  const float cinv = 1.0f / cs;
  short* pbw = Pb[wq];
  #pragma unroll
  for (int t = 0; t < 8; ++t)
    #pragma unroll
    for (int r = 0; r < 4; ++r) {
      float al = acc[t][r] * cinv;
      float rsv = al;
      rsv += __shfl_xor(rsv, 1);
      rsv += __shfl_xor(rsv, 2);
      rsv += __shfl_xor(rsv, 4);
      rsv += __shfl_xor(rsv, 8);
      float pf = al / (1e-10f + rsv);
      pbw[(t * 16 + kg * 4 + r) * 16 + rowl] = f2bf(pf);
    }
  __syncthreads();
  bf16x8 w1f = zero8;
  if (kg < 2) {
    f32x4 a = *(const f32x4*)(W1 + rowl * 16 + kg * 8);
    f32x4 c = *(const f32x4*)(W1 + rowl * 16 + kg * 8 + 4);
    w1f = pack8(a, c);
  }
  const float b1v = b1[rowl];
  #pragma unroll
  for (int t = 0; t < 8; ++t) {
    bf16x8 pa = zero8;
    if (kg < 2)
      pa = *(const bf16x8*)(pbw + (t * 16 + rowl) * 16 + kg * 8);
    f32x4 z = {0.f, 0.f, 0.f, 0.f};
    f32x4 oacc = __builtin_amdgcn_mfma_f32_16x16x32_bf16(pa, w1f, z, 0, 0, 0);
    #pragma unroll
    for (int r = 0; r < 4; ++r) {
      int n = wq * 128 + t * 16 + kg * 4 + r;
      slice[(long)n * 16 + rowl] = f2bf(oacc[r] + b1v);
    }
  }
}

// ---------------- mega2: attn3(1024) + rowdot2(2176) ----------------
__global__ __launch_bounds__(256) void mega2_kernel(
    short* __restrict__ x12h,
    const float* __restrict__ W0, const float* __restrict__ b0,
    const float* __restrict__ W1, const float* __restrict__ b1,
    const float* __restrict__ hopeG, const float* __restrict__ alo,
    float* __restrict__ ao,
    const float* __restrict__ hmac, const float* __restrict__ alm,
    float* __restrict__ am) {
  const int blk = blockIdx.x, tid = threadIdx.x;
  if (blk < 1024) {
    attn3_body(blk >> 6, blk & 63, tid, x12h, W0, b0, W1, b1);
  } else {
    int t = blk - 1024;
    int wid = t * 4 + (tid >> 6);
    int lane = tid & 63;
    const float* X; const float* al; float* out; int r;
    if (wid < 8192)       { X = hopeG; al = alo; out = ao; r = wid; }
    else if (wid < 8704)  { X = hmac;  al = alm; out = am; r = wid - 8192; }
    else return;
    const float* row = X + (long)r * 128;
    float v = fmaf(row[lane], al[lane], row[lane + 64] * al[lane + 64]);
    #pragma unroll
    for (int off = 32; off; off >>= 1) v += __shfl_down(v, off);
    if (lane == 0) out[r] = v;
  }
}

// ---------------- proj GEMM body v3: bf16 pre-converted W (Wph) ----------------
__device__ void gemm_hx_body(int bx, int by, int tid,
    const short* __restrict__ Xh, const short* __restrict__ Wh,
    const float* __restrict__ bias, float* __restrict__ C) {
  const int lane = tid & 63, w = tid >> 6;
  const int rowl = lane & 15, kg = lane >> 4;
  const int n0 = bx * 64;
  const int m0 = (by * 4 + w) * 16;
  const int row = m0 + rowl, b = row >> 9, n = row & 511;
  const short* xb = Xh + (long)b * 524288 + (long)n * 16 + (kg & 1) * 8;
  const long hofs = kg >> 1;
  const short* wb = Wh + (long)(n0 + rowl) * 1024 + kg * 8;
  const long sw = 16 * 1024L;
  f32x4 acc[4] = {};
  bf16x8 A0, A1;
  bf16x8 Wb0[4], Wb1[4];
  A0 = *(const bf16x8*)(xb + hofs * 8192);
  #pragma unroll
  for (int ni = 0; ni < 4; ++ni)
    Wb0[ni] = *(const bf16x8*)(wb + ni * sw);
  for (int k = 0; k < 1024; k += 64) {
    A1 = *(const bf16x8*)(xb + (((k + 32) >> 4) + hofs) * 8192);
    #pragma unroll
    for (int ni = 0; ni < 4; ++ni)
      Wb1[ni] = *(const bf16x8*)(wb + ni * sw + k + 32);
    #pragma unroll
    for (int ni = 0; ni < 4; ++ni)
      acc[ni] = __builtin_amdgcn_mfma_f32_16x16x32_bf16(A0, Wb0[ni], acc[ni], 0, 0, 0);
    if (k + 64 < 1024) {
      A0 = *(const bf16x8*)(xb + (((k + 64) >> 4) + hofs) * 8192);
      #pragma unroll
      for (int ni = 0; ni < 4; ++ni)
        Wb0[ni] = *(const bf16x8*)(wb + ni * sw + k + 64);
    }
    #pragma unroll
    for (int ni = 0; ni < 4; ++ni)
      acc[ni] = __builtin_amdgcn_mfma_f32_16x16x32_bf16(A1, Wb1[ni], acc[ni], 0, 0, 0);
  }
  #pragma unroll
  for (int ni = 0; ni < 4; ++ni) {
    int col = n0 + ni * 16 + rowl;
    float bv = bias ? bias[col] : 0.0f;
    int rb = m0 + kg * 4;
    #pragma unroll
    for (int r = 0; r < 4; ++r)
      C[(long)(rb + r) * 128 + col] = acc[ni][r] + bv;
  }
}

// ---------------- GAT body: 256 threads, 2 o's/thread (verified) ----------------
__device__ void gat_body(int b, int m, int tid,
    const float* __restrict__ adj, const float* __restrict__ ao,
    const float* __restrict__ am, const float* __restrict__ hopeG,
    const float* __restrict__ hmac, float* __restrict__ hmacs) {
  __shared__ float al[NO];
  __shared__ float redA[4], redB[4];
  __shared__ float part[2][128];
  const int lane = tid & 63, w = tid >> 6;
  const float amv = am[b * NM + m];
  float av[2], ev[2];
  float mx = -1e30f;
  #pragma unroll
  for (int i = 0; i < 2; ++i) {
    int o = tid + i * 256;
    float a = adj[(b * NO + o) * NM + m];
    float e = ao[b * NO + o] + amv;
    e = (e >= 0.f) ? e : 0.2f * e;
    av[i] = a; ev[i] = e;
    if (a == 1.0f) mx = fmaxf(mx, e);
  }
  #pragma unroll
  for (int off = 32; off; off >>= 1) mx = fmaxf(mx, __shfl_down(mx, off));
  if (lane == 0) redA[w] = mx;
  __syncthreads();
  mx = fmaxf(fmaxf(redA[0], redA[1]), fmaxf(redA[2], redA[3]));
  float p[2], s = 0.f;
  #pragma unroll
  for (int i = 0; i < 2; ++i) {
    p[i] = (av[i] == 1.0f) ? __expf(ev[i] - mx) : 0.f;
    s += p[i];
  }
  #pragma unroll
  for (int off = 32; off; off >>= 1) s += __shfl_down(s, off);
  if (lane == 0) redB[w] = s;
  __syncthreads();
  s = redB[0] + redB[1] + redB[2] + redB[3];
  const float sinv = (s > 0.f) ? 1.0f / s : 0.f;
  al[tid] = p[0] * sinv;
  al[tid + 256] = p[1] * sinv;
  __syncthreads();
  const int d = tid & 127, og = tid >> 7;
  float acc0 = 0.f, acc1 = 0.f;
  const float* hb = hopeG + ((long)(b * NO) + og * 256) * DOC + d;
  #pragma unroll 8
  for (int i = 0; i < 256; i += 2) {
    acc0 = fmaf(al[og * 256 + i],     hb[(long)i * DOC],       acc0);
    acc1 = fmaf(al[og * 256 + i + 1], hb[(long)(i + 1) * DOC], acc1);
  }
  part[og][d] = acc0 + acc1;
  __syncthreads();
  if (og == 0)
    hmacs[(b * NM + m) * DOC + d] = part[0][d] + part[1][d]
                                   + hmac[(b * NM + m) * DOC + d];
}

// ---------------- mega3: proj v3(256) + gat(512, b-major XCD remap) ----------------
__global__ __launch_bounds__(256) void mega3_kernel(
    const short* __restrict__ x12h, const short* __restrict__ Wph,
    const float* __restrict__ bp, float* __restrict__ hopes,
    const float* __restrict__ adj, const float* __restrict__ ao,
    const float* __restrict__ am, const float* __restrict__ hopeG,
    const float* __restrict__ hmac, float* __restrict__ hmacs) {
  const int blk = blockIdx.x, tid = threadIdx.x;
  if (blk < 256) {
    gemm_hx_body(blk & 1, blk >> 1, tid, x12h, Wph, bp, hopes);
  } else {
    int t = blk - 256;            // t = m*16 + b  -> XCD (t%8) = b%8: all m of a
    gat_body(t & 15, t >> 4, tid, // given b share one XCD's L2 for hopeG/adj
             adj, ao, am, hopeG, hmac, hmacs);
  }
}

// ---------------- pool+up+critic: one block per b (verified r29/r30 interior) ----------------
__device__ void pool_up_body(int b, int tid,
    const float* __restrict__ hopes, const float* __restrict__ hmacs,
    const float* __restrict__ A0, const float* __restrict__ Ab0,
    const float* __restrict__ C0, const float* __restrict__ Cb0,
    const float* __restrict__ C1, const float* __restrict__ Cb1,
    const float* __restrict__ C2, const float* __restrict__ Cb2,
    float* __restrict__ po, float* __restrict__ pm, float* __restrict__ up,
    float* __restrict__ out) {
  __shared__ float part[2][128];
  __shared__ float pos[128], pms[128];
  __shared__ float zc[128];
  __shared__ float scc[2];
  const int j = tid & 127, og = tid >> 7;
  // hopes sum: each og-half covers 256 rows, coalesced 512B row reads
  const float* hb = hopes + ((long)(b * 512) + og * 256) * 128 + j;
  float a0 = 0.f, a1 = 0.f;
  #pragma unroll 8
  for (int i = 0; i < 256; i += 2) {
    a0 += hb[(long)i * 128];
    a1 += hb[(long)(i + 1) * 128];
  }
  part[og][j] = a0 + a1;
  __syncthreads();
  if (og == 0) {
    float s = (part[0][j] + part[1][j]) * (1.0f / 512.0f);
    po[b * 128 + j] = s;
    pos[j] = s;
  } else {
    const float* mb = hmacs + (long)(b * 32) * 128 + j;
    float t0 = 0.f;
    #pragma unroll 8
    for (int i = 0; i < 32; ++i) t0 += mb[(long)i * 128];
    t0 *= (1.0f / 32.0f);
    pm[b * 128 + j] = t0;
    pms[j] = t0;
  }
  __syncthreads();
  if (tid < 128) {
    const float* a1p = A0 + (long)j * 512 + 256;
    const float* a2p = A0 + (long)j * 512 + 384;
    float acc = Ab0[j];
    #pragma unroll 4
    for (int k4 = 0; k4 < 32; ++k4) {
      f32x4 av = *(const f32x4*)(a1p + k4 * 4);
      acc = fmaf(av[0], pos[k4 * 4], acc);
      acc = fmaf(av[1], pos[k4 * 4 + 1], acc);
      acc = fmaf(av[2], pos[k4 * 4 + 2], acc);
      acc = fmaf(av[3], pos[k4 * 4 + 3], acc);
    }
    #pragma unroll 4
    for (int k4 = 0; k4 < 32; ++k4) {
      f32x4 av = *(const f32x4*)(a2p + k4 * 4);
      acc = fmaf(av[0], pms[k4 * 4], acc);
      acc = fmaf(av[1], pms[k4 * 4 + 1], acc);
      acc = fmaf(av[2], pms[k4 * 4 + 2], acc);
      acc = fmaf(av[3], pms[k4 * 4 + 3], acc);
    }
    up[b * 128 + j] = acc;
    // critic layer 1: v = (pos, pms)
    float cacc = Cb0[j];
    for (int k = 0; k < 128; ++k) cacc = fmaf(C0[j * 256 + k], pos[k], cacc);
    for (int k = 0; k < 128; ++k) cacc = fmaf(C0[j * 256 + 128 + k], pms[k], cacc);
    zc[j] = fast_tanh(cacc);
  }
  __syncthreads();
  if (tid < 128) {
    float acc2 = Cb1[j];
    for (int k = 0; k < 128; ++k) acc2 = fmaf(C1[j * 128 + k], zc[k], acc2);
    float z2 = fast_tanh(acc2);
    float p = C2[j] * z2;
    #pragma unroll
    for (int off = 32; off; off >>= 1) p += __shfl_down(p, off);
    const int lane = tid & 63, w = tid >> 6;
    if (lane == 0) scc[w] = p;
  }
  __syncthreads();
  if (tid == 0) out[16 + b] = scc[0] + scc[1] + Cb2[0];   // state_values
}

// ---------------- mega4 v3: pool+up+critic(16) + UoGEMM(256) + UmhmGEMM(16) ----------------
__global__ __launch_bounds__(256) void mega4_kernel(
    const float* __restrict__ hopes, const float* __restrict__ hmacs,
    const float* __restrict__ A0, const float* __restrict__ Ab0,
    const float* __restrict__ C0, const float* __restrict__ Cb0,
    const float* __restrict__ C1, const float* __restrict__ Cb1,
    const float* __restrict__ C2, const float* __restrict__ Cb2,
    float* __restrict__ po, float* __restrict__ pm, float* __restrict__ up,
    float* __restrict__ Uo, float* __restrict__ umhm,
    float* __restrict__ out) {
  const int blk = blockIdx.x, tid = threadIdx.x;
  if (blk < 16) {
    pool_up_body(blk, tid, hopes, hmacs, A0, Ab0, C0, Cb0, C1, Cb1, C2, Cb2,
                 po, pm, up, out);
  } else if (blk < 272) {
    int t = blk - 16;
    gemm_wave_body<1>(t & 1, t >> 1, tid, hopes, A0, nullptr, Uo, 128, 128, 128, 512);
  } else {
    int t = blk - 272;            // M=512 rows of hmacs, W=A0 cols 128:256
    gemm_wave_body<1>(t & 1, t >> 1, tid, hmacs, A0 + 128, nullptr, umhm, 128, 128, 128, 512);
  }
}

// ---------------- actor v9: fused per-wave masked softmax partials (verified r27/r28/r30) ----------------
__global__ __launch_bounds__(256) void actor_mfma9_kernel(
    const float* __restrict__ Uo, const float* __restrict__ umhm,
    const float* __restrict__ up, const short* __restrict__ A1p,
    const float* __restrict__ Ab1, const float* __restrict__ A2,
    const float* __restrict__ Ab2, const void* __restrict__ maskp,
    const int* __restrict__ flag, float* __restrict__ logits,
    float* __restrict__ partw) {
  const int tid = threadIdx.x;
  const int blk = blockIdx.x;
  const int oc = blk & 7;
  const int mg = (blk >> 3) & 7;
  const int b  = blk >> 6;
  const int obase = oc * 64;
  const int m0 = mg * 4;
  const int lane = tid & 63, w = tid >> 6;
  const int rowl = lane & 15, kg = lane >> 4;
  const float* uo = Uo + (long)(b * NO + obase + w * 16 + rowl) * 128;
  const float* upb = up + b * 128;
  const float* umb = umhm + (b * NM + m0) * 128;
  bf16x8 af[4][4];                       // [mi][kk]
  #pragma unroll
  for (int kk = 0; kk < 4; ++kk) {
    int kb = kk * 32 + kg * 8;
    f32x4 u0 = *(const f32x4*)(uo + kb);
    f32x4 u1 = *(const f32x4*)(uo + kb + 4);
    f32x4 p0 = *(const f32x4*)(upb + kb);
    f32x4 p1 = *(const f32x4*)(upb + kb + 4);
    float base0[4], base1[4];
    #pragma unroll
    for (int e = 0; e < 4; ++e) {
      base0[e] = u0[e] + p0[e];
      base1[e] = u1[e] + p1[e];
    }
    #pragma unroll
    for (int mi = 0; mi < 4; ++mi) {
      f32x4 a0 = *(const f32x4*)(umb + mi * 128 + kb);
      f32x4 a1 = *(const f32x4*)(umb + mi * 128 + kb + 4);
      float t[8];
      #pragma unroll
      for (int e = 0; e < 4; ++e) {
        t[e]     = fast_tanh(base0[e] + a0[e]);
        t[4 + e] = fast_tanh(base1[e] + a1[e]);
      }
      af[mi][kk] = pack8f(t);
    }
  }
  float pr[4][4] = {};
  #pragma unroll
  for (int ct = 0; ct < 8; ++ct) {
    const int col = ct * 16 + rowl;
    bf16x8 bf[4];
    #pragma unroll
    for (int kk = 0; kk < 4; ++kk)
      bf[kk] = *(const bf16x8*)(A1p + ((kk * 4 + kg) * 128 + col) * 8);
    f32x4 ac[4] = {};
    #pragma unroll
    for (int kk = 0; kk < 4; ++kk)
      #pragma unroll
      for (int mi = 0; mi < 4; ++mi)
        ac[mi] = __builtin_amdgcn_mfma_f32_16x16x32_bf16(af[mi][kk], bf[kk], ac[mi], 0, 0, 0);
    const float ab = Ab1[col], a2c = A2[col];
    #pragma unroll
    for (int mi = 0; mi < 4; ++mi)
      #pragma unroll
      for (int r = 0; r < 4; ++r) {
        float z = fast_tanh(ac[mi][r] + ab);
        pr[mi][r] = fmaf(a2c, z, pr[mi][r]);
      }
  }
  const float ab2 = Ab2[0];
  // butterfly-reduce; keep all 16 final logits per lane (identical across rowl)
  float rv[4][4];                        // [r][mi]
  #pragma unroll
  for (int r = 0; r < 4; ++r) {
    float v0 = pr[0][r], v1 = pr[1][r], v2 = pr[2][r], v3 = pr[3][r];
    #pragma unroll
    for (int off = 1; off < 16; off <<= 1) {
      v0 += __shfl_xor(v0, off);
      v1 += __shfl_xor(v1, off);
      v2 += __shfl_xor(v2, off);
      v3 += __shfl_xor(v3, off);
    }
    rv[r][0] = v0 + ab2; rv[r][1] = v1 + ab2;
    rv[r][2] = v2 + ab2; rv[r][3] = v3 + ab2;
  }
  const long base0 = ((long)b << 14) + (long)m0 * 512 + obase + w * 16 + kg * 4;
  if (rowl == 0) {
    #pragma unroll
    for (int r = 0; r < 4; ++r) {
      logits[base0 + r]        = rv[r][0];
      logits[base0 + 512 + r]  = rv[r][1];
      logits[base0 + 1024 + r] = rv[r][2];
      logits[base0 + 1536 + r] = rv[r][3];
    }
  }
  // fused masked softmax partial: lane covers o = obase+w*16+kg*4+r, m = m0+mi
  const bool word_mode = (flag[0] == 0);
  const int ob = obase + w * 16 + kg * 4;
  bool mk[4][4];
  if (word_mode) {
    const unsigned int* mw = (const unsigned int*)maskp;
    #pragma unroll
    for (int r = 0; r < 4; ++r) {
      long mo = (long)(b * NO + ob + r) * NM + m0;
      #pragma unroll
      for (int mi = 0; mi < 4; ++mi) mk[r][mi] = (mw[mo + mi] != 0u);
    }
  } else {
    const unsigned char* mb = (const unsigned char*)maskp;
    #pragma unroll
    for (int r = 0; r < 4; ++r) {
      long mo = (long)(b * NO + ob + r) * NM + m0;
      #pragma unroll
      for (int mi = 0; mi < 4; ++mi) mk[r][mi] = (mb[mo + mi] != 0);
    }
  }
  float lm = -1e30f;
  #pragma unroll
  for (int r = 0; r < 4; ++r)
    #pragma unroll
    for (int mi = 0; mi < 4; ++mi)
      if (mk[r][mi]) lm = fmaxf(lm, rv[r][mi]);
  float lS = 0.f, lT = 0.f;
  #pragma unroll
  for (int r = 0; r < 4; ++r)
    #pragma unroll
    for (int mi = 0; mi < 4; ++mi)
      if (mk[r][mi]) {
        float d = rv[r][mi] - lm;
        float e = __expf(d);
        lS += e; lT += e * d;
      }
  // merge across kg groups only (rowl lanes are duplicates)
  #pragma unroll
  for (int off = 16; off < 64; off <<= 1) {
    float om = __shfl_xor(lm, off);
    float oS = __shfl_xor(lS, off);
    float oT = __shfl_xor(lT, off);
    smmerge(lm, lS, lT, om, oS, oT);
  }
  if (lane == 0) {
    float* pp = partw + ((long)blk * 4 + w) * 3;
    pp[0] = lm; pp[1] = lS; pp[2] = lT;
  }
}

// ---------------- final_ab: 256-triple combine + gather + entropy (16 blocks x 64) ----------------
__global__ __launch_bounds__(64) void final_ab_kernel(
    const float* __restrict__ part, const float* __restrict__ logits,
    const int* __restrict__ aidx, float* __restrict__ out) {
  const int b = blockIdx.x;
  const int lane = threadIdx.x;
  float lm = -3e30f, lS = 0.f, lT = 0.f;
  const float* pp = part + ((long)b * 256 + lane * 4) * 3;
  #pragma unroll
  for (int t = 0; t < 4; ++t)
    smmerge(lm, lS, lT, pp[t * 3], pp[t * 3 + 1], pp[t * 3 + 2]);
  #pragma unroll
  for (int off = 1; off < 64; off <<= 1) {
    float om = __shfl_xor(lm, off);
    float oS = __shfl_xor(lS, off);
    float oT = __shfl_xor(lT, off);
    smmerge(lm, lS, lT, om, oS, oT);
  }
  if (lane == 0) {
    float lSm = logf(lS);
    out[b] = logits[(long)b * (NM * NO) + aidx[b]] - lm - lSm;  // action_logprobs
    out[32 + b] = lSm - lT / lS;                                // dist_entropys
  }
}

extern "C" void kernel_launch(void* const* d_in, const int* in_sizes, int n_in,
                              void* d_out, int out_size, void* d_ws, size_t ws_size,
                              hipStream_t stream) {
  (void)in_sizes; (void)n_in; (void)out_size; (void)ws_size;
  const float* adj  = (const float*)d_in[0];
  const float* nop  = (const float*)d_in[1];
  const float* nmac = (const float*)d_in[2];
  const void*  maskp = d_in[3];
  const int*   aidx = (const int*)d_in[4];
  const float* Wtr  = (const float*)d_in[5];
  const float* btr  = (const float*)d_in[6];
  const float* W0   = (const float*)d_in[7];
  const float* b0   = (const float*)d_in[8];
  const float* W1   = (const float*)d_in[9];
  const float* b1   = (const float*)d_in[10];
  const float* Wp   = (const float*)d_in[11];
  const float* bp   = (const float*)d_in[12];
  const float* Wo   = (const float*)d_in[13];
  const float* Wm   = (const float*)d_in[14];
  const float* alo  = (const float*)d_in[15];
  const float* alm  = (const float*)d_in[16];
  const float* A0   = (const float*)d_in[17];
  const float* Ab0  = (const float*)d_in[18];
  const float* A1   = (const float*)d_in[19];
  const float* Ab1  = (const float*)d_in[20];
  const float* A2   = (const float*)d_in[21];
  const float* Ab2  = (const float*)d_in[22];
  const float* C0   = (const float*)d_in[23];
  const float* Cb0  = (const float*)d_in[24];
  const float* C1   = (const float*)d_in[25];
  const float* Cb1  = (const float*)d_in[26];
  const float* C2   = (const float*)d_in[27];
  const float* Cb2  = (const float*)d_in[28];

  float* ws     = (float*)d_ws;        // needs ~45 MiB
  short* x12h   = (short*)(ws + OFF_X12);
  float* hopes  = ws + OFF_HOPES;
  float* hopeG  = ws + OFF_HOPEG;
  float* hmac   = ws + OFF_HMAC;
  float* hmacs  = ws + OFF_HMACS;
  float* ao     = ws + OFF_AO;
  float* am     = ws + OFF_AM;
  float* po     = ws + OFF_PO;
  float* pm     = ws + OFF_PM;
  float* Uo     = ws + OFF_UO;
  float* umhm   = ws + OFF_UMHM;
  float* logits = ws + OFF_LOG;
  float* up     = ws + OFF_UP;
  short* A1p    = (short*)(ws + OFF_A1P);
  short* Wph    = (short*)(ws + OFF_WPH);
  int*   flag   = (int*)(ws + OFF_FLAG);
  float* partw  = ws + OFF_PART2;
  float* outp   = (float*)d_out;

  // 1: trans(MT=4) + hopeG + hmac + A1-convert + Wp-convert + mask-probe
  mega1_kernel<<<913, 256, 0, stream>>>(nop, Wtr, btr, x12h, Wo, hopeG,
                                        nmac, Wm, hmac, A1, A1p, Wp, Wph,
                                        (const unsigned int*)maskp, flag);
  // 2: attention middle (MFMA) + rowdots
  mega2_kernel<<<3200, 256, 0, stream>>>(x12h, W0, b0, W1, b1,
                                         hopeG, alo, ao, hmac, alm, am);
  // 3: proj v3 (bf16 W) + gat (b-major XCD remap)
  mega3_kernel<<<768, 256, 0, stream>>>(x12h, Wph, bp, hopes,
                                        adj, ao, am, hopeG, hmac, hmacs);
  // 4: pool+up+critic + Uo GEMM + Um-hmacs GEMM
  mega4_kernel<<<288, 256, 0, stream>>>(hopes, hmacs, A0, Ab0,
                                        C0, Cb0, C1, Cb1, C2, Cb2,
                                        po, pm, up, Uo, umhm, outp);
  // 5: actor v9 (fused softmax partials)
  actor_mfma9_kernel<<<1024, 256, 0, stream>>>(Uo, umhm, up, A1p, Ab1, A2, Ab2,
                                               maskp, flag, logits, partw);
  // 6: combine(256 triples) + gather + entropy
  final_ab_kernel<<<16, 64, 0, stream>>>(partw, logits, aidx, outp);
}

// Round 32
// 123.076 us; speedup vs baseline: 1.2780x; 1.0263x over previous
//
#include <hip/hip_runtime.h>

#define BB 16
#define NO 512
#define NM 32
#define DOC 128
#define C8 1024
#define NH 64
#define KD 16

// ---------------- ws layout (float offsets), ~47 MiB used ----------------
#define OFF_X12   0          // [16][64][512][16] bf16 h-sliced x1/x2 (in-place)
#define OFF_UO    0          // [8192,128] f32 (alias: x12h dead by then)
#define OFF_LOG   1048576    // [16,16384] (alias, after Uo)
#define OFF_HOPES 8388608    // [8192,128] ext-attn output
#define OFF_HOPEG 9437184    // [8192,128] GAT h_ope
#define OFF_HMAC  10485760   // [512,128]  GAT h_mac (pre)
#define OFF_HMACS 10551296   // [512,128]  GAT output
#define OFF_AO    10616832   // [8192]
#define OFF_AM    10625024   // [512]
#define OFF_PO    10625536   // [16,128]
#define OFF_PM    10627584   // [16,128]
#define OFF_UMHM  10629632   // [512,128]  hmacs-part of Um (MFMA)
#define OFF_FLAG  10695168   // int flag (mask dtype probe)
#define OFF_UP    10720000   // [16,128]   Up[b] = A0[:,256:512]*(po,pm)+Ab0
#define OFF_PART2 10750000   // [4096,3] per-wave actor softmax partials
#define OFF_A1P   10900000   // [16384] bf16 A1 pre-converted (OUTSIDE x12h!)
#define OFF_WPH   11000000   // [131072] bf16 Wp pre-converted (65536 floats)
#define OFF_NOPB  11100000   // [1048576] bf16 nop pre-converted (524288 floats)
#define OFF_WTRB  11650000   // [131072] bf16 Wtr (65536 floats)
#define OFF_WOB   11720000   // [16384] bf16 Wo (8192 floats)

using f32x4  = __attribute__((ext_vector_type(4))) float;
using s16x4  = __attribute__((ext_vector_type(4))) short;
using bf16x8 = __attribute__((ext_vector_type(8))) short;   // 8 bf16 (4 VGPRs)

// clamp-free: exp(2x)->{0,inf} at extremes gives exactly -1/+1 via rcp
__device__ __forceinline__ float fast_tanh(float x) {
  float e = __expf(2.0f * x);
  return 1.0f - 2.0f * __builtin_amdgcn_rcpf(e + 1.0f);
}

__device__ __forceinline__ short f2bf(float f) {          // RNE f32->bf16
  unsigned u = __builtin_bit_cast(unsigned, f);
  u += 0x7FFFu + ((u >> 16) & 1u);
  return (short)(u >> 16);
}

__device__ __forceinline__ float bf2f(short s) {
  return __builtin_bit_cast(float, ((unsigned)(unsigned short)s) << 16);
}

__device__ __forceinline__ unsigned cvtpk(float a, float b) {
  unsigned r;
  asm("v_cvt_pk_bf16_f32 %0, %1, %2" : "=v"(r) : "v"(a), "v"(b));
  return r;
}

__device__ __forceinline__ bf16x8 pack8(f32x4 u0, f32x4 u1) {
  union { unsigned u[4]; bf16x8 v; } cv;
  cv.u[0] = cvtpk(u0[0], u0[1]);
  cv.u[1] = cvtpk(u0[2], u0[3]);
  cv.u[2] = cvtpk(u1[0], u1[1]);
  cv.u[3] = cvtpk(u1[2], u1[3]);
  return cv.v;
}

__device__ __forceinline__ bf16x8 pack8f(const float* t) {
  union { unsigned u[4]; bf16x8 v; } cv;
  cv.u[0] = cvtpk(t[0], t[1]);
  cv.u[1] = cvtpk(t[2], t[3]);
  cv.u[2] = cvtpk(t[4], t[5]);
  cv.u[3] = cvtpk(t[6], t[7]);
  return cv.v;
}

// online-softmax partial merge: (Ma,Sa,Ta) += (Mb,Sb,Tb)
__device__ __forceinline__ void smmerge(float& lm, float& lS, float& lT,
                                        float om, float oS, float oT) {
  float nm = fmaxf(lm, om);
  float ea = __expf(lm - nm), eb = __expf(om - nm);
  lT = (lT + (lm - nm) * lS) * ea + (oT + (om - nm) * oS) * eb;
  lS = lS * ea + oS * eb;
  lm = nm;
}

// ---------------- mask dtype probe (body) ----------------
__device__ void probe_body(int tid, const unsigned int* __restrict__ mask,
                           int* __restrict__ flag) {
  __shared__ int s[4];
  int bad = 0;
  for (int i = tid; i < 4096; i += 256) {
    unsigned int v = mask[i];
    if (!(v == 0u || v == 1u || v == 0x3f800000u)) bad = 1;
  }
  unsigned long long any = __ballot(bad);
  int lane = tid & 63, w = tid >> 6;
  if (lane == 0) s[w] = (any != 0ull) ? 1 : 0;
  __syncthreads();
  if (tid == 0) flag[0] = s[0] | s[1] | s[2] | s[3];
}

// ---------------- converters ----------------
__device__ void convert8_body(int blk, int tid,
    const float* __restrict__ src, short* __restrict__ dst) {
  int i = (blk * 256 + tid) * 8;
  f32x4 a = *(const f32x4*)(src + i);
  f32x4 b = *(const f32x4*)(src + i + 4);
  *(bf16x8*)(dst + i) = pack8(a, b);
}

__device__ void convert_a1_body(int blk, int tid,
    const float* __restrict__ A1, short* __restrict__ A1p) {
  int i = blk * 256 + tid;
  int col = i >> 7, k = i & 127;
  A1p[((k >> 3) * 128 + col) * 8 + (k & 7)] = f2bf(A1[i]);
}

// ---------------- mega0: all pre-conversions + probe ----------------
// nop(512) + Wtr(64) + Wo(8) + A1(64) + Wp(64) + probe(1) = 713 blocks
__global__ __launch_bounds__(256) void mega0_kernel(
    const float* __restrict__ nop, short* __restrict__ nopb,
    const float* __restrict__ Wtr, short* __restrict__ Wtrb,
    const float* __restrict__ Wo, short* __restrict__ Wob,
    const float* __restrict__ A1, short* __restrict__ A1p,
    const float* __restrict__ Wp, short* __restrict__ Wph,
    const unsigned int* __restrict__ mask, int* __restrict__ flag) {
  const int blk = blockIdx.x, tid = threadIdx.x;
  if (blk < 512) {
    convert8_body(blk, tid, nop, nopb);
  } else if (blk < 576) {
    convert8_body(blk - 512, tid, Wtr, Wtrb);
  } else if (blk < 584) {
    convert8_body(blk - 576, tid, Wo, Wob);
  } else if (blk < 648) {
    convert_a1_body(blk - 584, tid, A1, A1p);
  } else if (blk < 712) {
    convert8_body(blk - 648, tid, Wp, Wph);
  } else {
    probe_body(tid, mask, flag);
  }
}

// ---------------- GEMM bodies (f32, verbatim, verified) ----------------
template<int MT>
__device__ __forceinline__ void loadk(const float* xb, const float* wb,
                                      long sx, long sw, int k0,
                                      f32x4 (&xa)[MT][2], f32x4 (&wa)[4][2]) {
  #pragma unroll
  for (int mi = 0; mi < MT; ++mi) {
    xa[mi][0] = *(const f32x4*)(xb + mi * sx + k0);
    xa[mi][1] = *(const f32x4*)(xb + mi * sx + k0 + 4);
  }
  #pragma unroll
  for (int ni = 0; ni < 4; ++ni) {
    wa[ni][0] = *(const f32x4*)(wb + ni * sw + k0);
    wa[ni][1] = *(const f32x4*)(wb + ni * sw + k0 + 4);
  }
}

template<int MT>
__device__ __forceinline__ void consume(f32x4 (&xa)[MT][2], f32x4 (&wa)[4][2],
                                        f32x4 (&acc)[MT][4]) {
  bf16x8 bfr[4];
  #pragma unroll
  for (int ni = 0; ni < 4; ++ni) bfr[ni] = pack8(wa[ni][0], wa[ni][1]);
  #pragma unroll
  for (int mi = 0; mi < MT; ++mi) {
    bf16x8 af = pack8(xa[mi][0], xa[mi][1]);
    #pragma unroll
    for (int ni = 0; ni < 4; ++ni)
      acc[mi][ni] = __builtin_amdgcn_mfma_f32_16x16x32_bf16(af, bfr[ni], acc[mi][ni], 0, 0, 0);
  }
}

template<int MT>
__device__ void gemm_wave_body(int bx, int by, int tid,
    const float* __restrict__ X, const float* __restrict__ W,
    const float* __restrict__ bias, float* __restrict__ C,
    int N, int Kdim, int ldx, int ldw) {
  const int lane = tid & 63, w = tid >> 6;
  const int rowl = lane & 15, kg = lane >> 4;
  const int n0 = bx * 64;
  const int m0 = (by * 4 + w) * (MT * 16);
  const float* xb = X + (long)(m0 + rowl) * ldx + kg * 8;
  const float* wb = W + (long)(n0 + rowl) * ldw + kg * 8;
  const long sx = (long)16 * ldx, sw = (long)16 * ldw;
  f32x4 acc[MT][4] = {};
  f32x4 A0[MT][2], B0[4][2], A1[MT][2], B1[4][2];
  loadk<MT>(xb, wb, sx, sw, 0, A0, B0);
  for (int k = 0; k < Kdim; k += 64) {
    loadk<MT>(xb, wb, sx, sw, k + 32, A1, B1);
    consume<MT>(A0, B0, acc);
    if (k + 64 < Kdim) loadk<MT>(xb, wb, sx, sw, k + 64, A0, B0);
    consume<MT>(A1, B1, acc);
  }
  #pragma unroll
  for (int mi = 0; mi < MT; ++mi) {
    #pragma unroll
    for (int ni = 0; ni < 4; ++ni) {
      int col = n0 + ni * 16 + rowl;
      float bv = bias ? bias[col] : 0.0f;
      int rb = m0 + mi * 16 + kg * 4;
      #pragma unroll
      for (int r = 0; r < 4; ++r)
        C[(long)(rb + r) * N + col] = acc[mi][ni][r] + bv;
    }
  }
}

// ---------------- bf16-input GEMM helpers ----------------
template<int MT>
__device__ __forceinline__ void loadk_bf(const short* xb, const short* wb,
                                         long sx, long sw, int k0,
                                         bf16x8 (&xa)[MT], bf16x8 (&wa)[4]) {
  #pragma unroll
  for (int mi = 0; mi < MT; ++mi)
    xa[mi] = *(const bf16x8*)(xb + mi * sx + k0);
  #pragma unroll
  for (int ni = 0; ni < 4; ++ni)
    wa[ni] = *(const bf16x8*)(wb + ni * sw + k0);
}

template<int MT>
__device__ __forceinline__ void consume_bf(bf16x8 (&xa)[MT], bf16x8 (&wa)[4],
                                           f32x4 (&acc)[MT][4]) {
  #pragma unroll
  for (int mi = 0; mi < MT; ++mi)
    #pragma unroll
    for (int ni = 0; ni < 4; ++ni)
      acc[mi][ni] = __builtin_amdgcn_mfma_f32_16x16x32_bf16(xa[mi], wa[ni], acc[mi][ni], 0, 0, 0);
}

// bf16 X + bf16 W -> f32 out (same tiling as gemm_wave_body)
template<int MT>
__device__ void gemm_wave_bf_body(int bx, int by, int tid,
    const short* __restrict__ Xh, const short* __restrict__ Wh,
    const float* __restrict__ bias, float* __restrict__ C,
    int N, int Kdim, int ldx, int ldw) {
  const int lane = tid & 63, w = tid >> 6;
  const int rowl = lane & 15, kg = lane >> 4;
  const int n0 = bx * 64;
  const int m0 = (by * 4 + w) * (MT * 16);
  const short* xb = Xh + (long)(m0 + rowl) * ldx + kg * 8;
  const short* wb = Wh + (long)(n0 + rowl) * ldw + kg * 8;
  const long sx = (long)16 * ldx, sw = (long)16 * ldw;
  f32x4 acc[MT][4] = {};
  bf16x8 A0[MT], B0[4], A1[MT], B1[4];
  loadk_bf<MT>(xb, wb, sx, sw, 0, A0, B0);
  for (int k = 0; k < Kdim; k += 64) {
    loadk_bf<MT>(xb, wb, sx, sw, k + 32, A1, B1);
    consume_bf<MT>(A0, B0, acc);
    if (k + 64 < Kdim) loadk_bf<MT>(xb, wb, sx, sw, k + 64, A0, B0);
    consume_bf<MT>(A1, B1, acc);
  }
  #pragma unroll
  for (int mi = 0; mi < MT; ++mi) {
    #pragma unroll
    for (int ni = 0; ni < 4; ++ni) {
      int col = n0 + ni * 16 + rowl;
      float bv = bias ? bias[col] : 0.0f;
      int rb = m0 + mi * 16 + kg * 4;
      #pragma unroll
      for (int r = 0; r < 4; ++r)
        C[(long)(rb + r) * N + col] = acc[mi][ni][r] + bv;
    }
  }
}

// bf16 X + bf16 W -> bf16 h-sliced out (trans GEMM epilogue, verified layout)
template<int MT>
__device__ void gemm_ht_bf_body(int bx, int by, int tid,
    const short* __restrict__ Xh, const short* __restrict__ Wh,
    const float* __restrict__ bias, short* __restrict__ Ch,
    int Kdim, int ldx, int ldw) {
  const int lane = tid & 63, w = tid >> 6;
  const int rowl = lane & 15, kg = lane >> 4;
  const int n0 = bx * 64;
  const int m0 = (by * 4 + w) * (MT * 16);
  const short* xb = Xh + (long)(m0 + rowl) * ldx + kg * 8;
  const short* wb = Wh + (long)(n0 + rowl) * ldw + kg * 8;
  const long sx = (long)16 * ldx, sw = (long)16 * ldw;
  f32x4 acc[MT][4] = {};
  bf16x8 A0[MT], B0[4], A1[MT], B1[4];
  loadk_bf<MT>(xb, wb, sx, sw, 0, A0, B0);
  for (int k = 0; k < Kdim; k += 64) {
    loadk_bf<MT>(xb, wb, sx, sw, k + 32, A1, B1);
    consume_bf<MT>(A0, B0, acc);
    if (k + 64 < Kdim) loadk_bf<MT>(xb, wb, sx, sw, k + 64, A0, B0);
    consume_bf<MT>(A1, B1, acc);
  }
  #pragma unroll
  for (int mi = 0; mi < MT; ++mi) {
    #pragma unroll
    for (int ni = 0; ni < 4; ++ni) {
      int col = n0 + ni * 16 + rowl;
      float bv = bias ? bias[col] : 0.0f;
      int h = col >> 4, e = col & 15;
      int rb = m0 + mi * 16 + kg * 4;
      #pragma unroll
      for (int r = 0; r < 4; ++r) {
        int rowI = rb + r;
        int b = rowI >> 9, n = rowI & 511;
        Ch[((long)(b * 64 + h) * 512 + n) * 16 + e] = f2bf(acc[mi][ni][r] + bv);
      }
    }
  }
}

// ---------------- mega1: trans bf16 MT=4 (512) + hopeG bf16 (256) + hmac f32 (16) ----------------
__global__ __launch_bounds__(256) void mega1_kernel(
    const short* __restrict__ nopb, const short* __restrict__ Wtrb,
    const float* __restrict__ btr, short* __restrict__ x12h,
    const short* __restrict__ Wob, float* __restrict__ hopeG,
    const float* __restrict__ nmac, const float* __restrict__ Wm,
    float* __restrict__ hmac) {
  const int blk = blockIdx.x, tid = threadIdx.x;
  if (blk < 512) {
    gemm_ht_bf_body<4>(blk & 15, blk >> 4, tid, nopb, Wtrb, btr, x12h, 128, 128, 128);
  } else if (blk < 768) {
    int t = blk - 512;
    gemm_wave_bf_body<1>(t & 1, t >> 1, tid, nopb, Wob, nullptr, hopeG, 128, 128, 128, 128);
  } else {
    int t = blk - 768;
    gemm_wave_body<1>(t & 1, t >> 1, tid, nmac, Wm, nullptr, hmac, 128, 64, 64, 64);
  }
}

// ---------------- attn v3: MFMA-based (verified r23/r24) ----------------
__device__ void attn3_body(int b, int h, int tid, short* __restrict__ x12h,
    const float* __restrict__ W0, const float* __restrict__ b0,
    const float* __restrict__ W1, const float* __restrict__ b1) {
  __shared__ short Pb[4][128 * 16];      // 16 KB
  __shared__ float cmw[4][16], csw[4][16];
  const int wq = tid >> 6, lane = tid & 63;
  const int rowl = lane & 15, kg = lane >> 4;
  short* slice = x12h + (long)(b * 64 + h) * 8192;
  const short* wrows = slice + (long)(wq * 128) * 16;
  const bf16x8 zero8 = {};
  bf16x8 xa[8];
  #pragma unroll
  for (int t = 0; t < 8; ++t) {
    if (kg < 2)
      xa[t] = *(const bf16x8*)(wrows + (t * 16 + rowl) * 16 + kg * 8);
    else
      xa[t] = zero8;
  }
  bf16x8 w0f = zero8;
  if (kg < 2) {
    f32x4 a = *(const f32x4*)(W0 + rowl * 16 + kg * 8);
    f32x4 c = *(const f32x4*)(W0 + rowl * 16 + kg * 8 + 4);
    w0f = pack8(a, c);
  }
  const float b0v = b0[rowl];
  f32x4 acc[8];
  #pragma unroll
  for (int t = 0; t < 8; ++t) {
    f32x4 z = {0.f, 0.f, 0.f, 0.f};
    acc[t] = __builtin_amdgcn_mfma_f32_16x16x32_bf16(xa[t], w0f, z, 0, 0, 0);
  }
  float m = -1e30f;
  #pragma unroll
  for (int t = 0; t < 8; ++t)
    #pragma unroll
    for (int r = 0; r < 4; ++r) {
      acc[t][r] += b0v;
      m = fmaxf(m, acc[t][r]);
    }
  m = fmaxf(m, __shfl_xor(m, 16));
  m = fmaxf(m, __shfl_xor(m, 32));
  if (lane < 16) cmw[wq][lane] = m;
  __syncthreads();
  const float cm = fmaxf(fmaxf(cmw[0][rowl], cmw[1][rowl]),
                         fmaxf(cmw[2][rowl], cmw[3][rowl]));
  float s = 0.f;
  #pragma unroll
  for (int t = 0; t < 8; ++t)
    #pragma unroll
    for (int r = 0; r < 4; ++r) {
      float e = __expf(acc[t][r] - cm);
      acc[t][r] = e;
      s += e;
    }
  s += __shfl_xor(s, 16);
  s += __shfl_xor(s, 32);
  if (lane < 16) csw[wq][lane] = s;
  __syncthreads();
  const float cs = csw[0][rowl] + csw[1][rowl] + csw[2][rowl] + csw[3][rowl];
  const float cinv = 1.0f / cs;
  short* pbw = Pb[wq];
  #pragma unroll
  for (int t = 0; t < 8; ++t)
    #pragma unroll
    for (int r = 0; r < 4; ++r) {
      float al = acc[t][r] * cinv;
      float rsv = al;
      rsv += __shfl_xor(rsv, 1);
      rsv += __shfl_xor(rsv, 2);
      rsv += __shfl_xor(rsv, 4);
      rsv += __shfl_xor(rsv, 8);
      float pf = al / (1e-10f + rsv);
      pbw[(t * 16 + kg * 4 + r) * 16 + rowl] = f2bf(pf);
    }
  __syncthreads();
  bf16x8 w1f = zero8;
  if (kg < 2) {
    f32x4 a = *(const f32x4*)(W1 + rowl * 16 + kg * 8);
    f32x4 c = *(const f32x4*)(W1 + rowl * 16 + kg * 8 + 4);
    w1f = pack8(a, c);
  }
  const float b1v = b1[rowl];
  #pragma unroll
  for (int t = 0; t < 8; ++t) {
    bf16x8 pa = zero8;
    if (kg < 2)
      pa = *(const bf16x8*)(pbw + (t * 16 + rowl) * 16 + kg * 8);
    f32x4 z = {0.f, 0.f, 0.f, 0.f};
    f32x4 oacc = __builtin_amdgcn_mfma_f32_16x16x32_bf16(pa, w1f, z, 0, 0, 0);
    #pragma unroll
    for (int r = 0; r < 4; ++r) {
      int n = wq * 128 + t * 16 + kg * 4 + r;
      slice[(long)n * 16 + rowl] = f2bf(oacc[r] + b1v);
    }
  }
}

// ---------------- mega2: attn3(1024) + rowdot2(2176) ----------------
__global__ __launch_bounds__(256) void mega2_kernel(
    short* __restrict__ x12h,
    const float* __restrict__ W0, const float* __restrict__ b0,
    const float* __restrict__ W1, const float* __restrict__ b1,
    const float* __restrict__ hopeG, const float* __restrict__ alo,
    float* __restrict__ ao,
    const float* __restrict__ hmac, const float* __restrict__ alm,
    float* __restrict__ am) {
  const int blk = blockIdx.x, tid = threadIdx.x;
  if (blk < 1024) {
    attn3_body(blk >> 6, blk & 63, tid, x12h, W0, b0, W1, b1);
  } else {
    int t = blk - 1024;
    int wid = t * 4 + (tid >> 6);
    int lane = tid & 63;
    const float* X; const float* al; float* out; int r;
    if (wid < 8192)       { X = hopeG; al = alo; out = ao; r = wid; }
    else if (wid < 8704)  { X = hmac;  al = alm; out = am; r = wid - 8192; }
    else return;
    const float* row = X + (long)r * 128;
    float v = fmaf(row[lane], al[lane], row[lane + 64] * al[lane + 64]);
    #pragma unroll
    for (int off = 32; off; off >>= 1) v += __shfl_down(v, off);
    if (lane == 0) out[r] = v;
  }
}

// ---------------- proj GEMM body v3: bf16 pre-converted W (Wph), verified r31 ----------------
__device__ void gemm_hx_body(int bx, int by, int tid,
    const short* __restrict__ Xh, const short* __restrict__ Wh,
    const float* __restrict__ bias, float* __restrict__ C) {
  const int lane = tid & 63, w = tid >> 6;
  const int rowl = lane & 15, kg = lane >> 4;
  const int n0 = bx * 64;
  const int m0 = (by * 4 + w) * 16;
  const int row = m0 + rowl, b = row >> 9, n = row & 511;
  const short* xb = Xh + (long)b * 524288 + (long)n * 16 + (kg & 1) * 8;
  const long hofs = kg >> 1;
  const short* wb = Wh + (long)(n0 + rowl) * 1024 + kg * 8;
  const long sw = 16 * 1024L;
  f32x4 acc[4] = {};
  bf16x8 A0, A1;
  bf16x8 Wb0[4], Wb1[4];
  A0 = *(const bf16x8*)(xb + hofs * 8192);
  #pragma unroll
  for (int ni = 0; ni < 4; ++ni)
    Wb0[ni] = *(const bf16x8*)(wb + ni * sw);
  for (int k = 0; k < 1024; k += 64) {
    A1 = *(const bf16x8*)(xb + (((k + 32) >> 4) + hofs) * 8192);
    #pragma unroll
    for (int ni = 0; ni < 4; ++ni)
      Wb1[ni] = *(const bf16x8*)(wb + ni * sw + k + 32);
    #pragma unroll
    for (int ni = 0; ni < 4; ++ni)
      acc[ni] = __builtin_amdgcn_mfma_f32_16x16x32_bf16(A0, Wb0[ni], acc[ni], 0, 0, 0);
    if (k + 64 < 1024) {
      A0 = *(const bf16x8*)(xb + (((k + 64) >> 4) + hofs) * 8192);
      #pragma unroll
      for (int ni = 0; ni < 4; ++ni)
        Wb0[ni] = *(const bf16x8*)(wb + ni * sw + k + 64);
    }
    #pragma unroll
    for (int ni = 0; ni < 4; ++ni)
      acc[ni] = __builtin_amdgcn_mfma_f32_16x16x32_bf16(A1, Wb1[ni], acc[ni], 0, 0, 0);
  }
  #pragma unroll
  for (int ni = 0; ni < 4; ++ni) {
    int col = n0 + ni * 16 + rowl;
    float bv = bias ? bias[col] : 0.0f;
    int rb = m0 + kg * 4;
    #pragma unroll
    for (int r = 0; r < 4; ++r)
      C[(long)(rb + r) * 128 + col] = acc[ni][r] + bv;
  }
}

// ---------------- GAT body: 256 threads, 2 o's/thread (verified) ----------------
__device__ void gat_body(int b, int m, int tid,
    const float* __restrict__ adj, const float* __restrict__ ao,
    const float* __restrict__ am, const float* __restrict__ hopeG,
    const float* __restrict__ hmac, float* __restrict__ hmacs) {
  __shared__ float al[NO];
  __shared__ float redA[4], redB[4];
  __shared__ float part[2][128];
  const int lane = tid & 63, w = tid >> 6;
  const float amv = am[b * NM + m];
  float av[2], ev[2];
  float mx = -1e30f;
  #pragma unroll
  for (int i = 0; i < 2; ++i) {
    int o = tid + i * 256;
    float a = adj[(b * NO + o) * NM + m];
    float e = ao[b * NO + o] + amv;
    e = (e >= 0.f) ? e : 0.2f * e;
    av[i] = a; ev[i] = e;
    if (a == 1.0f) mx = fmaxf(mx, e);
  }
  #pragma unroll
  for (int off = 32; off; off >>= 1) mx = fmaxf(mx, __shfl_down(mx, off));
  if (lane == 0) redA[w] = mx;
  __syncthreads();
  mx = fmaxf(fmaxf(redA[0], redA[1]), fmaxf(redA[2], redA[3]));
  float p[2], s = 0.f;
  #pragma unroll
  for (int i = 0; i < 2; ++i) {
    p[i] = (av[i] == 1.0f) ? __expf(ev[i] - mx) : 0.f;
    s += p[i];
  }
  #pragma unroll
  for (int off = 32; off; off >>= 1) s += __shfl_down(s, off);
  if (lane == 0) redB[w] = s;
  __syncthreads();
  s = redB[0] + redB[1] + redB[2] + redB[3];
  const float sinv = (s > 0.f) ? 1.0f / s : 0.f;
  al[tid] = p[0] * sinv;
  al[tid + 256] = p[1] * sinv;
  __syncthreads();
  const int d = tid & 127, og = tid >> 7;
  float acc0 = 0.f, acc1 = 0.f;
  const float* hb = hopeG + ((long)(b * NO) + og * 256) * DOC + d;
  #pragma unroll 8
  for (int i = 0; i < 256; i += 2) {
    acc0 = fmaf(al[og * 256 + i],     hb[(long)i * DOC],       acc0);
    acc1 = fmaf(al[og * 256 + i + 1], hb[(long)(i + 1) * DOC], acc1);
  }
  part[og][d] = acc0 + acc1;
  __syncthreads();
  if (og == 0)
    hmacs[(b * NM + m) * DOC + d] = part[0][d] + part[1][d]
                                   + hmac[(b * NM + m) * DOC + d];
}

// ---------------- mega3: proj v3(256) + gat(512, b-major XCD remap) ----------------
__global__ __launch_bounds__(256) void mega3_kernel(
    const short* __restrict__ x12h, const short* __restrict__ Wph,
    const float* __restrict__ bp, float* __restrict__ hopes,
    const float* __restrict__ adj, const float* __restrict__ ao,
    const float* __restrict__ am, const float* __restrict__ hopeG,
    const float* __restrict__ hmac, float* __restrict__ hmacs) {
  const int blk = blockIdx.x, tid = threadIdx.x;
  if (blk < 256) {
    gemm_hx_body(blk & 1, blk >> 1, tid, x12h, Wph, bp, hopes);
  } else {
    int t = blk - 256;            // t = m*16 + b  -> XCD (t%8) = b%8: all m of a
    gat_body(t & 15, t >> 4, tid, // given b share one XCD's L2 for hopeG/adj
             adj, ao, am, hopeG, hmac, hmacs);
  }
}

// ---------------- pool+up+critic: one block per b (verified r29/r30 interior) ----------------
__device__ void pool_up_body(int b, int tid,
    const float* __restrict__ hopes, const float* __restrict__ hmacs,
    const float* __restrict__ A0, const float* __restrict__ Ab0,
    const float* __restrict__ C0, const float* __restrict__ Cb0,
    const float* __restrict__ C1, const float* __restrict__ Cb1,
    const float* __restrict__ C2, const float* __restrict__ Cb2,
    float* __restrict__ po, float* __restrict__ pm, float* __restrict__ up,
    float* __restrict__ out) {
  __shared__ float part[2][128];
  __shared__ float pos[128], pms[128];
  __shared__ float zc[128];
  __shared__ float scc[2];
  const int j = tid & 127, og = tid >> 7;
  // hopes sum: each og-half covers 256 rows, coalesced 512B row reads
  const float* hb = hopes + ((long)(b * 512) + og * 256) * 128 + j;
  float a0 = 0.f, a1 = 0.f;
  #pragma unroll 8
  for (int i = 0; i < 256; i += 2) {
    a0 += hb[(long)i * 128];
    a1 += hb[(long)(i + 1) * 128];
  }
  part[og][j] = a0 + a1;
  __syncthreads();
  if (og == 0) {
    float s = (part[0][j] + part[1][j]) * (1.0f / 512.0f);
    po[b * 128 + j] = s;
    pos[j] = s;
  } else {
    const float* mb = hmacs + (long)(b * 32) * 128 + j;
    float t0 = 0.f;
    #pragma unroll 8
    for (int i = 0; i < 32; ++i) t0 += mb[(long)i * 128];
    t0 *= (1.0f / 32.0f);
    pm[b * 128 + j] = t0;
    pms[j] = t0;
  }
  __syncthreads();
  if (tid < 128) {
    const float* a1p = A0 + (long)j * 512 + 256;
    const float* a2p = A0 + (long)j * 512 + 384;
    float acc = Ab0[j];
    #pragma unroll 4
    for (int k4 = 0; k4 < 32; ++k4) {
      f32x4 av = *(const f32x4*)(a1p + k4 * 4);
      acc = fmaf(av[0], pos[k4 * 4], acc);
      acc = fmaf(av[1], pos[k4 * 4 + 1], acc);
      acc = fmaf(av[2], pos[k4 * 4 + 2], acc);
      acc = fmaf(av[3], pos[k4 * 4 + 3], acc);
    }
    #pragma unroll 4
    for (int k4 = 0; k4 < 32; ++k4) {
      f32x4 av = *(const f32x4*)(a2p + k4 * 4);
      acc = fmaf(av[0], pms[k4 * 4], acc);
      acc = fmaf(av[1], pms[k4 * 4 + 1], acc);
      acc = fmaf(av[2], pms[k4 * 4 + 2], acc);
      acc = fmaf(av[3], pms[k4 * 4 + 3], acc);
    }
    up[b * 128 + j] = acc;
    // critic layer 1: v = (pos, pms)
    float cacc = Cb0[j];
    for (int k = 0; k < 128; ++k) cacc = fmaf(C0[j * 256 + k], pos[k], cacc);
    for (int k = 0; k < 128; ++k) cacc = fmaf(C0[j * 256 + 128 + k], pms[k], cacc);
    zc[j] = fast_tanh(cacc);
  }
  __syncthreads();
  if (tid < 128) {
    float acc2 = Cb1[j];
    for (int k = 0; k < 128; ++k) acc2 = fmaf(C1[j * 128 + k], zc[k], acc2);
    float z2 = fast_tanh(acc2);
    float p = C2[j] * z2;
    #pragma unroll
    for (int off = 32; off; off >>= 1) p += __shfl_down(p, off);
    const int lane = tid & 63, w = tid >> 6;
    if (lane == 0) scc[w] = p;
  }
  __syncthreads();
  if (tid == 0) out[16 + b] = scc[0] + scc[1] + Cb2[0];   // state_values
}

// ---------------- mega4 v3: pool+up+critic(16) + UoGEMM(256) + UmhmGEMM(16) ----------------
__global__ __launch_bounds__(256) void mega4_kernel(
    const float* __restrict__ hopes, const float* __restrict__ hmacs,
    const float* __restrict__ A0, const float* __restrict__ Ab0,
    const float* __restrict__ C0, const float* __restrict__ Cb0,
    const float* __restrict__ C1, const float* __restrict__ Cb1,
    const float* __restrict__ C2, const float* __restrict__ Cb2,
    float* __restrict__ po, float* __restrict__ pm, float* __restrict__ up,
    float* __restrict__ Uo, float* __restrict__ umhm,
    float* __restrict__ out) {
  const int blk = blockIdx.x, tid = threadIdx.x;
  if (blk < 16) {
    pool_up_body(blk, tid, hopes, hmacs, A0, Ab0, C0, Cb0, C1, Cb1, C2, Cb2,
                 po, pm, up, out);
  } else if (blk < 272) {
    int t = blk - 16;
    gemm_wave_body<1>(t & 1, t >> 1, tid, hopes, A0, nullptr, Uo, 128, 128, 128, 512);
  } else {
    int t = blk - 272;            // M=512 rows of hmacs, W=A0 cols 128:256
    gemm_wave_body<1>(t & 1, t >> 1, tid, hmacs, A0 + 128, nullptr, umhm, 128, 128, 128, 512);
  }
}

// ---------------- actor v9: fused per-wave masked softmax partials (verified r27/r28/r30) ----------------
__global__ __launch_bounds__(256) void actor_mfma9_kernel(
    const float* __restrict__ Uo, const float* __restrict__ umhm,
    const float* __restrict__ up, const short* __restrict__ A1p,
    const float* __restrict__ Ab1, const float* __restrict__ A2,
    const float* __restrict__ Ab2, const void* __restrict__ maskp,
    const int* __restrict__ flag, float* __restrict__ logits,
    float* __restrict__ partw) {
  const int tid = threadIdx.x;
  const int blk = blockIdx.x;
  const int oc = blk & 7;
  const int mg = (blk >> 3) & 7;
  const int b  = blk >> 6;
  const int obase = oc * 64;
  const int m0 = mg * 4;
  const int lane = tid & 63, w = tid >> 6;
  const int rowl = lane & 15, kg = lane >> 4;
  const float* uo = Uo + (long)(b * NO + obase + w * 16 + rowl) * 128;
  const float* upb = up + b * 128;
  const float* umb = umhm + (b * NM + m0) * 128;
  bf16x8 af[4][4];                       // [mi][kk]
  #pragma unroll
  for (int kk = 0; kk < 4; ++kk) {
    int kb = kk * 32 + kg * 8;
    f32x4 u0 = *(const f32x4*)(uo + kb);
    f32x4 u1 = *(const f32x4*)(uo + kb + 4);
    f32x4 p0 = *(const f32x4*)(upb + kb);
    f32x4 p1 = *(const f32x4*)(upb + kb + 4);
    float base0[4], base1[4];
    #pragma unroll
    for (int e = 0; e < 4; ++e) {
      base0[e] = u0[e] + p0[e];
      base1[e] = u1[e] + p1[e];
    }
    #pragma unroll
    for (int mi = 0; mi < 4; ++mi) {
      f32x4 a0 = *(const f32x4*)(umb + mi * 128 + kb);
      f32x4 a1 = *(const f32x4*)(umb + mi * 128 + kb + 4);
      float t[8];
      #pragma unroll
      for (int e = 0; e < 4; ++e) {
        t[e]     = fast_tanh(base0[e] + a0[e]);
        t[4 + e] = fast_tanh(base1[e] + a1[e]);
      }
      af[mi][kk] = pack8f(t);
    }
  }
  float pr[4][4] = {};
  #pragma unroll
  for (int ct = 0; ct < 8; ++ct) {
    const int col = ct * 16 + rowl;
    bf16x8 bf[4];
    #pragma unroll
    for (int kk = 0; kk < 4; ++kk)
      bf[kk] = *(const bf16x8*)(A1p + ((kk * 4 + kg) * 128 + col) * 8);
    f32x4 ac[4] = {};
    #pragma unroll
    for (int kk = 0; kk < 4; ++kk)
      #pragma unroll
      for (int mi = 0; mi < 4; ++mi)
        ac[mi] = __builtin_amdgcn_mfma_f32_16x16x32_bf16(af[mi][kk], bf[kk], ac[mi], 0, 0, 0);
    const float ab = Ab1[col], a2c = A2[col];
    #pragma unroll
    for (int mi = 0; mi < 4; ++mi)
      #pragma unroll
      for (int r = 0; r < 4; ++r) {
        float z = fast_tanh(ac[mi][r] + ab);
        pr[mi][r] = fmaf(a2c, z, pr[mi][r]);
      }
  }
  const float ab2 = Ab2[0];
  // butterfly-reduce; keep all 16 final logits per lane (identical across rowl)
  float rv[4][4];                        // [r][mi]
  #pragma unroll
  for (int r = 0; r < 4; ++r) {
    float v0 = pr[0][r], v1 = pr[1][r], v2 = pr[2][r], v3 = pr[3][r];
    #pragma unroll
    for (int off = 1; off < 16; off <<= 1) {
      v0 += __shfl_xor(v0, off);
      v1 += __shfl_xor(v1, off);
      v2 += __shfl_xor(v2, off);
      v3 += __shfl_xor(v3, off);
    }
    rv[r][0] = v0 + ab2; rv[r][1] = v1 + ab2;
    rv[r][2] = v2 + ab2; rv[r][3] = v3 + ab2;
  }
  const long base0 = ((long)b << 14) + (long)m0 * 512 + obase + w * 16 + kg * 4;
  if (rowl == 0) {
    #pragma unroll
    for (int r = 0; r < 4; ++r) {
      logits[base0 + r]        = rv[r][0];
      logits[base0 + 512 + r]  = rv[r][1];
      logits[base0 + 1024 + r] = rv[r][2];
      logits[base0 + 1536 + r] = rv[r][3];
    }
  }
  // fused masked softmax partial: lane covers o = obase+w*16+kg*4+r, m = m0+mi
  const bool word_mode = (flag[0] == 0);
  const int ob = obase + w * 16 + kg * 4;
  bool mk[4][4];
  if (word_mode) {
    const unsigned int* mw = (const unsigned int*)maskp;
    #pragma unroll
    for (int r = 0; r < 4; ++r) {
      long mo = (long)(b * NO + ob + r) * NM + m0;
      #pragma unroll
      for (int mi = 0; mi < 4; ++mi) mk[r][mi] = (mw[mo + mi] != 0u);
    }
  } else {
    const unsigned char* mb = (const unsigned char*)maskp;
    #pragma unroll
    for (int r = 0; r < 4; ++r) {
      long mo = (long)(b * NO + ob + r) * NM + m0;
      #pragma unroll
      for (int mi = 0; mi < 4; ++mi) mk[r][mi] = (mb[mo + mi] != 0);
    }
  }
  float lm = -1e30f;
  #pragma unroll
  for (int r = 0; r < 4; ++r)
    #pragma unroll
    for (int mi = 0; mi < 4; ++mi)
      if (mk[r][mi]) lm = fmaxf(lm, rv[r][mi]);
  float lS = 0.f, lT = 0.f;
  #pragma unroll
  for (int r = 0; r < 4; ++r)
    #pragma unroll
    for (int mi = 0; mi < 4; ++mi)
      if (mk[r][mi]) {
        float d = rv[r][mi] - lm;
        float e = __expf(d);
        lS += e; lT += e * d;
      }
  // merge across kg groups only (rowl lanes are duplicates)
  #pragma unroll
  for (int off = 16; off < 64; off <<= 1) {
    float om = __shfl_xor(lm, off);
    float oS = __shfl_xor(lS, off);
    float oT = __shfl_xor(lT, off);
    smmerge(lm, lS, lT, om, oS, oT);
  }
  if (lane == 0) {
    float* pp = partw + ((long)blk * 4 + w) * 3;
    pp[0] = lm; pp[1] = lS; pp[2] = lT;
  }
}

// ---------------- final_ab: 256-triple combine + gather + entropy (16 blocks x 64) ----------------
__global__ __launch_bounds__(64) void final_ab_kernel(
    const float* __restrict__ part, const float* __restrict__ logits,
    const int* __restrict__ aidx, float* __restrict__ out) {
  const int b = blockIdx.x;
  const int lane = threadIdx.x;
  float lm = -3e30f, lS = 0.f, lT = 0.f;
  const float* pp = part + ((long)b * 256 + lane * 4) * 3;
  #pragma unroll
  for (int t = 0; t < 4; ++t)
    smmerge(lm, lS, lT, pp[t * 3], pp[t * 3 + 1], pp[t * 3 + 2]);
  #pragma unroll
  for (int off = 1; off < 64; off <<= 1) {
    float om = __shfl_xor(lm, off);
    float oS = __shfl_xor(lS, off);
    float oT = __shfl_xor(lT, off);
    smmerge(lm, lS, lT, om, oS, oT);
  }
  if (lane == 0) {
    float lSm = logf(lS);
    out[b] = logits[(long)b * (NM * NO) + aidx[b]] - lm - lSm;  // action_logprobs
    out[32 + b] = lSm - lT / lS;                                // dist_entropys
  }
}

extern "C" void kernel_launch(void* const* d_in, const int* in_sizes, int n_in,
                              void* d_out, int out_size, void* d_ws, size_t ws_size,
                              hipStream_t stream) {
  (void)in_sizes; (void)n_in; (void)out_size; (void)ws_size;
  const float* adj  = (const float*)d_in[0];
  const float* nop  = (const float*)d_in[1];
  const float* nmac = (const float*)d_in[2];
  const void*  maskp = d_in[3];
  const int*   aidx = (const int*)d_in[4];
  const float* Wtr  = (const float*)d_in[5];
  const float* btr  = (const float*)d_in[6];
  const float* W0   = (const float*)d_in[7];
  const float* b0   = (const float*)d_in[8];
  const float* W1   = (const float*)d_in[9];
  const float* b1   = (const float*)d_in[10];
  const float* Wp   = (const float*)d_in[11];
  const float* bp   = (const float*)d_in[12];
  const float* Wo   = (const float*)d_in[13];
  const float* Wm   = (const float*)d_in[14];
  const float* alo  = (const float*)d_in[15];
  const float* alm  = (const float*)d_in[16];
  const float* A0   = (const float*)d_in[17];
  const float* Ab0  = (const float*)d_in[18];
  const float* A1   = (const float*)d_in[19];
  const float* Ab1  = (const float*)d_in[20];
  const float* A2   = (const float*)d_in[21];
  const float* Ab2  = (const float*)d_in[22];
  const float* C0   = (const float*)d_in[23];
  const float* Cb0  = (const float*)d_in[24];
  const float* C1   = (const float*)d_in[25];
  const float* Cb1  = (const float*)d_in[26];
  const float* C2   = (const float*)d_in[27];
  const float* Cb2  = (const float*)d_in[28];

  float* ws     = (float*)d_ws;        // needs ~47 MiB
  short* x12h   = (short*)(ws + OFF_X12);
  float* hopes  = ws + OFF_HOPES;
  float* hopeG  = ws + OFF_HOPEG;
  float* hmac   = ws + OFF_HMAC;
  float* hmacs  = ws + OFF_HMACS;
  float* ao     = ws + OFF_AO;
  float* am     = ws + OFF_AM;
  float* po     = ws + OFF_PO;
  float* pm     = ws + OFF_PM;
  float* Uo     = ws + OFF_UO;
  float* umhm   = ws + OFF_UMHM;
  float* logits = ws + OFF_LOG;
  float* up     = ws + OFF_UP;
  short* A1p    = (short*)(ws + OFF_A1P);
  short* Wph    = (short*)(ws + OFF_WPH);
  short* nopb   = (short*)(ws + OFF_NOPB);
  short* Wtrb   = (short*)(ws + OFF_WTRB);
  short* Wob    = (short*)(ws + OFF_WOB);
  int*   flag   = (int*)(ws + OFF_FLAG);
  float* partw  = ws + OFF_PART2;
  float* outp   = (float*)d_out;

  // 0: pre-convert nop/Wtr/Wo/A1/Wp to bf16 + mask-probe
  mega0_kernel<<<713, 256, 0, stream>>>(nop, nopb, Wtr, Wtrb, Wo, Wob,
                                        A1, A1p, Wp, Wph,
                                        (const unsigned int*)maskp, flag);
  // 1: trans bf16 (MT=4) + hopeG bf16 + hmac f32
  mega1_kernel<<<784, 256, 0, stream>>>(nopb, Wtrb, btr, x12h, Wob, hopeG,
                                        nmac, Wm, hmac);
  // 2: attention middle (MFMA) + rowdots
  mega2_kernel<<<3200, 256, 0, stream>>>(x12h, W0, b0, W1, b1,
                                         hopeG, alo, ao, hmac, alm, am);
  // 3: proj v3 (bf16 W) + gat (b-major XCD remap)
  mega3_kernel<<<768, 256, 0, stream>>>(x12h, Wph, bp, hopes,
                                        adj, ao, am, hopeG, hmac, hmacs);
  // 4: pool+up+critic + Uo GEMM + Um-hmacs GEMM
  mega4_kernel<<<288, 256, 0, stream>>>(hopes, hmacs, A0, Ab0,
                                        C0, Cb0, C1, Cb1, C2, Cb2,
                                        po, pm, up, Uo, umhm, outp);
  // 5: actor v9 (fused softmax partials)
  actor_mfma9_kernel<<<1024, 256, 0, stream>>>(Uo, umhm, up, A1p, Ab1, A2, Ab2,
                                               maskp, flag, logits, partw);
  // 6: combine(256 triples) + gather + entropy
  final_ab_kernel<<<16, 64, 0, stream>>>(partw, logits, aidx, outp);
}

// Round 33
// 121.282 us; speedup vs baseline: 1.2969x; 1.0148x over previous
//
#include <hip/hip_runtime.h>

#define BB 16
#define NO 512
#define NM 32
#define DOC 128
#define C8 1024
#define NH 64
#define KD 16

// ---------------- ws layout (float offsets), ~47 MiB used ----------------
#define OFF_X12   0          // [16][64][512][16] bf16 h-sliced x1/x2 (in-place)
#define OFF_UO    0          // [8192,128] f32 (alias: x12h dead by then)
#define OFF_LOG   1048576    // [16,16384] (alias, after Uo)
#define OFF_HOPES 8388608    // [8192,128] ext-attn output
#define OFF_HOPEG 9437184    // [8192,128] GAT h_ope
#define OFF_HMAC  10485760   // [512,128]  GAT h_mac (pre)
#define OFF_HMACS 10551296   // [512,128]  GAT output
#define OFF_AO    10616832   // [8192]
#define OFF_AM    10625024   // [512]
#define OFF_PO    10625536   // [16,128]
#define OFF_PM    10627584   // [16,128]
#define OFF_UMHM  10629632   // [512,128]  hmacs-part of Um (MFMA)
#define OFF_FLAG  10695168   // int flag (mask dtype probe)
#define OFF_UP    10720000   // [16,128]   Up[b] = A0[:,256:512]*(po,pm)+Ab0
#define OFF_PART2 10750000   // [4096,3] per-wave actor softmax partials
#define OFF_A1P   10900000   // [16384] bf16 A1 pre-converted (OUTSIDE x12h!)
#define OFF_WPH   11000000   // [131072] bf16 Wp pre-converted (65536 floats)
#define OFF_NOPB  11100000   // [1048576] bf16 nop pre-converted (524288 floats)
#define OFF_WTRB  11650000   // [131072] bf16 Wtr (65536 floats)
#define OFF_WOB   11720000   // [16384] bf16 Wo (8192 floats)
#define OFF_A0B   11730000   // [131072] bf16 A0 (65536 floats)

using f32x4  = __attribute__((ext_vector_type(4))) float;
using s16x4  = __attribute__((ext_vector_type(4))) short;
using bf16x8 = __attribute__((ext_vector_type(8))) short;   // 8 bf16 (4 VGPRs)

// clamp-free: exp(2x)->{0,inf} at extremes gives exactly -1/+1 via rcp
__device__ __forceinline__ float fast_tanh(float x) {
  float e = __expf(2.0f * x);
  return 1.0f - 2.0f * __builtin_amdgcn_rcpf(e + 1.0f);
}

__device__ __forceinline__ short f2bf(float f) {          // RNE f32->bf16
  unsigned u = __builtin_bit_cast(unsigned, f);
  u += 0x7FFFu + ((u >> 16) & 1u);
  return (short)(u >> 16);
}

__device__ __forceinline__ float bf2f(short s) {
  return __builtin_bit_cast(float, ((unsigned)(unsigned short)s) << 16);
}

__device__ __forceinline__ unsigned cvtpk(float a, float b) {
  unsigned r;
  asm("v_cvt_pk_bf16_f32 %0, %1, %2" : "=v"(r) : "v"(a), "v"(b));
  return r;
}

__device__ __forceinline__ bf16x8 pack8(f32x4 u0, f32x4 u1) {
  union { unsigned u[4]; bf16x8 v; } cv;
  cv.u[0] = cvtpk(u0[0], u0[1]);
  cv.u[1] = cvtpk(u0[2], u0[3]);
  cv.u[2] = cvtpk(u1[0], u1[1]);
  cv.u[3] = cvtpk(u1[2], u1[3]);
  return cv.v;
}

__device__ __forceinline__ bf16x8 pack8f(const float* t) {
  union { unsigned u[4]; bf16x8 v; } cv;
  cv.u[0] = cvtpk(t[0], t[1]);
  cv.u[1] = cvtpk(t[2], t[3]);
  cv.u[2] = cvtpk(t[4], t[5]);
  cv.u[3] = cvtpk(t[6], t[7]);
  return cv.v;
}

// online-softmax partial merge: (Ma,Sa,Ta) += (Mb,Sb,Tb)
__device__ __forceinline__ void smmerge(float& lm, float& lS, float& lT,
                                        float om, float oS, float oT) {
  float nm = fmaxf(lm, om);
  float ea = __expf(lm - nm), eb = __expf(om - nm);
  lT = (lT + (lm - nm) * lS) * ea + (oT + (om - nm) * oS) * eb;
  lS = lS * ea + oS * eb;
  lm = nm;
}

// ---------------- mask dtype probe (body) ----------------
__device__ void probe_body(int tid, const unsigned int* __restrict__ mask,
                           int* __restrict__ flag) {
  __shared__ int s[4];
  int bad = 0;
  for (int i = tid; i < 4096; i += 256) {
    unsigned int v = mask[i];
    if (!(v == 0u || v == 1u || v == 0x3f800000u)) bad = 1;
  }
  unsigned long long any = __ballot(bad);
  int lane = tid & 63, w = tid >> 6;
  if (lane == 0) s[w] = (any != 0ull) ? 1 : 0;
  __syncthreads();
  if (tid == 0) flag[0] = s[0] | s[1] | s[2] | s[3];
}

// ---------------- converters ----------------
__device__ void convert8_body(int blk, int tid,
    const float* __restrict__ src, short* __restrict__ dst) {
  int i = (blk * 256 + tid) * 8;
  f32x4 a = *(const f32x4*)(src + i);
  f32x4 b = *(const f32x4*)(src + i + 4);
  *(bf16x8*)(dst + i) = pack8(a, b);
}

__device__ void convert_a1_body(int blk, int tid,
    const float* __restrict__ A1, short* __restrict__ A1p) {
  int i = blk * 256 + tid;
  int col = i >> 7, k = i & 127;
  A1p[((k >> 3) * 128 + col) * 8 + (k & 7)] = f2bf(A1[i]);
}

// ---------------- mega0: all pre-conversions + probe ----------------
// nop(512) + Wtr(64) + Wo(8) + A1(64) + Wp(64) + A0(32) + probe(1) = 745 blocks
__global__ __launch_bounds__(256) void mega0_kernel(
    const float* __restrict__ nop, short* __restrict__ nopb,
    const float* __restrict__ Wtr, short* __restrict__ Wtrb,
    const float* __restrict__ Wo, short* __restrict__ Wob,
    const float* __restrict__ A1, short* __restrict__ A1p,
    const float* __restrict__ Wp, short* __restrict__ Wph,
    const float* __restrict__ A0, short* __restrict__ A0b,
    const unsigned int* __restrict__ mask, int* __restrict__ flag) {
  const int blk = blockIdx.x, tid = threadIdx.x;
  if (blk < 512) {
    convert8_body(blk, tid, nop, nopb);
  } else if (blk < 576) {
    convert8_body(blk - 512, tid, Wtr, Wtrb);
  } else if (blk < 584) {
    convert8_body(blk - 576, tid, Wo, Wob);
  } else if (blk < 648) {
    convert_a1_body(blk - 584, tid, A1, A1p);
  } else if (blk < 712) {
    convert8_body(blk - 648, tid, Wp, Wph);
  } else if (blk < 744) {
    convert8_body(blk - 712, tid, A0, A0b);
  } else {
    probe_body(tid, mask, flag);
  }
}

// ---------------- GEMM bodies (f32, verbatim, verified) ----------------
template<int MT>
__device__ __forceinline__ void loadk(const float* xb, const float* wb,
                                      long sx, long sw, int k0,
                                      f32x4 (&xa)[MT][2], f32x4 (&wa)[4][2]) {
  #pragma unroll
  for (int mi = 0; mi < MT; ++mi) {
    xa[mi][0] = *(const f32x4*)(xb + mi * sx + k0);
    xa[mi][1] = *(const f32x4*)(xb + mi * sx + k0 + 4);
  }
  #pragma unroll
  for (int ni = 0; ni < 4; ++ni) {
    wa[ni][0] = *(const f32x4*)(wb + ni * sw + k0);
    wa[ni][1] = *(const f32x4*)(wb + ni * sw + k0 + 4);
  }
}

template<int MT>
__device__ __forceinline__ void consume(f32x4 (&xa)[MT][2], f32x4 (&wa)[4][2],
                                        f32x4 (&acc)[MT][4]) {
  bf16x8 bfr[4];
  #pragma unroll
  for (int ni = 0; ni < 4; ++ni) bfr[ni] = pack8(wa[ni][0], wa[ni][1]);
  #pragma unroll
  for (int mi = 0; mi < MT; ++mi) {
    bf16x8 af = pack8(xa[mi][0], xa[mi][1]);
    #pragma unroll
    for (int ni = 0; ni < 4; ++ni)
      acc[mi][ni] = __builtin_amdgcn_mfma_f32_16x16x32_bf16(af, bfr[ni], acc[mi][ni], 0, 0, 0);
  }
}

template<int MT>
__device__ void gemm_wave_body(int bx, int by, int tid,
    const float* __restrict__ X, const float* __restrict__ W,
    const float* __restrict__ bias, float* __restrict__ C,
    int N, int Kdim, int ldx, int ldw) {
  const int lane = tid & 63, w = tid >> 6;
  const int rowl = lane & 15, kg = lane >> 4;
  const int n0 = bx * 64;
  const int m0 = (by * 4 + w) * (MT * 16);
  const float* xb = X + (long)(m0 + rowl) * ldx + kg * 8;
  const float* wb = W + (long)(n0 + rowl) * ldw + kg * 8;
  const long sx = (long)16 * ldx, sw = (long)16 * ldw;
  f32x4 acc[MT][4] = {};
  f32x4 A0[MT][2], B0[4][2], A1[MT][2], B1[4][2];
  loadk<MT>(xb, wb, sx, sw, 0, A0, B0);
  for (int k = 0; k < Kdim; k += 64) {
    loadk<MT>(xb, wb, sx, sw, k + 32, A1, B1);
    consume<MT>(A0, B0, acc);
    if (k + 64 < Kdim) loadk<MT>(xb, wb, sx, sw, k + 64, A0, B0);
    consume<MT>(A1, B1, acc);
  }
  #pragma unroll
  for (int mi = 0; mi < MT; ++mi) {
    #pragma unroll
    for (int ni = 0; ni < 4; ++ni) {
      int col = n0 + ni * 16 + rowl;
      float bv = bias ? bias[col] : 0.0f;
      int rb = m0 + mi * 16 + kg * 4;
      #pragma unroll
      for (int r = 0; r < 4; ++r)
        C[(long)(rb + r) * N + col] = acc[mi][ni][r] + bv;
    }
  }
}

// ---------------- bf16-input GEMM helpers ----------------
template<int MT>
__device__ __forceinline__ void loadk_bf(const short* xb, const short* wb,
                                         long sx, long sw, int k0,
                                         bf16x8 (&xa)[MT], bf16x8 (&wa)[4]) {
  #pragma unroll
  for (int mi = 0; mi < MT; ++mi)
    xa[mi] = *(const bf16x8*)(xb + mi * sx + k0);
  #pragma unroll
  for (int ni = 0; ni < 4; ++ni)
    wa[ni] = *(const bf16x8*)(wb + ni * sw + k0);
}

template<int MT>
__device__ __forceinline__ void consume_bf(bf16x8 (&xa)[MT], bf16x8 (&wa)[4],
                                           f32x4 (&acc)[MT][4]) {
  #pragma unroll
  for (int mi = 0; mi < MT; ++mi)
    #pragma unroll
    for (int ni = 0; ni < 4; ++ni)
      acc[mi][ni] = __builtin_amdgcn_mfma_f32_16x16x32_bf16(xa[mi], wa[ni], acc[mi][ni], 0, 0, 0);
}

// bf16 X + bf16 W -> f32 out (same tiling as gemm_wave_body)
template<int MT>
__device__ void gemm_wave_bf_body(int bx, int by, int tid,
    const short* __restrict__ Xh, const short* __restrict__ Wh,
    const float* __restrict__ bias, float* __restrict__ C,
    int N, int Kdim, int ldx, int ldw) {
  const int lane = tid & 63, w = tid >> 6;
  const int rowl = lane & 15, kg = lane >> 4;
  const int n0 = bx * 64;
  const int m0 = (by * 4 + w) * (MT * 16);
  const short* xb = Xh + (long)(m0 + rowl) * ldx + kg * 8;
  const short* wb = Wh + (long)(n0 + rowl) * ldw + kg * 8;
  const long sx = (long)16 * ldx, sw = (long)16 * ldw;
  f32x4 acc[MT][4] = {};
  bf16x8 A0[MT], B0[4], A1[MT], B1[4];
  loadk_bf<MT>(xb, wb, sx, sw, 0, A0, B0);
  for (int k = 0; k < Kdim; k += 64) {
    loadk_bf<MT>(xb, wb, sx, sw, k + 32, A1, B1);
    consume_bf<MT>(A0, B0, acc);
    if (k + 64 < Kdim) loadk_bf<MT>(xb, wb, sx, sw, k + 64, A0, B0);
    consume_bf<MT>(A1, B1, acc);
  }
  #pragma unroll
  for (int mi = 0; mi < MT; ++mi) {
    #pragma unroll
    for (int ni = 0; ni < 4; ++ni) {
      int col = n0 + ni * 16 + rowl;
      float bv = bias ? bias[col] : 0.0f;
      int rb = m0 + mi * 16 + kg * 4;
      #pragma unroll
      for (int r = 0; r < 4; ++r)
        C[(long)(rb + r) * N + col] = acc[mi][ni][r] + bv;
    }
  }
}

// f32 X (runtime pack) + bf16 W (direct load) -> f32 out
template<int MT>
__device__ void gemm_wave_fb_body(int bx, int by, int tid,
    const float* __restrict__ X, const short* __restrict__ Wh,
    const float* __restrict__ bias, float* __restrict__ C,
    int N, int Kdim, int ldx, int ldw) {
  const int lane = tid & 63, w = tid >> 6;
  const int rowl = lane & 15, kg = lane >> 4;
  const int n0 = bx * 64;
  const int m0 = (by * 4 + w) * (MT * 16);
  const float* xb = X + (long)(m0 + rowl) * ldx + kg * 8;
  const short* wb = Wh + (long)(n0 + rowl) * ldw + kg * 8;
  const long sx = (long)16 * ldx, sw = (long)16 * ldw;
  f32x4 acc[MT][4] = {};
  f32x4 A0[MT][2], A1[MT][2];
  bf16x8 B0[4], B1[4];
  #pragma unroll
  for (int mi = 0; mi < MT; ++mi) {
    A0[mi][0] = *(const f32x4*)(xb + mi * sx);
    A0[mi][1] = *(const f32x4*)(xb + mi * sx + 4);
  }
  #pragma unroll
  for (int ni = 0; ni < 4; ++ni) B0[ni] = *(const bf16x8*)(wb + ni * sw);
  for (int k = 0; k < Kdim; k += 64) {
    #pragma unroll
    for (int mi = 0; mi < MT; ++mi) {
      A1[mi][0] = *(const f32x4*)(xb + mi * sx + k + 32);
      A1[mi][1] = *(const f32x4*)(xb + mi * sx + k + 36);
    }
    #pragma unroll
    for (int ni = 0; ni < 4; ++ni) B1[ni] = *(const bf16x8*)(wb + ni * sw + k + 32);
    #pragma unroll
    for (int mi = 0; mi < MT; ++mi) {
      bf16x8 af = pack8(A0[mi][0], A0[mi][1]);
      #pragma unroll
      for (int ni = 0; ni < 4; ++ni)
        acc[mi][ni] = __builtin_amdgcn_mfma_f32_16x16x32_bf16(af, B0[ni], acc[mi][ni], 0, 0, 0);
    }
    if (k + 64 < Kdim) {
      #pragma unroll
      for (int mi = 0; mi < MT; ++mi) {
        A0[mi][0] = *(const f32x4*)(xb + mi * sx + k + 64);
        A0[mi][1] = *(const f32x4*)(xb + mi * sx + k + 68);
      }
      #pragma unroll
      for (int ni = 0; ni < 4; ++ni) B0[ni] = *(const bf16x8*)(wb + ni * sw + k + 64);
    }
    #pragma unroll
    for (int mi = 0; mi < MT; ++mi) {
      bf16x8 af = pack8(A1[mi][0], A1[mi][1]);
      #pragma unroll
      for (int ni = 0; ni < 4; ++ni)
        acc[mi][ni] = __builtin_amdgcn_mfma_f32_16x16x32_bf16(af, B1[ni], acc[mi][ni], 0, 0, 0);
    }
  }
  #pragma unroll
  for (int mi = 0; mi < MT; ++mi) {
    #pragma unroll
    for (int ni = 0; ni < 4; ++ni) {
      int col = n0 + ni * 16 + rowl;
      float bv = bias ? bias[col] : 0.0f;
      int rb = m0 + mi * 16 + kg * 4;
      #pragma unroll
      for (int r = 0; r < 4; ++r)
        C[(long)(rb + r) * N + col] = acc[mi][ni][r] + bv;
    }
  }
}

// bf16 X + bf16 W -> bf16 h-sliced out (trans GEMM epilogue, verified layout)
template<int MT>
__device__ void gemm_ht_bf_body(int bx, int by, int tid,
    const short* __restrict__ Xh, const short* __restrict__ Wh,
    const float* __restrict__ bias, short* __restrict__ Ch,
    int Kdim, int ldx, int ldw) {
  const int lane = tid & 63, w = tid >> 6;
  const int rowl = lane & 15, kg = lane >> 4;
  const int n0 = bx * 64;
  const int m0 = (by * 4 + w) * (MT * 16);
  const short* xb = Xh + (long)(m0 + rowl) * ldx + kg * 8;
  const short* wb = Wh + (long)(n0 + rowl) * ldw + kg * 8;
  const long sx = (long)16 * ldx, sw = (long)16 * ldw;
  f32x4 acc[MT][4] = {};
  bf16x8 A0[MT], B0[4], A1[MT], B1[4];
  loadk_bf<MT>(xb, wb, sx, sw, 0, A0, B0);
  for (int k = 0; k < Kdim; k += 64) {
    loadk_bf<MT>(xb, wb, sx, sw, k + 32, A1, B1);
    consume_bf<MT>(A0, B0, acc);
    if (k + 64 < Kdim) loadk_bf<MT>(xb, wb, sx, sw, k + 64, A0, B0);
    consume_bf<MT>(A1, B1, acc);
  }
  #pragma unroll
  for (int mi = 0; mi < MT; ++mi) {
    #pragma unroll
    for (int ni = 0; ni < 4; ++ni) {
      int col = n0 + ni * 16 + rowl;
      float bv = bias ? bias[col] : 0.0f;
      int h = col >> 4, e = col & 15;
      int rb = m0 + mi * 16 + kg * 4;
      #pragma unroll
      for (int r = 0; r < 4; ++r) {
        int rowI = rb + r;
        int b = rowI >> 9, n = rowI & 511;
        Ch[((long)(b * 64 + h) * 512 + n) * 16 + e] = f2bf(acc[mi][ni][r] + bv);
      }
    }
  }
}

// ---------------- mega1: trans bf16 MT=4 (512) + hopeG bf16 (256) + hmac f32 (16) ----------------
__global__ __launch_bounds__(256) void mega1_kernel(
    const short* __restrict__ nopb, const short* __restrict__ Wtrb,
    const float* __restrict__ btr, short* __restrict__ x12h,
    const short* __restrict__ Wob, float* __restrict__ hopeG,
    const float* __restrict__ nmac, const float* __restrict__ Wm,
    float* __restrict__ hmac) {
  const int blk = blockIdx.x, tid = threadIdx.x;
  if (blk < 512) {
    gemm_ht_bf_body<4>(blk & 15, blk >> 4, tid, nopb, Wtrb, btr, x12h, 128, 128, 128);
  } else if (blk < 768) {
    int t = blk - 512;
    gemm_wave_bf_body<1>(t & 1, t >> 1, tid, nopb, Wob, nullptr, hopeG, 128, 128, 128, 128);
  } else {
    int t = blk - 768;
    gemm_wave_body<1>(t & 1, t >> 1, tid, nmac, Wm, nullptr, hmac, 128, 64, 64, 64);
  }
}

// ---------------- attn v3: MFMA-based (verified r23/r24) ----------------
__device__ void attn3_body(int b, int h, int tid, short* __restrict__ x12h,
    const float* __restrict__ W0, const float* __restrict__ b0,
    const float* __restrict__ W1, const float* __restrict__ b1) {
  __shared__ short Pb[4][128 * 16];      // 16 KB
  __shared__ float cmw[4][16], csw[4][16];
  const int wq = tid >> 6, lane = tid & 63;
  const int rowl = lane & 15, kg = lane >> 4;
  short* slice = x12h + (long)(b * 64 + h) * 8192;
  const short* wrows = slice + (long)(wq * 128) * 16;
  const bf16x8 zero8 = {};
  bf16x8 xa[8];
  #pragma unroll
  for (int t = 0; t < 8; ++t) {
    if (kg < 2)
      xa[t] = *(const bf16x8*)(wrows + (t * 16 + rowl) * 16 + kg * 8);
    else
      xa[t] = zero8;
  }
  bf16x8 w0f = zero8;
  if (kg < 2) {
    f32x4 a = *(const f32x4*)(W0 + rowl * 16 + kg * 8);
    f32x4 c = *(const f32x4*)(W0 + rowl * 16 + kg * 8 + 4);
    w0f = pack8(a, c);
  }
  const float b0v = b0[rowl];
  f32x4 acc[8];
  #pragma unroll
  for (int t = 0; t < 8; ++t) {
    f32x4 z = {0.f, 0.f, 0.f, 0.f};
    acc[t] = __builtin_amdgcn_mfma_f32_16x16x32_bf16(xa[t], w0f, z, 0, 0, 0);
  }
  float m = -1e30f;
  #pragma unroll
  for (int t = 0; t < 8; ++t)
    #pragma unroll
    for (int r = 0; r < 4; ++r) {
      acc[t][r] += b0v;
      m = fmaxf(m, acc[t][r]);
    }
  m = fmaxf(m, __shfl_xor(m, 16));
  m = fmaxf(m, __shfl_xor(m, 32));
  if (lane < 16) cmw[wq][lane] = m;
  __syncthreads();
  const float cm = fmaxf(fmaxf(cmw[0][rowl], cmw[1][rowl]),
                         fmaxf(cmw[2][rowl], cmw[3][rowl]));
  float s = 0.f;
  #pragma unroll
  for (int t = 0; t < 8; ++t)
    #pragma unroll
    for (int r = 0; r < 4; ++r) {
      float e = __expf(acc[t][r] - cm);
      acc[t][r] = e;
      s += e;
    }
  s += __shfl_xor(s, 16);
  s += __shfl_xor(s, 32);
  if (lane < 16) csw[wq][lane] = s;
  __syncthreads();
  const float cs = csw[0][rowl] + csw[1][rowl] + csw[2][rowl] + csw[3][rowl];
  const float cinv = 1.0f / cs;
  short* pbw = Pb[wq];
  #pragma unroll
  for (int t = 0; t < 8; ++t)
    #pragma unroll
    for (int r = 0; r < 4; ++r) {
      float al = acc[t][r] * cinv;
      float rsv = al;
      rsv += __shfl_xor(rsv, 1);
      rsv += __shfl_xor(rsv, 2);
      rsv += __shfl_xor(rsv, 4);
      rsv += __shfl_xor(rsv, 8);
      float pf = al / (1e-10f + rsv);
      pbw[(t * 16 + kg * 4 + r) * 16 + rowl] = f2bf(pf);
    }
  __syncthreads();
  bf16x8 w1f = zero8;
  if (kg < 2) {
    f32x4 a = *(const f32x4*)(W1 + rowl * 16 + kg * 8);
    f32x4 c = *(const f32x4*)(W1 + rowl * 16 + kg * 8 + 4);
    w1f = pack8(a, c);
  }
  const float b1v = b1[rowl];
  #pragma unroll
  for (int t = 0; t < 8; ++t) {
    bf16x8 pa = zero8;
    if (kg < 2)
      pa = *(const bf16x8*)(pbw + (t * 16 + rowl) * 16 + kg * 8);
    f32x4 z = {0.f, 0.f, 0.f, 0.f};
    f32x4 oacc = __builtin_amdgcn_mfma_f32_16x16x32_bf16(pa, w1f, z, 0, 0, 0);
    #pragma unroll
    for (int r = 0; r < 4; ++r) {
      int n = wq * 128 + t * 16 + kg * 4 + r;
      slice[(long)n * 16 + rowl] = f2bf(oacc[r] + b1v);
    }
  }
}

// ---------------- mega2: attn3(1024) + rowdot2(2176) ----------------
__global__ __launch_bounds__(256) void mega2_kernel(
    short* __restrict__ x12h,
    const float* __restrict__ W0, const float* __restrict__ b0,
    const float* __restrict__ W1, const float* __restrict__ b1,
    const float* __restrict__ hopeG, const float* __restrict__ alo,
    float* __restrict__ ao,
    const float* __restrict__ hmac, const float* __restrict__ alm,
    float* __restrict__ am) {
  const int blk = blockIdx.x, tid = threadIdx.x;
  if (blk < 1024) {
    attn3_body(blk >> 6, blk & 63, tid, x12h, W0, b0, W1, b1);
  } else {
    int t = blk - 1024;
    int wid = t * 4 + (tid >> 6);
    int lane = tid & 63;
    const float* X; const float* al; float* out; int r;
    if (wid < 8192)       { X = hopeG; al = alo; out = ao; r = wid; }
    else if (wid < 8704)  { X = hmac;  al = alm; out = am; r = wid - 8192; }
    else return;
    const float* row = X + (long)r * 128;
    float v = fmaf(row[lane], al[lane], row[lane + 64] * al[lane + 64]);
    #pragma unroll
    for (int off = 32; off; off >>= 1) v += __shfl_down(v, off);
    if (lane == 0) out[r] = v;
  }
}

// ---------------- proj GEMM body v3: bf16 pre-converted W (Wph), verified r31 ----------------
__device__ void gemm_hx_body(int bx, int by, int tid,
    const short* __restrict__ Xh, const short* __restrict__ Wh,
    const float* __restrict__ bias, float* __restrict__ C) {
  const int lane = tid & 63, w = tid >> 6;
  const int rowl = lane & 15, kg = lane >> 4;
  const int n0 = bx * 64;
  const int m0 = (by * 4 + w) * 16;
  const int row = m0 + rowl, b = row >> 9, n = row & 511;
  const short* xb = Xh + (long)b * 524288 + (long)n * 16 + (kg & 1) * 8;
  const long hofs = kg >> 1;
  const short* wb = Wh + (long)(n0 + rowl) * 1024 + kg * 8;
  const long sw = 16 * 1024L;
  f32x4 acc[4] = {};
  bf16x8 A0, A1;
  bf16x8 Wb0[4], Wb1[4];
  A0 = *(const bf16x8*)(xb + hofs * 8192);
  #pragma unroll
  for (int ni = 0; ni < 4; ++ni)
    Wb0[ni] = *(const bf16x8*)(wb + ni * sw);
  for (int k = 0; k < 1024; k += 64) {
    A1 = *(const bf16x8*)(xb + (((k + 32) >> 4) + hofs) * 8192);
    #pragma unroll
    for (int ni = 0; ni < 4; ++ni)
      Wb1[ni] = *(const bf16x8*)(wb + ni * sw + k + 32);
    #pragma unroll
    for (int ni = 0; ni < 4; ++ni)
      acc[ni] = __builtin_amdgcn_mfma_f32_16x16x32_bf16(A0, Wb0[ni], acc[ni], 0, 0, 0);
    if (k + 64 < 1024) {
      A0 = *(const bf16x8*)(xb + (((k + 64) >> 4) + hofs) * 8192);
      #pragma unroll
      for (int ni = 0; ni < 4; ++ni)
        Wb0[ni] = *(const bf16x8*)(wb + ni * sw + k + 64);
    }
    #pragma unroll
    for (int ni = 0; ni < 4; ++ni)
      acc[ni] = __builtin_amdgcn_mfma_f32_16x16x32_bf16(A1, Wb1[ni], acc[ni], 0, 0, 0);
  }
  #pragma unroll
  for (int ni = 0; ni < 4; ++ni) {
    int col = n0 + ni * 16 + rowl;
    float bv = bias ? bias[col] : 0.0f;
    int rb = m0 + kg * 4;
    #pragma unroll
    for (int r = 0; r < 4; ++r)
      C[(long)(rb + r) * 128 + col] = acc[ni][r] + bv;
  }
}

// ---------------- GAT body: 256 threads, 2 o's/thread (verified) ----------------
__device__ void gat_body(int b, int m, int tid,
    const float* __restrict__ adj, const float* __restrict__ ao,
    const float* __restrict__ am, const float* __restrict__ hopeG,
    const float* __restrict__ hmac, float* __restrict__ hmacs) {
  __shared__ float al[NO];
  __shared__ float redA[4], redB[4];
  __shared__ float part[2][128];
  const int lane = tid & 63, w = tid >> 6;
  const float amv = am[b * NM + m];
  float av[2], ev[2];
  float mx = -1e30f;
  #pragma unroll
  for (int i = 0; i < 2; ++i) {
    int o = tid + i * 256;
    float a = adj[(b * NO + o) * NM + m];
    float e = ao[b * NO + o] + amv;
    e = (e >= 0.f) ? e : 0.2f * e;
    av[i] = a; ev[i] = e;
    if (a == 1.0f) mx = fmaxf(mx, e);
  }
  #pragma unroll
  for (int off = 32; off; off >>= 1) mx = fmaxf(mx, __shfl_down(mx, off));
  if (lane == 0) redA[w] = mx;
  __syncthreads();
  mx = fmaxf(fmaxf(redA[0], redA[1]), fmaxf(redA[2], redA[3]));
  float p[2], s = 0.f;
  #pragma unroll
  for (int i = 0; i < 2; ++i) {
    p[i] = (av[i] == 1.0f) ? __expf(ev[i] - mx) : 0.f;
    s += p[i];
  }
  #pragma unroll
  for (int off = 32; off; off >>= 1) s += __shfl_down(s, off);
  if (lane == 0) redB[w] = s;
  __syncthreads();
  s = redB[0] + redB[1] + redB[2] + redB[3];
  const float sinv = (s > 0.f) ? 1.0f / s : 0.f;
  al[tid] = p[0] * sinv;
  al[tid + 256] = p[1] * sinv;
  __syncthreads();
  const int d = tid & 127, og = tid >> 7;
  float acc0 = 0.f, acc1 = 0.f;
  const float* hb = hopeG + ((long)(b * NO) + og * 256) * DOC + d;
  #pragma unroll 8
  for (int i = 0; i < 256; i += 2) {
    acc0 = fmaf(al[og * 256 + i],     hb[(long)i * DOC],       acc0);
    acc1 = fmaf(al[og * 256 + i + 1], hb[(long)(i + 1) * DOC], acc1);
  }
  part[og][d] = acc0 + acc1;
  __syncthreads();
  if (og == 0)
    hmacs[(b * NM + m) * DOC + d] = part[0][d] + part[1][d]
                                   + hmac[(b * NM + m) * DOC + d];
}

// ---------------- mega3: proj v3(256) + gat(512, b-major XCD remap) ----------------
__global__ __launch_bounds__(256) void mega3_kernel(
    const short* __restrict__ x12h, const short* __restrict__ Wph,
    const float* __restrict__ bp, float* __restrict__ hopes,
    const float* __restrict__ adj, const float* __restrict__ ao,
    const float* __restrict__ am, const float* __restrict__ hopeG,
    const float* __restrict__ hmac, float* __restrict__ hmacs) {
  const int blk = blockIdx.x, tid = threadIdx.x;
  if (blk < 256) {
    gemm_hx_body(blk & 1, blk >> 1, tid, x12h, Wph, bp, hopes);
  } else {
    int t = blk - 256;            // t = m*16 + b  -> XCD (t%8) = b%8: all m of a
    gat_body(t & 15, t >> 4, tid, // given b share one XCD's L2 for hopeG/adj
             adj, ao, am, hopeG, hmac, hmacs);
  }
}

// ---------------- pool+up+critic: one block per b (verified r29/r30 interior) ----------------
__device__ void pool_up_body(int b, int tid,
    const float* __restrict__ hopes, const float* __restrict__ hmacs,
    const float* __restrict__ A0, const float* __restrict__ Ab0,
    const float* __restrict__ C0, const float* __restrict__ Cb0,
    const float* __restrict__ C1, const float* __restrict__ Cb1,
    const float* __restrict__ C2, const float* __restrict__ Cb2,
    float* __restrict__ po, float* __restrict__ pm, float* __restrict__ up,
    float* __restrict__ out) {
  __shared__ float part[2][128];
  __shared__ float pos[128], pms[128];
  __shared__ float zc[128];
  __shared__ float scc[2];
  const int j = tid & 127, og = tid >> 7;
  // hopes sum: each og-half covers 256 rows, coalesced 512B row reads
  const float* hb = hopes + ((long)(b * 512) + og * 256) * 128 + j;
  float a0 = 0.f, a1 = 0.f;
  #pragma unroll 8
  for (int i = 0; i < 256; i += 2) {
    a0 += hb[(long)i * 128];
    a1 += hb[(long)(i + 1) * 128];
  }
  part[og][j] = a0 + a1;
  __syncthreads();
  if (og == 0) {
    float s = (part[0][j] + part[1][j]) * (1.0f / 512.0f);
    po[b * 128 + j] = s;
    pos[j] = s;
  } else {
    const float* mb = hmacs + (long)(b * 32) * 128 + j;
    float t0 = 0.f;
    #pragma unroll 8
    for (int i = 0; i < 32; ++i) t0 += mb[(long)i * 128];
    t0 *= (1.0f / 32.0f);
    pm[b * 128 + j] = t0;
    pms[j] = t0;
  }
  __syncthreads();
  if (tid < 128) {
    const float* a1p = A0 + (long)j * 512 + 256;
    const float* a2p = A0 + (long)j * 512 + 384;
    float acc = Ab0[j];
    #pragma unroll 4
    for (int k4 = 0; k4 < 32; ++k4) {
      f32x4 av = *(const f32x4*)(a1p + k4 * 4);
      acc = fmaf(av[0], pos[k4 * 4], acc);
      acc = fmaf(av[1], pos[k4 * 4 + 1], acc);
      acc = fmaf(av[2], pos[k4 * 4 + 2], acc);
      acc = fmaf(av[3], pos[k4 * 4 + 3], acc);
    }
    #pragma unroll 4
    for (int k4 = 0; k4 < 32; ++k4) {
      f32x4 av = *(const f32x4*)(a2p + k4 * 4);
      acc = fmaf(av[0], pms[k4 * 4], acc);
      acc = fmaf(av[1], pms[k4 * 4 + 1], acc);
      acc = fmaf(av[2], pms[k4 * 4 + 2], acc);
      acc = fmaf(av[3], pms[k4 * 4 + 3], acc);
    }
    up[b * 128 + j] = acc;
    // critic layer 1: v = (pos, pms)
    float cacc = Cb0[j];
    for (int k = 0; k < 128; ++k) cacc = fmaf(C0[j * 256 + k], pos[k], cacc);
    for (int k = 0; k < 128; ++k) cacc = fmaf(C0[j * 256 + 128 + k], pms[k], cacc);
    zc[j] = fast_tanh(cacc);
  }
  __syncthreads();
  if (tid < 128) {
    float acc2 = Cb1[j];
    for (int k = 0; k < 128; ++k) acc2 = fmaf(C1[j * 128 + k], zc[k], acc2);
    float z2 = fast_tanh(acc2);
    float p = C2[j] * z2;
    #pragma unroll
    for (int off = 32; off; off >>= 1) p += __shfl_down(p, off);
    const int lane = tid & 63, w = tid >> 6;
    if (lane == 0) scc[w] = p;
  }
  __syncthreads();
  if (tid == 0) out[16 + b] = scc[0] + scc[1] + Cb2[0];   // state_values
}

// ---------------- mega4 v4: pool+up+critic(16) + UoGEMM bf16-W(256) + UmhmGEMM bf16-W(16) ----------------
__global__ __launch_bounds__(256) void mega4_kernel(
    const float* __restrict__ hopes, const float* __restrict__ hmacs,
    const float* __restrict__ A0, const short* __restrict__ A0b,
    const float* __restrict__ Ab0,
    const float* __restrict__ C0, const float* __restrict__ Cb0,
    const float* __restrict__ C1, const float* __restrict__ Cb1,
    const float* __restrict__ C2, const float* __restrict__ Cb2,
    float* __restrict__ po, float* __restrict__ pm, float* __restrict__ up,
    float* __restrict__ Uo, float* __restrict__ umhm,
    float* __restrict__ out) {
  const int blk = blockIdx.x, tid = threadIdx.x;
  if (blk < 16) {
    pool_up_body(blk, tid, hopes, hmacs, A0, Ab0, C0, Cb0, C1, Cb1, C2, Cb2,
                 po, pm, up, out);
  } else if (blk < 272) {
    int t = blk - 16;
    gemm_wave_fb_body<1>(t & 1, t >> 1, tid, hopes, A0b, nullptr, Uo, 128, 128, 128, 512);
  } else {
    int t = blk - 272;            // M=512 rows of hmacs, W=A0 cols 128:256
    gemm_wave_fb_body<1>(t & 1, t >> 1, tid, hmacs, A0b + 128, nullptr, umhm, 128, 128, 128, 512);
  }
}

// ---------------- actor v9: fused per-wave masked softmax partials (verified r27/r28/r30) ----------------
__global__ __launch_bounds__(256) void actor_mfma9_kernel(
    const float* __restrict__ Uo, const float* __restrict__ umhm,
    const float* __restrict__ up, const short* __restrict__ A1p,
    const float* __restrict__ Ab1, const float* __restrict__ A2,
    const float* __restrict__ Ab2, const void* __restrict__ maskp,
    const int* __restrict__ flag, float* __restrict__ logits,
    float* __restrict__ partw) {
  const int tid = threadIdx.x;
  const int blk = blockIdx.x;
  const int oc = blk & 7;
  const int mg = (blk >> 3) & 7;
  const int b  = blk >> 6;
  const int obase = oc * 64;
  const int m0 = mg * 4;
  const int lane = tid & 63, w = tid >> 6;
  const int rowl = lane & 15, kg = lane >> 4;
  const float* uo = Uo + (long)(b * NO + obase + w * 16 + rowl) * 128;
  const float* upb = up + b * 128;
  const float* umb = umhm + (b * NM + m0) * 128;
  bf16x8 af[4][4];                       // [mi][kk]
  #pragma unroll
  for (int kk = 0; kk < 4; ++kk) {
    int kb = kk * 32 + kg * 8;
    f32x4 u0 = *(const f32x4*)(uo + kb);
    f32x4 u1 = *(const f32x4*)(uo + kb + 4);
    f32x4 p0 = *(const f32x4*)(upb + kb);
    f32x4 p1 = *(const f32x4*)(upb + kb + 4);
    float base0[4], base1[4];
    #pragma unroll
    for (int e = 0; e < 4; ++e) {
      base0[e] = u0[e] + p0[e];
      base1[e] = u1[e] + p1[e];
    }
    #pragma unroll
    for (int mi = 0; mi < 4; ++mi) {
      f32x4 a0 = *(const f32x4*)(umb + mi * 128 + kb);
      f32x4 a1 = *(const f32x4*)(umb + mi * 128 + kb + 4);
      float t[8];
      #pragma unroll
      for (int e = 0; e < 4; ++e) {
        t[e]     = fast_tanh(base0[e] + a0[e]);
        t[4 + e] = fast_tanh(base1[e] + a1[e]);
      }
      af[mi][kk] = pack8f(t);
    }
  }
  float pr[4][4] = {};
  #pragma unroll
  for (int ct = 0; ct < 8; ++ct) {
    const int col = ct * 16 + rowl;
    bf16x8 bf[4];
    #pragma unroll
    for (int kk = 0; kk < 4; ++kk)
      bf[kk] = *(const bf16x8*)(A1p + ((kk * 4 + kg) * 128 + col) * 8);
    f32x4 ac[4] = {};
    #pragma unroll
    for (int kk = 0; kk < 4; ++kk)
      #pragma unroll
      for (int mi = 0; mi < 4; ++mi)
        ac[mi] = __builtin_amdgcn_mfma_f32_16x16x32_bf16(af[mi][kk], bf[kk], ac[mi], 0, 0, 0);
    const float ab = Ab1[col], a2c = A2[col];
    #pragma unroll
    for (int mi = 0; mi < 4; ++mi)
      #pragma unroll
      for (int r = 0; r < 4; ++r) {
        float z = fast_tanh(ac[mi][r] + ab);
        pr[mi][r] = fmaf(a2c, z, pr[mi][r]);
      }
  }
  const float ab2 = Ab2[0];
  // butterfly-reduce; keep all 16 final logits per lane (identical across rowl)
  float rv[4][4];                        // [r][mi]
  #pragma unroll
  for (int r = 0; r < 4; ++r) {
    float v0 = pr[0][r], v1 = pr[1][r], v2 = pr[2][r], v3 = pr[3][r];
    #pragma unroll
    for (int off = 1; off < 16; off <<= 1) {
      v0 += __shfl_xor(v0, off);
      v1 += __shfl_xor(v1, off);
      v2 += __shfl_xor(v2, off);
      v3 += __shfl_xor(v3, off);
    }
    rv[r][0] = v0 + ab2; rv[r][1] = v1 + ab2;
    rv[r][2] = v2 + ab2; rv[r][3] = v3 + ab2;
  }
  const long base0 = ((long)b << 14) + (long)m0 * 512 + obase + w * 16 + kg * 4;
  if (rowl == 0) {
    #pragma unroll
    for (int r = 0; r < 4; ++r) {
      logits[base0 + r]        = rv[r][0];
      logits[base0 + 512 + r]  = rv[r][1];
      logits[base0 + 1024 + r] = rv[r][2];
      logits[base0 + 1536 + r] = rv[r][3];
    }
  }
  // fused masked softmax partial: lane covers o = obase+w*16+kg*4+r, m = m0+mi
  const bool word_mode = (flag[0] == 0);
  const int ob = obase + w * 16 + kg * 4;
  bool mk[4][4];
  if (word_mode) {
    const unsigned int* mw = (const unsigned int*)maskp;
    #pragma unroll
    for (int r = 0; r < 4; ++r) {
      long mo = (long)(b * NO + ob + r) * NM + m0;
      #pragma unroll
      for (int mi = 0; mi < 4; ++mi) mk[r][mi] = (mw[mo + mi] != 0u);
    }
  } else {
    const unsigned char* mb = (const unsigned char*)maskp;
    #pragma unroll
    for (int r = 0; r < 4; ++r) {
      long mo = (long)(b * NO + ob + r) * NM + m0;
      #pragma unroll
      for (int mi = 0; mi < 4; ++mi) mk[r][mi] = (mb[mo + mi] != 0);
    }
  }
  float lm = -1e30f;
  #pragma unroll
  for (int r = 0; r < 4; ++r)
    #pragma unroll
    for (int mi = 0; mi < 4; ++mi)
      if (mk[r][mi]) lm = fmaxf(lm, rv[r][mi]);
  float lS = 0.f, lT = 0.f;
  #pragma unroll
  for (int r = 0; r < 4; ++r)
    #pragma unroll
    for (int mi = 0; mi < 4; ++mi)
      if (mk[r][mi]) {
        float d = rv[r][mi] - lm;
        float e = __expf(d);
        lS += e; lT += e * d;
      }
  // merge across kg groups only (rowl lanes are duplicates)
  #pragma unroll
  for (int off = 16; off < 64; off <<= 1) {
    float om = __shfl_xor(lm, off);
    float oS = __shfl_xor(lS, off);
    float oT = __shfl_xor(lT, off);
    smmerge(lm, lS, lT, om, oS, oT);
  }
  if (lane == 0) {
    float* pp = partw + ((long)blk * 4 + w) * 3;
    pp[0] = lm; pp[1] = lS; pp[2] = lT;
  }
}

// ---------------- final_ab: 256-triple combine + gather + entropy (16 blocks x 64) ----------------
__global__ __launch_bounds__(64) void final_ab_kernel(
    const float* __restrict__ part, const float* __restrict__ logits,
    const int* __restrict__ aidx, float* __restrict__ out) {
  const int b = blockIdx.x;
  const int lane = threadIdx.x;
  float lm = -3e30f, lS = 0.f, lT = 0.f;
  const float* pp = part + ((long)b * 256 + lane * 4) * 3;
  #pragma unroll
  for (int t = 0; t < 4; ++t)
    smmerge(lm, lS, lT, pp[t * 3], pp[t * 3 + 1], pp[t * 3 + 2]);
  #pragma unroll
  for (int off = 1; off < 64; off <<= 1) {
    float om = __shfl_xor(lm, off);
    float oS = __shfl_xor(lS, off);
    float oT = __shfl_xor(lT, off);
    smmerge(lm, lS, lT, om, oS, oT);
  }
  if (lane == 0) {
    float lSm = logf(lS);
    out[b] = logits[(long)b * (NM * NO) + aidx[b]] - lm - lSm;  // action_logprobs
    out[32 + b] = lSm - lT / lS;                                // dist_entropys
  }
}

extern "C" void kernel_launch(void* const* d_in, const int* in_sizes, int n_in,
                              void* d_out, int out_size, void* d_ws, size_t ws_size,
                              hipStream_t stream) {
  (void)in_sizes; (void)n_in; (void)out_size; (void)ws_size;
  const float* adj  = (const float*)d_in[0];
  const float* nop  = (const float*)d_in[1];
  const float* nmac = (const float*)d_in[2];
  const void*  maskp = d_in[3];
  const int*   aidx = (const int*)d_in[4];
  const float* Wtr  = (const float*)d_in[5];
  const float* btr  = (const float*)d_in[6];
  const float* W0   = (const float*)d_in[7];
  const float* b0   = (const float*)d_in[8];
  const float* W1   = (const float*)d_in[9];
  const float* b1   = (const float*)d_in[10];
  const float* Wp   = (const float*)d_in[11];
  const float* bp   = (const float*)d_in[12];
  const float* Wo   = (const float*)d_in[13];
  const float* Wm   = (const float*)d_in[14];
  const float* alo  = (const float*)d_in[15];
  const float* alm  = (const float*)d_in[16];
  const float* A0   = (const float*)d_in[17];
  const float* Ab0  = (const float*)d_in[18];
  const float* A1   = (const float*)d_in[19];
  const float* Ab1  = (const float*)d_in[20];
  const float* A2   = (const float*)d_in[21];
  const float* Ab2  = (const float*)d_in[22];
  const float* C0   = (const float*)d_in[23];
  const float* Cb0  = (const float*)d_in[24];
  const float* C1   = (const float*)d_in[25];
  const float* Cb1  = (const float*)d_in[26];
  const float* C2   = (const float*)d_in[27];
  const float* Cb2  = (const float*)d_in[28];

  float* ws     = (float*)d_ws;        // needs ~47 MiB
  short* x12h   = (short*)(ws + OFF_X12);
  float* hopes  = ws + OFF_HOPES;
  float* hopeG  = ws + OFF_HOPEG;
  float* hmac   = ws + OFF_HMAC;
  float* hmacs  = ws + OFF_HMACS;
  float* ao     = ws + OFF_AO;
  float* am     = ws + OFF_AM;
  float* po     = ws + OFF_PO;
  float* pm     = ws + OFF_PM;
  float* Uo     = ws + OFF_UO;
  float* umhm   = ws + OFF_UMHM;
  float* logits = ws + OFF_LOG;
  float* up     = ws + OFF_UP;
  short* A1p    = (short*)(ws + OFF_A1P);
  short* Wph    = (short*)(ws + OFF_WPH);
  short* nopb   = (short*)(ws + OFF_NOPB);
  short* Wtrb   = (short*)(ws + OFF_WTRB);
  short* Wob    = (short*)(ws + OFF_WOB);
  short* A0b    = (short*)(ws + OFF_A0B);
  int*   flag   = (int*)(ws + OFF_FLAG);
  float* partw  = ws + OFF_PART2;
  float* outp   = (float*)d_out;

  // 0: pre-convert nop/Wtr/Wo/A1/Wp/A0 to bf16 + mask-probe
  mega0_kernel<<<745, 256, 0, stream>>>(nop, nopb, Wtr, Wtrb, Wo, Wob,
                                        A1, A1p, Wp, Wph, A0, A0b,
                                        (const unsigned int*)maskp, flag);
  // 1: trans bf16 (MT=4) + hopeG bf16 + hmac f32
  mega1_kernel<<<784, 256, 0, stream>>>(nopb, Wtrb, btr, x12h, Wob, hopeG,
                                        nmac, Wm, hmac);
  // 2: attention middle (MFMA) + rowdots
  mega2_kernel<<<3200, 256, 0, stream>>>(x12h, W0, b0, W1, b1,
                                         hopeG, alo, ao, hmac, alm, am);
  // 3: proj v3 (bf16 W) + gat (b-major XCD remap)
  mega3_kernel<<<768, 256, 0, stream>>>(x12h, Wph, bp, hopes,
                                        adj, ao, am, hopeG, hmac, hmacs);
  // 4: pool+up+critic + Uo GEMM (bf16 W) + Um-hmacs GEMM (bf16 W)
  mega4_kernel<<<288, 256, 0, stream>>>(hopes, hmacs, A0, A0b, Ab0,
                                        C0, Cb0, C1, Cb1, C2, Cb2,
                                        po, pm, up, Uo, umhm, outp);
  // 5: actor v9 (fused softmax partials)
  actor_mfma9_kernel<<<1024, 256, 0, stream>>>(Uo, umhm, up, A1p, Ab1, A2, Ab2,
                                               maskp, flag, logits, partw);
  // 6: combine(256 triples) + gather + entropy
  final_ab_kernel<<<16, 64, 0, stream>>>(partw, logits, aidx, outp);
}